// Round 1
// baseline (3208.831 us; speedup 1.0000x reference)
//
#include <hip/hip_runtime.h>
#include <cstddef>

// Problem constants (from reference)
#define NN 20000      // nodes
#define NE 320000     // edges
#define DIM 256       // model dim
#define NHEAD 8
#define DHEAD 32      // DK == DV == 32
#define NLAYER 2
#define HUS 1024

// ---------------------------------------------------------------------------
// fp32 tiled GEMM: C[M,N] = A[M,K] @ B[K,N] (+bias, optional relu)
// BM=BN=128, BK=16, 256 threads, 8x8 micro-tile per thread.
// VALU-bound by design: 64 v_fma (128cy/wave) vs 4 ds_read_b128 (~48cy) per k.
// ---------------------------------------------------------------------------
constexpr int BM = 128, BN = 128, BK = 16;

__global__ __launch_bounds__(256) void gemm_kernel(
    const float* __restrict__ A, int lda,
    const float* __restrict__ B, int ldb,
    float* __restrict__ C, int ldc,
    const float* __restrict__ bias,
    int M, int N, int K, int relu)
{
  __shared__ float As[BK][BM + 4];
  __shared__ float Bs[BK][BN + 4];
  const int tid = threadIdx.x;
  const int bm = blockIdx.y * BM;
  const int bn = blockIdx.x * BN;
  const int tx = tid & 15;
  const int ty = tid >> 4;
  const int row0 = ty * 8;
  const int col0 = tx * 8;

  float acc[8][8];
#pragma unroll
  for (int i = 0; i < 8; ++i)
#pragma unroll
    for (int j = 0; j < 8; ++j) acc[i][j] = 0.f;

  for (int k0 = 0; k0 < K; k0 += BK) {
    // A tile: 128x16, transpose into As[k][m]; 512 float4 slots, 2/thread
#pragma unroll
    for (int i = 0; i < 2; ++i) {
      int f = tid + i * 256;
      int ar = f >> 2, ac = (f & 3) * 4;
      float4 a4 = make_float4(0.f, 0.f, 0.f, 0.f);
      int grow = bm + ar;
      if (grow < M) a4 = *(const float4*)(A + (size_t)grow * lda + k0 + ac);
      As[ac + 0][ar] = a4.x;
      As[ac + 1][ar] = a4.y;
      As[ac + 2][ar] = a4.z;
      As[ac + 3][ar] = a4.w;
    }
    // B tile: 16x128 direct copy (N always multiple of 128 here)
#pragma unroll
    for (int i = 0; i < 2; ++i) {
      int f = tid + i * 256;
      int br = f >> 5, bc = (f & 31) * 4;
      *(float4*)&Bs[br][bc] =
          *(const float4*)(B + (size_t)(k0 + br) * ldb + bn + bc);
    }
    __syncthreads();
#pragma unroll
    for (int k = 0; k < BK; ++k) {
      float af[8], bf[8];
      *(float4*)&af[0] = *(const float4*)&As[k][row0];
      *(float4*)&af[4] = *(const float4*)&As[k][row0 + 4];
      *(float4*)&bf[0] = *(const float4*)&Bs[k][col0];
      *(float4*)&bf[4] = *(const float4*)&Bs[k][col0 + 4];
#pragma unroll
      for (int i = 0; i < 8; ++i)
#pragma unroll
        for (int j = 0; j < 8; ++j)
          acc[i][j] = fmaf(af[i], bf[j], acc[i][j]);
    }
    __syncthreads();
  }

  float bv[8];
#pragma unroll
  for (int j = 0; j < 8; ++j) bv[j] = bias ? bias[bn + col0 + j] : 0.f;

#pragma unroll
  for (int i = 0; i < 8; ++i) {
    int grow = bm + row0 + i;
    if (grow < M) {
      float* crow = C + (size_t)grow * ldc + bn + col0;
#pragma unroll
      for (int j4 = 0; j4 < 2; ++j4) {
        float4 o;
        o.x = acc[i][j4 * 4 + 0] + bv[j4 * 4 + 0];
        o.y = acc[i][j4 * 4 + 1] + bv[j4 * 4 + 1];
        o.z = acc[i][j4 * 4 + 2] + bv[j4 * 4 + 2];
        o.w = acc[i][j4 * 4 + 3] + bv[j4 * 4 + 3];
        if (relu) {
          o.x = fmaxf(o.x, 0.f); o.y = fmaxf(o.y, 0.f);
          o.z = fmaxf(o.z, 0.f); o.w = fmaxf(o.w, 0.f);
        }
        *(float4*)(crow + j4 * 4) = o;
      }
    }
  }
}

// ---------------------------------------------------------------------------
// Edge pass 1: one wave per edge. Lane i reads float4 i of q[dst] / k[src]
// rows (fully coalesced 1KB reads); 8-lane groups reduce per-head dot.
// Stores a = exp(e/sqrt(DK)), atomicAdd denominator z[dst,h].
// (max-free softmax: logits are O(1), z >= exp-of-some-term; matches ref
//  to ~1e-9 relative)
// ---------------------------------------------------------------------------
__global__ __launch_bounds__(256) void edge_logits(
    const float* __restrict__ qkv, const int* __restrict__ src,
    const int* __restrict__ dst, float* __restrict__ a_buf,
    float* __restrict__ z, int E)
{
  int e = (blockIdx.x * blockDim.x + threadIdx.x) >> 6;
  int lane = threadIdx.x & 63;
  if (e >= E) return;
  int s = src[e], d = dst[e];
  float4 q4 = ((const float4*)(qkv + (size_t)d * 768))[lane];        // q @ 0
  float4 k4 = ((const float4*)(qkv + (size_t)s * 768 + 256))[lane];  // k @ 256
  float p = q4.x * k4.x + q4.y * k4.y + q4.z * k4.z + q4.w * k4.w;
  p += __shfl_xor(p, 1);
  p += __shfl_xor(p, 2);
  p += __shfl_xor(p, 4);
  if ((lane & 7) == 0) {
    int h = lane >> 3;
    float av = expf(p * 0.17677669529663687f);  // 1/sqrt(32)
    a_buf[(size_t)e * NHEAD + h] = av;
    atomicAdd(&z[(size_t)d * NHEAD + h], av);
  }
}

// ---------------------------------------------------------------------------
// Edge pass 2: one wave per edge. alpha = a / (z[dst]+1e-9); scatter-add
// v[src] * alpha into agg[dst] (4 float atomics per lane).
// ---------------------------------------------------------------------------
__global__ __launch_bounds__(256) void edge_aggregate(
    const float* __restrict__ qkv, const int* __restrict__ src,
    const int* __restrict__ dst, const float* __restrict__ a_buf,
    const float* __restrict__ z, float* __restrict__ agg, int E)
{
  int e = (blockIdx.x * blockDim.x + threadIdx.x) >> 6;
  int lane = threadIdx.x & 63;
  if (e >= E) return;
  int s = src[e], d = dst[e];
  int h = lane >> 3;
  float alpha = a_buf[(size_t)e * NHEAD + h] /
                (z[(size_t)d * NHEAD + h] + 1e-9f);
  float4 v4 = ((const float4*)(qkv + (size_t)s * 768 + 512))[lane];  // v @ 512
  float* arow = agg + (size_t)d * DIM + lane * 4;
  atomicAdd(arow + 0, v4.x * alpha);
  atomicAdd(arow + 1, v4.y * alpha);
  atomicAdd(arow + 2, v4.z * alpha);
  atomicAdd(arow + 3, v4.w * alpha);
}

// ---------------------------------------------------------------------------
// Residual + LayerNorm, one wave per row (256 elems = 4/lane), h updated
// in place.
// ---------------------------------------------------------------------------
__global__ __launch_bounds__(256) void ln_residual(
    const float* __restrict__ attn, float* __restrict__ h,
    const float* __restrict__ g, const float* __restrict__ b, int n)
{
  int row = (blockIdx.x * blockDim.x + threadIdx.x) >> 6;
  int lane = threadIdx.x & 63;
  if (row >= n) return;
  float4 a4 = ((const float4*)(attn + (size_t)row * DIM))[lane];
  float4 h4 = ((const float4*)(h + (size_t)row * DIM))[lane];
  float x0 = a4.x + h4.x, x1 = a4.y + h4.y, x2 = a4.z + h4.z, x3 = a4.w + h4.w;
  float sum = x0 + x1 + x2 + x3;
#pragma unroll
  for (int off = 1; off < 64; off <<= 1) sum += __shfl_xor(sum, off);
  float mu = sum * (1.f / DIM);
  float d0 = x0 - mu, d1 = x1 - mu, d2 = x2 - mu, d3 = x3 - mu;
  float sq = d0 * d0 + d1 * d1 + d2 * d2 + d3 * d3;
#pragma unroll
  for (int off = 1; off < 64; off <<= 1) sq += __shfl_xor(sq, off);
  float inv = rsqrtf(sq * (1.f / DIM) + 1e-5f);
  float4 g4 = ((const float4*)g)[lane];
  float4 b4 = ((const float4*)b)[lane];
  float4 o;
  o.x = d0 * inv * g4.x + b4.x;
  o.y = d1 * inv * g4.y + b4.y;
  o.z = d2 * inv * g4.z + b4.z;
  o.w = d3 * inv * g4.w + b4.w;
  ((float4*)(h + (size_t)row * DIM))[lane] = o;
}

// ---------------------------------------------------------------------------
extern "C" void kernel_launch(void* const* d_in, const int* in_sizes, int n_in,
                              void* d_out, int out_size, void* d_ws, size_t ws_size,
                              hipStream_t stream)
{
  const float* h_in = (const float*)d_in[0];
  const int*   src  = (const int*)d_in[1];
  const int*   dst  = (const int*)d_in[2];
  const float* Wq   = (const float*)d_in[3];
  const float* Wk   = (const float*)d_in[4];
  const float* Wv   = (const float*)d_in[5];
  const float* Wo   = (const float*)d_in[6];
  const float* ln_g = (const float*)d_in[7];
  const float* ln_b = (const float*)d_in[8];
  const float* w1   = (const float*)d_in[9];
  const float* b1   = (const float*)d_in[10];
  const float* w2   = (const float*)d_in[11];
  const float* b2   = (const float*)d_in[12];
  float* out = (float*)d_out;

  // workspace layout (floats):
  //  [h: 5.12M][qkv: 15.36M][agg: 5.12M][a: 2.56M][z: 0.16M]  = 113.3 MB
  //  FFN hidden (20.48M) reuses qkv+agg exactly.
  float* ws   = (float*)d_ws;
  float* hbuf = ws;                                 // NN*DIM
  float* qkv  = hbuf + (size_t)NN * DIM;            // NN*768
  float* agg  = qkv + (size_t)NN * 768;             // NN*DIM
  float* abuf = agg + (size_t)NN * DIM;             // NE*NHEAD
  float* zbuf = abuf + (size_t)NE * NHEAD;          // NN*NHEAD
  float* ffn  = qkv;                                // NN*HUS (spans qkv+agg)

  hipMemcpyAsync(hbuf, h_in, (size_t)NN * DIM * sizeof(float),
                 hipMemcpyDeviceToDevice, stream);

  const dim3 blk(256);
  const dim3 g_proj(DIM / BN, (NN + BM - 1) / BM);        // 2 x 157
  const dim3 g_ffn1(HUS / BN, (NN + BM - 1) / BM);        // 8 x 157
  const int  g_edge = (NE * 64 + 255) / 256;              // 1 wave/edge
  const int  g_ln = (NN + 3) / 4;

  for (int l = 0; l < NLAYER; ++l) {
    const float* wq = Wq + (size_t)l * DIM * DIM;
    const float* wk = Wk + (size_t)l * DIM * DIM;
    const float* wv = Wv + (size_t)l * DIM * DIM;
    const float* wo = Wo + (size_t)l * DIM * DIM;

    // q,k,v projections into qkv (row stride 768)
    gemm_kernel<<<g_proj, blk, 0, stream>>>(hbuf, DIM, wq, DIM, qkv + 0, 768,
                                            nullptr, NN, DIM, DIM, 0);
    gemm_kernel<<<g_proj, blk, 0, stream>>>(hbuf, DIM, wk, DIM, qkv + 256, 768,
                                            nullptr, NN, DIM, DIM, 0);
    gemm_kernel<<<g_proj, blk, 0, stream>>>(hbuf, DIM, wv, DIM, qkv + 512, 768,
                                            nullptr, NN, DIM, DIM, 0);

    hipMemsetAsync(zbuf, 0, (size_t)NN * NHEAD * sizeof(float), stream);
    hipMemsetAsync(agg, 0, (size_t)NN * DIM * sizeof(float), stream);

    edge_logits<<<g_edge, blk, 0, stream>>>(qkv, src, dst, abuf, zbuf, NE);
    edge_aggregate<<<g_edge, blk, 0, stream>>>(qkv, src, dst, abuf, zbuf, agg, NE);

    // attention output projection into qkv region (now dead), stride DIM
    gemm_kernel<<<g_proj, blk, 0, stream>>>(agg, DIM, wo, DIM, qkv, DIM,
                                            nullptr, NN, DIM, DIM, 0);
    ln_residual<<<g_ln, blk, 0, stream>>>(qkv, hbuf, ln_g + l * DIM,
                                          ln_b + l * DIM, NN);
  }

  // FFN: relu(h@w1+b1) @ w2 + b2
  gemm_kernel<<<g_ffn1, blk, 0, stream>>>(hbuf, DIM, w1, HUS, ffn, HUS,
                                          b1, NN, HUS, DIM, 1);
  gemm_kernel<<<g_proj, blk, 0, stream>>>(ffn, HUS, w2, DIM, out, DIM,
                                          b2, NN, DIM, HUS, 0);
}

// Round 2
// 1178.233 us; speedup vs baseline: 2.7234x; 2.7234x over previous
//
#include <hip/hip_runtime.h>
#include <cstddef>

// Problem constants (from reference)
#define NN 20000      // nodes
#define NE 320000     // edges
#define DIM 256       // model dim
#define NHEAD 8
#define DHEAD 32      // DK == DV == 32
#define NLAYER 2
#define HUS 1024

// ---------------------------------------------------------------------------
// fp32 tiled GEMM: C[M,N] = A[M,K] @ B[K,N] (+bias, optional relu)
// BM=BN=128, BK=16, 256 threads, 8x8 micro-tile per thread.
// ---------------------------------------------------------------------------
constexpr int BM = 128, BN = 128, BK = 16;

__global__ __launch_bounds__(256) void gemm_kernel(
    const float* __restrict__ A, int lda,
    const float* __restrict__ B, int ldb,
    float* __restrict__ C, int ldc,
    const float* __restrict__ bias,
    int M, int N, int K, int relu)
{
  __shared__ float As[BK][BM + 4];
  __shared__ float Bs[BK][BN + 4];
  const int tid = threadIdx.x;
  const int bm = blockIdx.y * BM;
  const int bn = blockIdx.x * BN;
  const int tx = tid & 15;
  const int ty = tid >> 4;
  const int row0 = ty * 8;
  const int col0 = tx * 8;

  float acc[8][8];
#pragma unroll
  for (int i = 0; i < 8; ++i)
#pragma unroll
    for (int j = 0; j < 8; ++j) acc[i][j] = 0.f;

  for (int k0 = 0; k0 < K; k0 += BK) {
    // A tile: 128x16, transpose into As[k][m]; 512 float4 slots, 2/thread
#pragma unroll
    for (int i = 0; i < 2; ++i) {
      int f = tid + i * 256;
      int ar = f >> 2, ac = (f & 3) * 4;
      float4 a4 = make_float4(0.f, 0.f, 0.f, 0.f);
      int grow = bm + ar;
      if (grow < M) a4 = *(const float4*)(A + (size_t)grow * lda + k0 + ac);
      As[ac + 0][ar] = a4.x;
      As[ac + 1][ar] = a4.y;
      As[ac + 2][ar] = a4.z;
      As[ac + 3][ar] = a4.w;
    }
    // B tile: 16x128 direct copy (N always multiple of 128 here)
#pragma unroll
    for (int i = 0; i < 2; ++i) {
      int f = tid + i * 256;
      int br = f >> 5, bc = (f & 31) * 4;
      *(float4*)&Bs[br][bc] =
          *(const float4*)(B + (size_t)(k0 + br) * ldb + bn + bc);
    }
    __syncthreads();
#pragma unroll
    for (int k = 0; k < BK; ++k) {
      float af[8], bf[8];
      *(float4*)&af[0] = *(const float4*)&As[k][row0];
      *(float4*)&af[4] = *(const float4*)&As[k][row0 + 4];
      *(float4*)&bf[0] = *(const float4*)&Bs[k][col0];
      *(float4*)&bf[4] = *(const float4*)&Bs[k][col0 + 4];
#pragma unroll
      for (int i = 0; i < 8; ++i)
#pragma unroll
        for (int j = 0; j < 8; ++j)
          acc[i][j] = fmaf(af[i], bf[j], acc[i][j]);
    }
    __syncthreads();
  }

  float bv[8];
#pragma unroll
  for (int j = 0; j < 8; ++j) bv[j] = bias ? bias[bn + col0 + j] : 0.f;

#pragma unroll
  for (int i = 0; i < 8; ++i) {
    int grow = bm + row0 + i;
    if (grow < M) {
      float* crow = C + (size_t)grow * ldc + bn + col0;
#pragma unroll
      for (int j4 = 0; j4 < 2; ++j4) {
        float4 o;
        o.x = acc[i][j4 * 4 + 0] + bv[j4 * 4 + 0];
        o.y = acc[i][j4 * 4 + 1] + bv[j4 * 4 + 1];
        o.z = acc[i][j4 * 4 + 2] + bv[j4 * 4 + 2];
        o.w = acc[i][j4 * 4 + 3] + bv[j4 * 4 + 3];
        if (relu) {
          o.x = fmaxf(o.x, 0.f); o.y = fmaxf(o.y, 0.f);
          o.z = fmaxf(o.z, 0.f); o.w = fmaxf(o.w, 0.f);
        }
        *(float4*)(crow + j4 * 4) = o;
      }
    }
  }
}

// ---------------------------------------------------------------------------
// CSR build: histogram of dst -> exclusive scan -> scatter edge ids.
// Rebuilt every launch (ws is re-poisoned); ~640K cheap atomics total.
// ---------------------------------------------------------------------------
__global__ __launch_bounds__(256) void hist_kernel(
    const int* __restrict__ dst, int* __restrict__ cnt, int E)
{
  int e = blockIdx.x * blockDim.x + threadIdx.x;
  if (e < E) atomicAdd(&cnt[dst[e]], 1);
}

__global__ __launch_bounds__(1024) void scan_kernel(
    const int* __restrict__ cnt, int* __restrict__ rowstart)
{
  __shared__ int part[1024];
  const int t = threadIdx.x;
  const int CHUNK = (NN + 1023) / 1024;  // 20
  const int base = t * CHUNK;
  int s = 0;
#pragma unroll
  for (int i = 0; i < CHUNK; ++i) {
    int idx = base + i;
    if (idx < NN) s += cnt[idx];
  }
  part[t] = s;
  __syncthreads();
  for (int off = 1; off < 1024; off <<= 1) {
    int v = (t >= off) ? part[t - off] : 0;
    __syncthreads();
    part[t] += v;
    __syncthreads();
  }
  int run = part[t] - s;  // exclusive prefix of this chunk
#pragma unroll
  for (int i = 0; i < CHUNK; ++i) {
    int idx = base + i;
    if (idx < NN) { rowstart[idx] = run; run += cnt[idx]; }
  }
  if (t == 1023) rowstart[NN] = part[1023];
}

__global__ __launch_bounds__(256) void scatter_kernel(
    const int* __restrict__ dst, const int* __restrict__ rowstart,
    int* __restrict__ cursor, int* __restrict__ eid, int E)
{
  int e = blockIdx.x * blockDim.x + threadIdx.x;
  if (e >= E) return;
  int d = dst[e];
  int pos = atomicAdd(&cursor[d], 1);
  eid[rowstart[d] + pos] = e;
}

// ---------------------------------------------------------------------------
// Fused per-node attention: one wave per dst node. Lane i owns float4 i of
// the 256-wide row; head h = lane>>3 (8 lanes per head).
// Pass 1: per incoming edge, read k[src] row (coalesced 1KB), dot with the
//   register-resident q[d] row, 3-shfl reduce per head, exp -> LDS; z in reg.
// Pass 2: alpha = a/(z+1e-9); acc += v[src]*alpha.  One float4 store per lane.
// No atomics anywhere. Max-free softmax (logits O(1), matches ref ~1e-9 rel).
// ---------------------------------------------------------------------------
constexpr int DEG_CAP = 128;  // Poisson(16) over 20000 nodes: max deg ~45

__global__ __launch_bounds__(256) void node_attn(
    const float* __restrict__ qkv, const int* __restrict__ src,
    const int* __restrict__ rowstart, const int* __restrict__ eid,
    float* __restrict__ agg)
{
  __shared__ float lds_a[4][DEG_CAP * NHEAD];
  const int wave = threadIdx.x >> 6;
  const int lane = threadIdx.x & 63;
  const int d = blockIdx.x * 4 + wave;
  if (d >= NN) return;
  const int beg = rowstart[d], end = rowstart[d + 1];
  const int h = lane >> 3;
  float* la = lds_a[wave];

  const float4 q4 = ((const float4*)(qkv + (size_t)d * 768))[lane];
  const float scale = 0.17677669529663687f;  // 1/sqrt(32)

  float z = 0.f;
  for (int i = beg; i < end; ++i) {
    int s = src[eid[i]];
    float4 k4 = ((const float4*)(qkv + (size_t)s * 768 + 256))[lane];
    float p = q4.x * k4.x + q4.y * k4.y + q4.z * k4.z + q4.w * k4.w;
    p += __shfl_xor(p, 1);
    p += __shfl_xor(p, 2);
    p += __shfl_xor(p, 4);
    float a = expf(p * scale);
    z += a;
    int idx = i - beg;
    if (idx < DEG_CAP && (lane & 7) == 0) la[idx * NHEAD + h] = a;
  }
  // same-wave LDS write->read: compiler inserts lgkmcnt wait, no barrier needed

  const float zden = z + 1e-9f;
  float4 acc = make_float4(0.f, 0.f, 0.f, 0.f);
  for (int i = beg; i < end; ++i) {
    int s = src[eid[i]];
    int idx = i - beg;
    float a;
    if (idx < DEG_CAP) {
      a = la[idx * NHEAD + h];
    } else {  // rare fallback: recompute logit
      float4 k4 = ((const float4*)(qkv + (size_t)s * 768 + 256))[lane];
      float p = q4.x * k4.x + q4.y * k4.y + q4.z * k4.z + q4.w * k4.w;
      p += __shfl_xor(p, 1);
      p += __shfl_xor(p, 2);
      p += __shfl_xor(p, 4);
      a = expf(p * scale);
    }
    float al = a / zden;
    float4 v4 = ((const float4*)(qkv + (size_t)s * 768 + 512))[lane];
    acc.x += v4.x * al;
    acc.y += v4.y * al;
    acc.z += v4.z * al;
    acc.w += v4.w * al;
  }
  ((float4*)(agg + (size_t)d * DIM))[lane] = acc;
}

// ---------------------------------------------------------------------------
// Residual + LayerNorm, one wave per row (256 elems = 4/lane), h in place.
// ---------------------------------------------------------------------------
__global__ __launch_bounds__(256) void ln_residual(
    const float* __restrict__ attn, float* __restrict__ h,
    const float* __restrict__ g, const float* __restrict__ b, int n)
{
  int row = (blockIdx.x * blockDim.x + threadIdx.x) >> 6;
  int lane = threadIdx.x & 63;
  if (row >= n) return;
  float4 a4 = ((const float4*)(attn + (size_t)row * DIM))[lane];
  float4 h4 = ((const float4*)(h + (size_t)row * DIM))[lane];
  float x0 = a4.x + h4.x, x1 = a4.y + h4.y, x2 = a4.z + h4.z, x3 = a4.w + h4.w;
  float sum = x0 + x1 + x2 + x3;
#pragma unroll
  for (int off = 1; off < 64; off <<= 1) sum += __shfl_xor(sum, off);
  float mu = sum * (1.f / DIM);
  float d0 = x0 - mu, d1 = x1 - mu, d2 = x2 - mu, d3 = x3 - mu;
  float sq = d0 * d0 + d1 * d1 + d2 * d2 + d3 * d3;
#pragma unroll
  for (int off = 1; off < 64; off <<= 1) sq += __shfl_xor(sq, off);
  float inv = rsqrtf(sq * (1.f / DIM) + 1e-5f);
  float4 g4 = ((const float4*)g)[lane];
  float4 b4 = ((const float4*)b)[lane];
  float4 o;
  o.x = d0 * inv * g4.x + b4.x;
  o.y = d1 * inv * g4.y + b4.y;
  o.z = d2 * inv * g4.z + b4.z;
  o.w = d3 * inv * g4.w + b4.w;
  ((float4*)(h + (size_t)row * DIM))[lane] = o;
}

// ---------------------------------------------------------------------------
extern "C" void kernel_launch(void* const* d_in, const int* in_sizes, int n_in,
                              void* d_out, int out_size, void* d_ws, size_t ws_size,
                              hipStream_t stream)
{
  const float* h_in = (const float*)d_in[0];
  const int*   src  = (const int*)d_in[1];
  const int*   dst  = (const int*)d_in[2];
  const float* Wq   = (const float*)d_in[3];
  const float* Wk   = (const float*)d_in[4];
  const float* Wv   = (const float*)d_in[5];
  const float* Wo   = (const float*)d_in[6];
  const float* ln_g = (const float*)d_in[7];
  const float* ln_b = (const float*)d_in[8];
  const float* w1   = (const float*)d_in[9];
  const float* b1   = (const float*)d_in[10];
  const float* w2   = (const float*)d_in[11];
  const float* b2   = (const float*)d_in[12];
  float* out = (float*)d_out;

  // workspace layout (floats):
  //  [h: 5.12M][qkv: 15.36M][agg: 5.12M][CSR ints: ~1.44MB]  = ~103.9 MB
  //  FFN hidden (20.48M floats) reuses qkv+agg exactly.
  float* ws   = (float*)d_ws;
  float* hbuf = ws;                                 // NN*DIM
  float* qkv  = hbuf + (size_t)NN * DIM;            // NN*768
  float* agg  = qkv + (size_t)NN * 768;             // NN*DIM
  int*   cnt      = (int*)(agg + (size_t)NN * DIM); // NN (doubles as cursor)
  int*   rowstart = cnt + NN;                       // NN+1
  int*   eid      = rowstart + NN + 1;              // NE
  float* ffn  = qkv;                                // NN*HUS (spans qkv+agg)

  hipMemcpyAsync(hbuf, h_in, (size_t)NN * DIM * sizeof(float),
                 hipMemcpyDeviceToDevice, stream);

  const dim3 blk(256);
  const dim3 g_proj(DIM / BN, (NN + BM - 1) / BM);        // 2 x 157
  const dim3 g_ffn1(HUS / BN, (NN + BM - 1) / BM);        // 8 x 157
  const int  g_edge = (NE + 255) / 256;
  const int  g_node = (NN + 3) / 4;
  const int  g_ln = (NN + 3) / 4;

  // ---- build CSR of incoming edges (graph is layer-invariant) ----
  hipMemsetAsync(cnt, 0, NN * sizeof(int), stream);
  hist_kernel<<<g_edge, blk, 0, stream>>>(dst, cnt, NE);
  scan_kernel<<<1, 1024, 0, stream>>>(cnt, rowstart);
  hipMemsetAsync(cnt, 0, NN * sizeof(int), stream);       // reuse as cursor
  scatter_kernel<<<g_edge, blk, 0, stream>>>(dst, rowstart, cnt, eid, NE);

  for (int l = 0; l < NLAYER; ++l) {
    const float* wq = Wq + (size_t)l * DIM * DIM;
    const float* wk = Wk + (size_t)l * DIM * DIM;
    const float* wv = Wv + (size_t)l * DIM * DIM;
    const float* wo = Wo + (size_t)l * DIM * DIM;

    // q,k,v projections into qkv (row stride 768)
    gemm_kernel<<<g_proj, blk, 0, stream>>>(hbuf, DIM, wq, DIM, qkv + 0, 768,
                                            nullptr, NN, DIM, DIM, 0);
    gemm_kernel<<<g_proj, blk, 0, stream>>>(hbuf, DIM, wk, DIM, qkv + 256, 768,
                                            nullptr, NN, DIM, DIM, 0);
    gemm_kernel<<<g_proj, blk, 0, stream>>>(hbuf, DIM, wv, DIM, qkv + 512, 768,
                                            nullptr, NN, DIM, DIM, 0);

    node_attn<<<g_node, blk, 0, stream>>>(qkv, src, rowstart, eid, agg);

    // attention output projection into qkv region (now dead), stride DIM
    gemm_kernel<<<g_proj, blk, 0, stream>>>(agg, DIM, wo, DIM, qkv, DIM,
                                            nullptr, NN, DIM, DIM, 0);
    ln_residual<<<g_ln, blk, 0, stream>>>(qkv, hbuf, ln_g + l * DIM,
                                          ln_b + l * DIM, NN);
  }

  // FFN: relu(h@w1+b1) @ w2 + b2
  gemm_kernel<<<g_ffn1, blk, 0, stream>>>(hbuf, DIM, w1, HUS, ffn, HUS,
                                          b1, NN, HUS, DIM, 1);
  gemm_kernel<<<g_proj, blk, 0, stream>>>(ffn, HUS, w2, DIM, out, DIM,
                                          b2, NN, DIM, HUS, 0);
}

// Round 3
// 673.751 us; speedup vs baseline: 4.7626x; 1.7488x over previous
//
#include <hip/hip_runtime.h>
#include <cstddef>

// Problem constants (from reference)
#define NN 20000      // nodes
#define NE 320000     // edges
#define DIM 256       // model dim
#define NHEAD 8
#define DHEAD 32      // DK == DV == 32
#define NLAYER 2
#define HUS 1024

typedef __bf16 bf16x8 __attribute__((ext_vector_type(8)));
typedef float  f32x4  __attribute__((ext_vector_type(4)));

// ---------------------------------------------------------------------------
// bf16 MFMA GEMM: C[M,N] = A[M,K] @ Bt[N,K]^T  (A, Bt bf16 row-major)
// fp32 accumulate; optional bias/relu; optional bf16 output.
// 128x128 tile, BK=32, 256 threads = 4 waves in 2x2, each wave 64x64 via
// 4x4 mfma_f32_16x16x32_bf16. LDS [row][32] layout: ds_read_b128 at
// (m*32+quad*8) is perfectly banked (32 banks, 8 phases, no conflicts).
// C/D layout (HW-verified): col = lane&15, row = (lane>>4)*4 + reg.
// ---------------------------------------------------------------------------
__global__ __launch_bounds__(256) void gemm_bf16(
    const __bf16* __restrict__ A, int lda,
    const __bf16* __restrict__ Bt, int ldb,
    float* __restrict__ C, int ldc,
    const float* __restrict__ bias,
    int M, int N, int K, int relu, int outbf)
{
  __shared__ __align__(16) __bf16 As[128 * 32];
  __shared__ __align__(16) __bf16 Bs[128 * 32];
  const int tid  = threadIdx.x;
  const int wave = tid >> 6;
  const int lane = tid & 63;
  const int bm = blockIdx.y * 128;
  const int bn = blockIdx.x * 128;
  const int wm = (wave >> 1) * 64;
  const int wn = (wave & 1) * 64;
  const int quad  = lane >> 4;
  const int col15 = lane & 15;

  f32x4 acc[4][4];
#pragma unroll
  for (int i = 0; i < 4; ++i)
#pragma unroll
    for (int j = 0; j < 4; ++j) acc[i][j] = (f32x4){0.f, 0.f, 0.f, 0.f};

  for (int k0 = 0; k0 < K; k0 += 32) {
    // stage A-tile and B-tile: 512 chunks of 16B each, 2 per thread
#pragma unroll
    for (int i = 0; i < 2; ++i) {
      int c = tid + i * 256;
      int row = c >> 2;
      int off = (c & 3) * 8;
      uint4 av = make_uint4(0u, 0u, 0u, 0u);
      int gr = bm + row;
      if (gr < M) av = *(const uint4*)(A + (size_t)gr * lda + k0 + off);
      *(uint4*)(&As[row * 32 + off]) = av;
      // N is always a multiple of 128 here: no guard on B
      *(uint4*)(&Bs[row * 32 + off]) =
          *(const uint4*)(Bt + (size_t)(bn + row) * ldb + k0 + off);
    }
    __syncthreads();

    bf16x8 af[4], bfr[4];
    const int ko = quad * 8;
#pragma unroll
    for (int mt = 0; mt < 4; ++mt)
      af[mt] = *(const bf16x8*)(&As[(wm + mt * 16 + col15) * 32 + ko]);
#pragma unroll
    for (int nt = 0; nt < 4; ++nt)
      bfr[nt] = *(const bf16x8*)(&Bs[(wn + nt * 16 + col15) * 32 + ko]);
#pragma unroll
    for (int mt = 0; mt < 4; ++mt)
#pragma unroll
      for (int nt = 0; nt < 4; ++nt)
        acc[mt][nt] = __builtin_amdgcn_mfma_f32_16x16x32_bf16(
            af[mt], bfr[nt], acc[mt][nt], 0, 0, 0);
    __syncthreads();
  }

  // epilogue
  __bf16* Cb = (__bf16*)C;
#pragma unroll
  for (int nt = 0; nt < 4; ++nt) {
    int gc = bn + wn + nt * 16 + col15;
    float bv = bias ? bias[gc] : 0.f;
#pragma unroll
    for (int mt = 0; mt < 4; ++mt) {
      int rbase = bm + wm + mt * 16 + quad * 4;
#pragma unroll
      for (int r = 0; r < 4; ++r) {
        int gr = rbase + r;
        if (gr < M) {
          float o = acc[mt][nt][r] + bv;
          if (relu) o = fmaxf(o, 0.f);
          if (outbf) Cb[(size_t)gr * ldc + gc] = (__bf16)o;
          else       C[(size_t)gr * ldc + gc] = o;
        }
      }
    }
  }
}

// ---------------------------------------------------------------------------
// Tiled transpose + fp32->bf16: out[n*K + k] = bf16(in[k*N + n]).
// All dims multiples of 32. 256 threads, 32x32 tile.
// ---------------------------------------------------------------------------
__global__ __launch_bounds__(256) void transpose_bf16(
    const float* __restrict__ in, __bf16* __restrict__ out, int K, int N)
{
  __shared__ float t[32][33];
  const int bk = blockIdx.x * 32, bn = blockIdx.y * 32;
  const int tx = threadIdx.x & 31, ty = threadIdx.x >> 5;  // ty 0..7
#pragma unroll
  for (int i = 0; i < 32; i += 8)
    t[ty + i][tx] = in[(size_t)(bk + ty + i) * N + bn + tx];
  __syncthreads();
#pragma unroll
  for (int i = 0; i < 32; i += 8)
    out[(size_t)(bn + ty + i) * K + bk + tx] = (__bf16)t[tx][ty + i];
}

// fp32 -> bf16 elementwise, 8 per thread (n multiple of 8)
__global__ __launch_bounds__(256) void f32_to_bf16(
    const float* __restrict__ in, __bf16* __restrict__ out, int n)
{
  int i = (blockIdx.x * blockDim.x + threadIdx.x) * 8;
  if (i >= n) return;
  float4 a = *(const float4*)(in + i);
  float4 b = *(const float4*)(in + i + 4);
  __bf16 o[8] = {(__bf16)a.x, (__bf16)a.y, (__bf16)a.z, (__bf16)a.w,
                 (__bf16)b.x, (__bf16)b.y, (__bf16)b.z, (__bf16)b.w};
  *(uint4*)(out + i) = *(uint4*)o;
}

// ---------------------------------------------------------------------------
// CSR build: histogram of dst -> exclusive scan -> scatter edge ids.
// ---------------------------------------------------------------------------
__global__ __launch_bounds__(256) void hist_kernel(
    const int* __restrict__ dst, int* __restrict__ cnt, int E)
{
  int e = blockIdx.x * blockDim.x + threadIdx.x;
  if (e < E) atomicAdd(&cnt[dst[e]], 1);
}

__global__ __launch_bounds__(1024) void scan_kernel(
    const int* __restrict__ cnt, int* __restrict__ rowstart)
{
  __shared__ int part[1024];
  const int t = threadIdx.x;
  const int CHUNK = (NN + 1023) / 1024;  // 20
  const int base = t * CHUNK;
  int s = 0;
#pragma unroll
  for (int i = 0; i < CHUNK; ++i) {
    int idx = base + i;
    if (idx < NN) s += cnt[idx];
  }
  part[t] = s;
  __syncthreads();
  for (int off = 1; off < 1024; off <<= 1) {
    int v = (t >= off) ? part[t - off] : 0;
    __syncthreads();
    part[t] += v;
    __syncthreads();
  }
  int run = part[t] - s;
#pragma unroll
  for (int i = 0; i < CHUNK; ++i) {
    int idx = base + i;
    if (idx < NN) { rowstart[idx] = run; run += cnt[idx]; }
  }
  if (t == 1023) rowstart[NN] = part[1023];
}

__global__ __launch_bounds__(256) void scatter_kernel(
    const int* __restrict__ dst, const int* __restrict__ rowstart,
    int* __restrict__ cursor, int* __restrict__ eid, int E)
{
  int e = blockIdx.x * blockDim.x + threadIdx.x;
  if (e >= E) return;
  int d = dst[e];
  int pos = atomicAdd(&cursor[d], 1);
  eid[rowstart[d] + pos] = e;
}

// ---------------------------------------------------------------------------
// Fused per-node attention: one wave per dst node (unchanged from R1).
// ---------------------------------------------------------------------------
constexpr int DEG_CAP = 128;

__global__ __launch_bounds__(256) void node_attn(
    const float* __restrict__ qkv, const int* __restrict__ src,
    const int* __restrict__ rowstart, const int* __restrict__ eid,
    float* __restrict__ agg)
{
  __shared__ float lds_a[4][DEG_CAP * NHEAD];
  const int wave = threadIdx.x >> 6;
  const int lane = threadIdx.x & 63;
  const int d = blockIdx.x * 4 + wave;
  if (d >= NN) return;
  const int beg = rowstart[d], end = rowstart[d + 1];
  const int h = lane >> 3;
  float* la = lds_a[wave];

  const float4 q4 = ((const float4*)(qkv + (size_t)d * 768))[lane];
  const float scale = 0.17677669529663687f;  // 1/sqrt(32)

  float z = 0.f;
  for (int i = beg; i < end; ++i) {
    int s = src[eid[i]];
    float4 k4 = ((const float4*)(qkv + (size_t)s * 768 + 256))[lane];
    float p = q4.x * k4.x + q4.y * k4.y + q4.z * k4.z + q4.w * k4.w;
    p += __shfl_xor(p, 1);
    p += __shfl_xor(p, 2);
    p += __shfl_xor(p, 4);
    float a = expf(p * scale);
    z += a;
    int idx = i - beg;
    if (idx < DEG_CAP && (lane & 7) == 0) la[idx * NHEAD + h] = a;
  }

  const float zden = z + 1e-9f;
  float4 acc = make_float4(0.f, 0.f, 0.f, 0.f);
  for (int i = beg; i < end; ++i) {
    int s = src[eid[i]];
    int idx = i - beg;
    float a;
    if (idx < DEG_CAP) {
      a = la[idx * NHEAD + h];
    } else {
      float4 k4 = ((const float4*)(qkv + (size_t)s * 768 + 256))[lane];
      float p = q4.x * k4.x + q4.y * k4.y + q4.z * k4.z + q4.w * k4.w;
      p += __shfl_xor(p, 1);
      p += __shfl_xor(p, 2);
      p += __shfl_xor(p, 4);
      a = expf(p * scale);
    }
    float al = a / zden;
    float4 v4 = ((const float4*)(qkv + (size_t)s * 768 + 512))[lane];
    acc.x += v4.x * al;
    acc.y += v4.y * al;
    acc.z += v4.z * al;
    acc.w += v4.w * al;
  }
  ((float4*)(agg + (size_t)d * DIM))[lane] = acc;
}

// ---------------------------------------------------------------------------
// Residual + LayerNorm: h (fp32, in place) and bf16 copy for the next GEMM.
// ---------------------------------------------------------------------------
__global__ __launch_bounds__(256) void ln_residual(
    const float* __restrict__ attn, float* __restrict__ h,
    __bf16* __restrict__ hb,
    const float* __restrict__ g, const float* __restrict__ b, int n)
{
  int row = (blockIdx.x * blockDim.x + threadIdx.x) >> 6;
  int lane = threadIdx.x & 63;
  if (row >= n) return;
  float4 a4 = ((const float4*)(attn + (size_t)row * DIM))[lane];
  float4 h4 = ((const float4*)(h + (size_t)row * DIM))[lane];
  float x0 = a4.x + h4.x, x1 = a4.y + h4.y, x2 = a4.z + h4.z, x3 = a4.w + h4.w;
  float sum = x0 + x1 + x2 + x3;
#pragma unroll
  for (int off = 1; off < 64; off <<= 1) sum += __shfl_xor(sum, off);
  float mu = sum * (1.f / DIM);
  float d0 = x0 - mu, d1 = x1 - mu, d2 = x2 - mu, d3 = x3 - mu;
  float sq = d0 * d0 + d1 * d1 + d2 * d2 + d3 * d3;
#pragma unroll
  for (int off = 1; off < 64; off <<= 1) sq += __shfl_xor(sq, off);
  float inv = rsqrtf(sq * (1.f / DIM) + 1e-5f);
  float4 g4 = ((const float4*)g)[lane];
  float4 b4 = ((const float4*)b)[lane];
  float4 o;
  o.x = d0 * inv * g4.x + b4.x;
  o.y = d1 * inv * g4.y + b4.y;
  o.z = d2 * inv * g4.z + b4.z;
  o.w = d3 * inv * g4.w + b4.w;
  ((float4*)(h + (size_t)row * DIM))[lane] = o;
  __bf16 ob[4] = {(__bf16)o.x, (__bf16)o.y, (__bf16)o.z, (__bf16)o.w};
  *(uint2*)(hb + (size_t)row * DIM + lane * 4) = *(uint2*)ob;
}

// ---------------------------------------------------------------------------
extern "C" void kernel_launch(void* const* d_in, const int* in_sizes, int n_in,
                              void* d_out, int out_size, void* d_ws, size_t ws_size,
                              hipStream_t stream)
{
  const float* h_in = (const float*)d_in[0];
  const int*   src  = (const int*)d_in[1];
  const int*   dst  = (const int*)d_in[2];
  const float* Wq   = (const float*)d_in[3];
  const float* Wk   = (const float*)d_in[4];
  const float* Wv   = (const float*)d_in[5];
  const float* Wo   = (const float*)d_in[6];
  const float* ln_g = (const float*)d_in[7];
  const float* ln_b = (const float*)d_in[8];
  const float* w1   = (const float*)d_in[9];
  const float* b1   = (const float*)d_in[10];
  const float* w2   = (const float*)d_in[11];
  const float* b2   = (const float*)d_in[12];
  float* out = (float*)d_out;

  // workspace layout (float-equivalents):
  //  hbuf 5.12M | qkv 15.36M (also attnout fp32 / ffn-hidden bf16) |
  //  agg 5.12M | hbf 2.56M (bf16; also agg-bf16) | weights-bf16 0.53M |
  //  CSR ints 0.36M  -> ~116 MB
  float*  ws   = (float*)d_ws;
  float*  hbuf = ws;                                  // NN*DIM fp32
  float*  qkv  = hbuf + (size_t)NN * DIM;             // NN*768 fp32
  float*  agg  = qkv + (size_t)NN * 768;              // NN*DIM fp32
  __bf16* hbf  = (__bf16*)(agg + (size_t)NN * DIM);   // NN*DIM bf16
  __bf16* wbf  = hbf + (size_t)NN * DIM;              // 1.05M bf16
  int*    cnt      = (int*)(wbf + 1048576);           // NN
  int*    rowstart = cnt + NN;                        // NN+1
  int*    eid      = rowstart + NN + 1;               // NE

  __bf16* wqkvt = wbf;                          // 2 x [768][256]
  __bf16* wot   = wqkvt + 2 * 768 * 256;        // 2 x [256][256]
  __bf16* w1t   = wot + 2 * 256 * 256;          // [1024][256]
  __bf16* w2t   = w1t + 1024 * 256;             // [256][1024]
  float*  attnout = qkv;                        // aliases (qkv dead by then)
  __bf16* ffnb    = (__bf16*)qkv;               // NN*HUS bf16 (FFN hidden)

  hipMemcpyAsync(hbuf, h_in, (size_t)NN * DIM * sizeof(float),
                 hipMemcpyDeviceToDevice, stream);

  const dim3 blk(256);
  const int  g_edge = (NE + 255) / 256;
  const int  g_node = (NN + 3) / 4;
  const dim3 g_t256(8, 8);          // 256x256 transpose
  const dim3 g_t1024a(8, 32);       // w1 [256][1024] -> [1024][256]
  const dim3 g_t1024b(32, 8);       // w2 [1024][256] -> [256][1024]

  // ---- weights -> bf16 transposed ----
  for (int l = 0; l < NLAYER; ++l) {
    transpose_bf16<<<g_t256, blk, 0, stream>>>(
        Wq + (size_t)l * 65536, wqkvt + (size_t)l * 196608 + 0, 256, 256);
    transpose_bf16<<<g_t256, blk, 0, stream>>>(
        Wk + (size_t)l * 65536, wqkvt + (size_t)l * 196608 + 65536, 256, 256);
    transpose_bf16<<<g_t256, blk, 0, stream>>>(
        Wv + (size_t)l * 65536, wqkvt + (size_t)l * 196608 + 131072, 256, 256);
    transpose_bf16<<<g_t256, blk, 0, stream>>>(
        Wo + (size_t)l * 65536, wot + (size_t)l * 65536, 256, 256);
  }
  transpose_bf16<<<g_t1024a, blk, 0, stream>>>(w1, w1t, 256, 1024);
  transpose_bf16<<<g_t1024b, blk, 0, stream>>>(w2, w2t, 1024, 256);

  // ---- CSR of incoming edges ----
  hipMemsetAsync(cnt, 0, NN * sizeof(int), stream);
  hist_kernel<<<g_edge, blk, 0, stream>>>(dst, cnt, NE);
  scan_kernel<<<1, 1024, 0, stream>>>(cnt, rowstart);
  hipMemsetAsync(cnt, 0, NN * sizeof(int), stream);
  scatter_kernel<<<g_edge, blk, 0, stream>>>(dst, rowstart, cnt, eid, NE);

  // ---- initial h -> bf16 ----
  f32_to_bf16<<<(NN * DIM / 8 + 255) / 256, blk, 0, stream>>>(
      h_in, hbf, NN * DIM);

  const dim3 g_qkv(6, (NN + 127) / 128);   // N=768
  const dim3 g_n256(2, (NN + 127) / 128);  // N=256
  const dim3 g_ffn1(8, (NN + 127) / 128);  // N=1024

  for (int l = 0; l < NLAYER; ++l) {
    // fused q|k|v projection: [NN,256] @ [256,768] -> qkv (dense, ld 768)
    gemm_bf16<<<g_qkv, blk, 0, stream>>>(
        hbf, DIM, wqkvt + (size_t)l * 196608, DIM, qkv, 768,
        nullptr, NN, 768, DIM, 0, 0);

    node_attn<<<g_node, blk, 0, stream>>>(qkv, src, rowstart, eid, agg);

    // agg -> bf16 (reuses hbf: h-proj input no longer needed this layer)
    f32_to_bf16<<<(NN * DIM / 8 + 255) / 256, blk, 0, stream>>>(
        agg, hbf, NN * DIM);

    // output projection into attnout (= qkv region, now dead)
    gemm_bf16<<<g_n256, blk, 0, stream>>>(
        hbf, DIM, wot + (size_t)l * 65536, DIM, attnout, DIM,
        nullptr, NN, DIM, DIM, 0, 0);

    // residual + LN -> hbuf (fp32) and hbf (bf16 for next GEMM)
    ln_residual<<<g_node, blk, 0, stream>>>(
        attnout, hbuf, hbf, ln_g + l * DIM, ln_b + l * DIM, NN);
  }

  // FFN1: relu(h@w1+b1) -> bf16 hidden (into qkv region)
  gemm_bf16<<<g_ffn1, blk, 0, stream>>>(
      hbf, DIM, w1t, DIM, (float*)ffnb, HUS, b1, NN, HUS, DIM, 1, 1);
  // FFN2: hidden @ w2 + b2 -> out (fp32)
  gemm_bf16<<<g_n256, blk, 0, stream>>>(
      ffnb, HUS, w2t, HUS, out, DIM, b2, NN, DIM, HUS, 0, 0);
}

// Round 4
// 503.726 us; speedup vs baseline: 6.3702x; 1.3375x over previous
//
#include <hip/hip_runtime.h>
#include <cstddef>

// Problem constants (from reference)
#define NN 20000      // nodes
#define NE 320000     // edges
#define DIM 256       // model dim
#define NHEAD 8
#define DHEAD 32      // DK == DV == 32
#define NLAYER 2
#define HUS 1024

typedef __bf16 bf16x8 __attribute__((ext_vector_type(8)));
typedef __bf16 bf16x4 __attribute__((ext_vector_type(4)));
typedef float  f32x4  __attribute__((ext_vector_type(4)));

// ---------------------------------------------------------------------------
// bf16 MFMA GEMM: C[M,N] = A[M,K] @ Bt[N,K]^T  (A, Bt bf16 row-major)
// fp32 accumulate; optional bias/relu; optional bf16 output.
// 128x128 tile, BK=32, 256 threads = 4 waves in 2x2, each wave 64x64 via
// 4x4 mfma_f32_16x16x32_bf16. C/D layout: col = lane&15, row = quad*4 + reg.
// ---------------------------------------------------------------------------
__global__ __launch_bounds__(256) void gemm_bf16(
    const __bf16* __restrict__ A, int lda,
    const __bf16* __restrict__ Bt, int ldb,
    float* __restrict__ C, int ldc,
    const float* __restrict__ bias,
    int M, int N, int K, int relu, int outbf)
{
  __shared__ __align__(16) __bf16 As[128 * 32];
  __shared__ __align__(16) __bf16 Bs[128 * 32];
  const int tid  = threadIdx.x;
  const int wave = tid >> 6;
  const int lane = tid & 63;
  const int bm = blockIdx.y * 128;
  const int bn = blockIdx.x * 128;
  const int wm = (wave >> 1) * 64;
  const int wn = (wave & 1) * 64;
  const int quad  = lane >> 4;
  const int col15 = lane & 15;

  f32x4 acc[4][4];
#pragma unroll
  for (int i = 0; i < 4; ++i)
#pragma unroll
    for (int j = 0; j < 4; ++j) acc[i][j] = (f32x4){0.f, 0.f, 0.f, 0.f};

  for (int k0 = 0; k0 < K; k0 += 32) {
    // stage A-tile and B-tile: 512 chunks of 16B each, 2 per thread
#pragma unroll
    for (int i = 0; i < 2; ++i) {
      int c = tid + i * 256;
      int row = c >> 2;
      int off = (c & 3) * 8;
      uint4 av = make_uint4(0u, 0u, 0u, 0u);
      int gr = bm + row;
      if (gr < M) av = *(const uint4*)(A + (size_t)gr * lda + k0 + off);
      *(uint4*)(&As[row * 32 + off]) = av;
      // N is always a multiple of 128 here: no guard on B
      *(uint4*)(&Bs[row * 32 + off]) =
          *(const uint4*)(Bt + (size_t)(bn + row) * ldb + k0 + off);
    }
    __syncthreads();

    bf16x8 af[4], bfr[4];
    const int ko = quad * 8;
#pragma unroll
    for (int mt = 0; mt < 4; ++mt)
      af[mt] = *(const bf16x8*)(&As[(wm + mt * 16 + col15) * 32 + ko]);
#pragma unroll
    for (int nt = 0; nt < 4; ++nt)
      bfr[nt] = *(const bf16x8*)(&Bs[(wn + nt * 16 + col15) * 32 + ko]);
#pragma unroll
    for (int mt = 0; mt < 4; ++mt)
#pragma unroll
      for (int nt = 0; nt < 4; ++nt)
        acc[mt][nt] = __builtin_amdgcn_mfma_f32_16x16x32_bf16(
            af[mt], bfr[nt], acc[mt][nt], 0, 0, 0);
    __syncthreads();
  }

  // epilogue
  __bf16* Cb = (__bf16*)C;
#pragma unroll
  for (int nt = 0; nt < 4; ++nt) {
    int gc = bn + wn + nt * 16 + col15;
    float bv = bias ? bias[gc] : 0.f;
#pragma unroll
    for (int mt = 0; mt < 4; ++mt) {
      int rbase = bm + wm + mt * 16 + quad * 4;
#pragma unroll
      for (int r = 0; r < 4; ++r) {
        int gr = rbase + r;
        if (gr < M) {
          float o = acc[mt][nt][r] + bv;
          if (relu) o = fmaxf(o, 0.f);
          if (outbf) Cb[(size_t)gr * ldc + gc] = (__bf16)o;
          else       C[(size_t)gr * ldc + gc] = o;
        }
      }
    }
  }
}

// ---------------------------------------------------------------------------
// Tiled transpose + fp32->bf16: out[n*K + k] = bf16(in[k*N + n]).
// ---------------------------------------------------------------------------
__global__ __launch_bounds__(256) void transpose_bf16(
    const float* __restrict__ in, __bf16* __restrict__ out, int K, int N)
{
  __shared__ float t[32][33];
  const int bk = blockIdx.x * 32, bn = blockIdx.y * 32;
  const int tx = threadIdx.x & 31, ty = threadIdx.x >> 5;  // ty 0..7
#pragma unroll
  for (int i = 0; i < 32; i += 8)
    t[ty + i][tx] = in[(size_t)(bk + ty + i) * N + bn + tx];
  __syncthreads();
#pragma unroll
  for (int i = 0; i < 32; i += 8)
    out[(size_t)(bn + ty + i) * K + bk + tx] = (__bf16)t[tx][ty + i];
}

// fp32 -> bf16 elementwise, 8 per thread (n multiple of 8)
__global__ __launch_bounds__(256) void f32_to_bf16(
    const float* __restrict__ in, __bf16* __restrict__ out, int n)
{
  int i = (blockIdx.x * blockDim.x + threadIdx.x) * 8;
  if (i >= n) return;
  float4 a = *(const float4*)(in + i);
  float4 b = *(const float4*)(in + i + 4);
  __bf16 o[8] = {(__bf16)a.x, (__bf16)a.y, (__bf16)a.z, (__bf16)a.w,
                 (__bf16)b.x, (__bf16)b.y, (__bf16)b.z, (__bf16)b.w};
  *(uint4*)(out + i) = *(uint4*)o;
}

// ---------------------------------------------------------------------------
// CSR build: histogram of dst -> exclusive scan -> scatter edge ids.
// ---------------------------------------------------------------------------
__global__ __launch_bounds__(256) void hist_kernel(
    const int* __restrict__ dst, int* __restrict__ cnt, int E)
{
  int e = blockIdx.x * blockDim.x + threadIdx.x;
  if (e < E) atomicAdd(&cnt[dst[e]], 1);
}

__global__ __launch_bounds__(1024) void scan_kernel(
    const int* __restrict__ cnt, int* __restrict__ rowstart)
{
  __shared__ int part[1024];
  const int t = threadIdx.x;
  const int CHUNK = (NN + 1023) / 1024;  // 20
  const int base = t * CHUNK;
  int s = 0;
#pragma unroll
  for (int i = 0; i < CHUNK; ++i) {
    int idx = base + i;
    if (idx < NN) s += cnt[idx];
  }
  part[t] = s;
  __syncthreads();
  for (int off = 1; off < 1024; off <<= 1) {
    int v = (t >= off) ? part[t - off] : 0;
    __syncthreads();
    part[t] += v;
    __syncthreads();
  }
  int run = part[t] - s;
#pragma unroll
  for (int i = 0; i < CHUNK; ++i) {
    int idx = base + i;
    if (idx < NN) { rowstart[idx] = run; run += cnt[idx]; }
  }
  if (t == 1023) rowstart[NN] = part[1023];
}

__global__ __launch_bounds__(256) void scatter_kernel(
    const int* __restrict__ dst, const int* __restrict__ rowstart,
    int* __restrict__ cursor, int* __restrict__ eid, int E)
{
  int e = blockIdx.x * blockDim.x + threadIdx.x;
  if (e >= E) return;
  int d = dst[e];
  int pos = atomicAdd(&cursor[d], 1);
  eid[rowstart[d] + pos] = e;
}

// ---------------------------------------------------------------------------
// Fused per-node attention, SINGLE pass: one wave per dst node.
// qkv is bf16 [NN][768] (q|k|v). Lane i owns 4 consecutive elems of the
// 256-wide row; head h = lane>>3 (8 lanes x 4 elems = 32 = DHEAD).
// Online trick: sum_e (a_e/z) v_e == (sum_e a_e v_e) / z  -> no 2nd pass.
// Src ids prefetched 64 at a time lane-parallel (kills eid->src->row chase).
// agg written directly in bf16 (feeds Wo GEMM). No atomics, no LDS.
// ---------------------------------------------------------------------------
__global__ __launch_bounds__(256) void node_attn(
    const __bf16* __restrict__ qkv, const int* __restrict__ src,
    const int* __restrict__ rowstart, const int* __restrict__ eid,
    __bf16* __restrict__ agg)
{
  const int wave = threadIdx.x >> 6;
  const int lane = threadIdx.x & 63;
  const int d = blockIdx.x * 4 + wave;
  if (d >= NN) return;
  const int beg = rowstart[d], end = rowstart[d + 1];

  float qf0, qf1, qf2, qf3;
  {
    bf16x4 q4 = *(const bf16x4*)(qkv + (size_t)d * 768 + lane * 4);
    qf0 = (float)q4[0]; qf1 = (float)q4[1];
    qf2 = (float)q4[2]; qf3 = (float)q4[3];
  }
  const float scale = 0.17677669529663687f;  // 1/sqrt(32)
  float z = 0.f;
  float a0 = 0.f, a1 = 0.f, a2 = 0.f, a3 = 0.f;

  for (int c = beg; c < end; c += 64) {
    const int n = min(64, end - c);
    const int myi = c + lane;
    const int s_l = (myi < end) ? src[eid[myi]] : 0;
#pragma unroll 2
    for (int i = 0; i < n; ++i) {
      const int s = __shfl(s_l, i);
      const __bf16* base = qkv + (size_t)s * 768 + 256 + lane * 4;
      bf16x4 k4 = *(const bf16x4*)(base);
      bf16x4 v4 = *(const bf16x4*)(base + 256);
      float p = qf0 * (float)k4[0] + qf1 * (float)k4[1] +
                qf2 * (float)k4[2] + qf3 * (float)k4[3];
      p += __shfl_xor(p, 1);
      p += __shfl_xor(p, 2);
      p += __shfl_xor(p, 4);
      float a = __expf(p * scale);
      z += a;
      a0 += a * (float)v4[0];
      a1 += a * (float)v4[1];
      a2 += a * (float)v4[2];
      a3 += a * (float)v4[3];
    }
  }
  const float inv = 1.f / (z + 1e-9f);
  __bf16 o[4] = {(__bf16)(a0 * inv), (__bf16)(a1 * inv),
                 (__bf16)(a2 * inv), (__bf16)(a3 * inv)};
  *(uint2*)(agg + (size_t)d * DIM + lane * 4) = *(uint2*)o;
}

// ---------------------------------------------------------------------------
// Residual + LayerNorm: h (fp32, in place) and bf16 copy for the next GEMM.
// ---------------------------------------------------------------------------
__global__ __launch_bounds__(256) void ln_residual(
    const float* __restrict__ attn, float* __restrict__ h,
    __bf16* __restrict__ hb,
    const float* __restrict__ g, const float* __restrict__ b, int n)
{
  int row = (blockIdx.x * blockDim.x + threadIdx.x) >> 6;
  int lane = threadIdx.x & 63;
  if (row >= n) return;
  float4 a4 = ((const float4*)(attn + (size_t)row * DIM))[lane];
  float4 h4 = ((const float4*)(h + (size_t)row * DIM))[lane];
  float x0 = a4.x + h4.x, x1 = a4.y + h4.y, x2 = a4.z + h4.z, x3 = a4.w + h4.w;
  float sum = x0 + x1 + x2 + x3;
#pragma unroll
  for (int off = 1; off < 64; off <<= 1) sum += __shfl_xor(sum, off);
  float mu = sum * (1.f / DIM);
  float d0 = x0 - mu, d1 = x1 - mu, d2 = x2 - mu, d3 = x3 - mu;
  float sq = d0 * d0 + d1 * d1 + d2 * d2 + d3 * d3;
#pragma unroll
  for (int off = 1; off < 64; off <<= 1) sq += __shfl_xor(sq, off);
  float inv = rsqrtf(sq * (1.f / DIM) + 1e-5f);
  float4 g4 = ((const float4*)g)[lane];
  float4 b4 = ((const float4*)b)[lane];
  float4 o;
  o.x = d0 * inv * g4.x + b4.x;
  o.y = d1 * inv * g4.y + b4.y;
  o.z = d2 * inv * g4.z + b4.z;
  o.w = d3 * inv * g4.w + b4.w;
  ((float4*)(h + (size_t)row * DIM))[lane] = o;
  __bf16 ob[4] = {(__bf16)o.x, (__bf16)o.y, (__bf16)o.z, (__bf16)o.w};
  *(uint2*)(hb + (size_t)row * DIM + lane * 4) = *(uint2*)ob;
}

// ---------------------------------------------------------------------------
extern "C" void kernel_launch(void* const* d_in, const int* in_sizes, int n_in,
                              void* d_out, int out_size, void* d_ws, size_t ws_size,
                              hipStream_t stream)
{
  const float* h_in = (const float*)d_in[0];
  const int*   src  = (const int*)d_in[1];
  const int*   dst  = (const int*)d_in[2];
  const float* Wq   = (const float*)d_in[3];
  const float* Wk   = (const float*)d_in[4];
  const float* Wv   = (const float*)d_in[5];
  const float* Wo   = (const float*)d_in[6];
  const float* ln_g = (const float*)d_in[7];
  const float* ln_b = (const float*)d_in[8];
  const float* w1   = (const float*)d_in[9];
  const float* b1   = (const float*)d_in[10];
  const float* w2   = (const float*)d_in[11];
  const float* b2   = (const float*)d_in[12];
  float* out = (float*)d_out;

  // workspace layout (fp32-equivalent units):
  //  hbuf 5.12M | big region 15.36M (qkv bf16 / attnout fp32 / ffn bf16) |
  //  hbf 2.56M (bf16 h / bf16 agg) | weights bf16 0.53M | CSR ints 0.36M
  float*  ws   = (float*)d_ws;
  float*  hbuf = ws;                                  // NN*DIM fp32
  float*  big  = hbuf + (size_t)NN * DIM;             // 15.36M floats
  __bf16* hbf  = (__bf16*)(big + (size_t)NN * 768);   // NN*DIM bf16
  __bf16* wbf  = hbf + (size_t)NN * DIM;              // 1.05M bf16
  int*    cnt      = (int*)(wbf + 1048576);           // NN
  int*    rowstart = cnt + NN;                        // NN+1
  int*    eid      = rowstart + NN + 1;               // NE

  __bf16* qkvb    = (__bf16*)big;               // NN*768 bf16
  float*  attnout = big;                        // NN*DIM fp32 (aliases qkvb)
  __bf16* ffnb    = (__bf16*)big;               // NN*HUS bf16 (FFN hidden)

  __bf16* wqkvt = wbf;                          // 2 x [768][256]
  __bf16* wot   = wqkvt + 2 * 768 * 256;        // 2 x [256][256]
  __bf16* w1t   = wot + 2 * 256 * 256;          // [1024][256]
  __bf16* w2t   = w1t + 1024 * 256;             // [256][1024]

  hipMemcpyAsync(hbuf, h_in, (size_t)NN * DIM * sizeof(float),
                 hipMemcpyDeviceToDevice, stream);

  const dim3 blk(256);
  const int  g_edge = (NE + 255) / 256;
  const int  g_node = (NN + 3) / 4;
  const dim3 g_t256(8, 8);
  const dim3 g_t1024a(8, 32);       // w1 [256][1024] -> [1024][256]
  const dim3 g_t1024b(32, 8);       // w2 [1024][256] -> [256][1024]

  // ---- weights -> bf16 transposed ----
  for (int l = 0; l < NLAYER; ++l) {
    transpose_bf16<<<g_t256, blk, 0, stream>>>(
        Wq + (size_t)l * 65536, wqkvt + (size_t)l * 196608 + 0, 256, 256);
    transpose_bf16<<<g_t256, blk, 0, stream>>>(
        Wk + (size_t)l * 65536, wqkvt + (size_t)l * 196608 + 65536, 256, 256);
    transpose_bf16<<<g_t256, blk, 0, stream>>>(
        Wv + (size_t)l * 65536, wqkvt + (size_t)l * 196608 + 131072, 256, 256);
    transpose_bf16<<<g_t256, blk, 0, stream>>>(
        Wo + (size_t)l * 65536, wot + (size_t)l * 65536, 256, 256);
  }
  transpose_bf16<<<g_t1024a, blk, 0, stream>>>(w1, w1t, 256, 1024);
  transpose_bf16<<<g_t1024b, blk, 0, stream>>>(w2, w2t, 1024, 256);

  // ---- CSR of incoming edges ----
  hipMemsetAsync(cnt, 0, NN * sizeof(int), stream);
  hist_kernel<<<g_edge, blk, 0, stream>>>(dst, cnt, NE);
  scan_kernel<<<1, 1024, 0, stream>>>(cnt, rowstart);
  hipMemsetAsync(cnt, 0, NN * sizeof(int), stream);
  scatter_kernel<<<g_edge, blk, 0, stream>>>(dst, rowstart, cnt, eid, NE);

  // ---- initial h -> bf16 ----
  f32_to_bf16<<<(NN * DIM / 8 + 255) / 256, blk, 0, stream>>>(
      h_in, hbf, NN * DIM);

  const dim3 g_qkv(6, (NN + 127) / 128);   // N=768
  const dim3 g_n256(2, (NN + 127) / 128);  // N=256
  const dim3 g_ffn1(8, (NN + 127) / 128);  // N=1024

  for (int l = 0; l < NLAYER; ++l) {
    // fused q|k|v projection -> bf16 qkv (ld 768)
    gemm_bf16<<<g_qkv, blk, 0, stream>>>(
        hbf, DIM, wqkvt + (size_t)l * 196608, DIM, (float*)qkvb, 768,
        nullptr, NN, 768, DIM, 0, 1);

    // single-pass attention; agg -> bf16 into hbf (h no longer needed)
    node_attn<<<g_node, blk, 0, stream>>>(qkvb, src, rowstart, eid, hbf);

    // output projection (qkvb dead -> attnout aliases it)
    gemm_bf16<<<g_n256, blk, 0, stream>>>(
        hbf, DIM, wot + (size_t)l * 65536, DIM, attnout, DIM,
        nullptr, NN, DIM, DIM, 0, 0);

    // residual + LN -> hbuf (fp32) and hbf (bf16 for next GEMM)
    ln_residual<<<g_node, blk, 0, stream>>>(
        attnout, hbuf, hbf, ln_g + l * DIM, ln_b + l * DIM, NN);
  }

  // FFN1: relu(h@w1+b1) -> bf16 hidden
  gemm_bf16<<<g_ffn1, blk, 0, stream>>>(
      hbf, DIM, w1t, DIM, (float*)ffnb, HUS, b1, NN, HUS, DIM, 1, 1);
  // FFN2: hidden @ w2 + b2 -> out (fp32)
  gemm_bf16<<<g_n256, blk, 0, stream>>>(
      ffnb, HUS, w2t, HUS, out, DIM, b2, NN, DIM, HUS, 0, 0);
}

// Round 5
// 477.839 us; speedup vs baseline: 6.7153x; 1.0542x over previous
//
#include <hip/hip_runtime.h>
#include <cstddef>

// Problem constants (from reference)
#define NN 20000      // nodes
#define NE 320000     // edges
#define DIM 256       // model dim
#define NHEAD 8
#define DHEAD 32      // DK == DV == 32
#define NLAYER 2
#define HUS 1024

typedef __bf16 bf16x8 __attribute__((ext_vector_type(8)));
typedef __bf16 bf16x4 __attribute__((ext_vector_type(4)));
typedef float  f32x4  __attribute__((ext_vector_type(4)));

// async global->LDS, 16B per lane; LDS dest must be wave-uniform base + lane*16
#define GLDS16(g, l) __builtin_amdgcn_global_load_lds(                        \
    (const __attribute__((address_space(1))) void*)(g),                       \
    (__attribute__((address_space(3))) void*)(l), 16, 0, 0)

// ---------------------------------------------------------------------------
// bf16 MFMA GEMM: C[M,N] = A[M,K] @ Bt[N,K]^T  (A, Bt bf16 row-major)
// fp32 accumulate; optional bias/relu; optional bf16 output.
// 128x128 tile, BK=32, 256 threads = 4 waves in 2x2, each wave 64x64 via
// 4x4 mfma_f32_16x16x32_bf16. Staging via global_load_lds width=16:
// chunk c (0..511) lives at LDS byte c*16, exactly wave-base + lane*16.
// C/D layout: col = lane&15, row = quad*4 + reg.
// ---------------------------------------------------------------------------
__global__ __launch_bounds__(256) void gemm_bf16(
    const __bf16* __restrict__ A, int lda,
    const __bf16* __restrict__ Bt, int ldb,
    float* __restrict__ C, int ldc,
    const float* __restrict__ bias,
    int M, int N, int K, int relu, int outbf)
{
  __shared__ __align__(16) __bf16 As[128 * 32];
  __shared__ __align__(16) __bf16 Bs[128 * 32];
  const int tid  = threadIdx.x;
  const int wave = tid >> 6;
  const int lane = tid & 63;
  const int bm = blockIdx.y * 128;
  const int bn = blockIdx.x * 128;
  const int wm = (wave >> 1) * 64;
  const int wn = (wave & 1) * 64;
  const int quad  = lane >> 4;
  const int col15 = lane & 15;

  // staging addresses (2 chunks of 16B per thread for each of As/Bs)
  const int c1 = tid, c2 = tid + 256;
  const int ar1 = c1 >> 2, ao1 = (c1 & 3) * 8;
  const int ar2 = c2 >> 2, ao2 = (c2 & 3) * 8;
  const bool mok1 = (bm + ar1) < M;
  const bool mok2 = (bm + ar2) < M;
  const __bf16* ag1 = A + (size_t)(bm + ar1) * lda + ao1;
  const __bf16* ag2 = A + (size_t)(bm + ar2) * lda + ao2;
  const __bf16* bg1 = Bt + (size_t)(bn + ar1) * ldb + ao1;  // N % 128 == 0
  const __bf16* bg2 = Bt + (size_t)(bn + ar2) * ldb + ao2;
  __bf16* al1 = As + c1 * 8;
  __bf16* al2 = As + c2 * 8;
  __bf16* bl1 = Bs + c1 * 8;
  __bf16* bl2 = Bs + c2 * 8;

  f32x4 acc[4][4];
#pragma unroll
  for (int i = 0; i < 4; ++i)
#pragma unroll
    for (int j = 0; j < 4; ++j) acc[i][j] = (f32x4){0.f, 0.f, 0.f, 0.f};

  for (int k0 = 0; k0 < K; k0 += 32) {
    if (mok1) GLDS16(ag1 + k0, al1);   // OOB rows: LDS stays stale; those
    if (mok2) GLDS16(ag2 + k0, al2);   // C rows are never stored
    GLDS16(bg1 + k0, bl1);
    GLDS16(bg2 + k0, bl2);
    __syncthreads();   // compiler drains vmcnt before s_barrier

    bf16x8 af[4], bfr[4];
    const int ko = quad * 8;
#pragma unroll
    for (int mt = 0; mt < 4; ++mt)
      af[mt] = *(const bf16x8*)(&As[(wm + mt * 16 + col15) * 32 + ko]);
#pragma unroll
    for (int nt = 0; nt < 4; ++nt)
      bfr[nt] = *(const bf16x8*)(&Bs[(wn + nt * 16 + col15) * 32 + ko]);
#pragma unroll
    for (int mt = 0; mt < 4; ++mt)
#pragma unroll
      for (int nt = 0; nt < 4; ++nt)
        acc[mt][nt] = __builtin_amdgcn_mfma_f32_16x16x32_bf16(
            af[mt], bfr[nt], acc[mt][nt], 0, 0, 0);
    __syncthreads();
  }

  // epilogue
  __bf16* Cb = (__bf16*)C;
#pragma unroll
  for (int nt = 0; nt < 4; ++nt) {
    int gc = bn + wn + nt * 16 + col15;
    float bv = bias ? bias[gc] : 0.f;
#pragma unroll
    for (int mt = 0; mt < 4; ++mt) {
      int rbase = bm + wm + mt * 16 + quad * 4;
#pragma unroll
      for (int r = 0; r < 4; ++r) {
        int gr = rbase + r;
        if (gr < M) {
          float o = acc[mt][nt][r] + bv;
          if (relu) o = fmaxf(o, 0.f);
          if (outbf) Cb[(size_t)gr * ldc + gc] = (__bf16)o;
          else       C[(size_t)gr * ldc + gc] = o;
        }
      }
    }
  }
}

// ---------------------------------------------------------------------------
// ONE dispatch for all 10 weight transposes (fp32 -> bf16, [K][N]->[N][K]).
// Blocks 0..511:   8 x [256][256] (Wq,Wk,Wv,Wo x 2 layers), 64 tiles each.
// Blocks 512..767: w1 [256][1024].   Blocks 768..1023: w2 [1024][256].
// Wk/Wv transposed rows are PERMUTED so the QKV GEMM emits k|v interleaved
// per lane: within the 512-wide kv block, cols 8g..8g+3 = k[4g..4g+3],
// 8g+4..8g+7 = v[4g..4g+3]  ->  node_attn reads one bf16x8 per lane.
// ---------------------------------------------------------------------------
__global__ __launch_bounds__(256) void transpose_all(
    const float* __restrict__ Wq, const float* __restrict__ Wk,
    const float* __restrict__ Wv, const float* __restrict__ Wo,
    const float* __restrict__ w1, const float* __restrict__ w2,
    __bf16* __restrict__ wqkvt, __bf16* __restrict__ wot,
    __bf16* __restrict__ w1t, __bf16* __restrict__ w2t)
{
  __shared__ float t[32][33];
  const int b = blockIdx.x;
  const float* src;
  __bf16* dst;
  int N, Kd, bk, bn, mode = 0;  // mode 0: identity, 1: k-perm, 2: v-perm
  if (b < 512) {
    int m = b >> 6, tt = b & 63;
    bk = (tt & 7) * 32; bn = (tt >> 3) * 32;
    N = 256; Kd = 256;
    int l = m & 1, w = m >> 1;  // w: 0=Wq 1=Wk 2=Wv 3=Wo
    const float* Ws[4] = {Wq, Wk, Wv, Wo};
    src = Ws[w] + (size_t)l * 65536;
    if (w == 3) dst = wot + (size_t)l * 65536;
    else { dst = wqkvt + (size_t)l * 196608; mode = (w == 0) ? 0 : w; }
  } else if (b < 768) {
    int tt = b - 512;
    bk = (tt & 7) * 32; bn = (tt >> 3) * 32;
    N = 1024; Kd = 256; src = w1; dst = w1t;
  } else {
    int tt = b - 768;
    bk = (tt >> 3) * 32; bn = (tt & 7) * 32;
    N = 256; Kd = 1024; src = w2; dst = w2t;
  }
  const int tx = threadIdx.x & 31, ty = threadIdx.x >> 5;
#pragma unroll
  for (int i = 0; i < 32; i += 8)
    t[ty + i][tx] = src[(size_t)(bk + ty + i) * N + bn + tx];
  __syncthreads();
#pragma unroll
  for (int i = 0; i < 32; i += 8) {
    int n = bn + ty + i;
    int r = (mode == 0) ? n
          : 256 + ((n >> 2) * 8) + (n & 3) + (mode == 2 ? 4 : 0);
    dst[(size_t)r * Kd + bk + tx] = (__bf16)t[tx][ty + i];
  }
}

// h init: fp32 copy + bf16 cast in one pass (8 elems/thread)
__global__ __launch_bounds__(256) void init_h(
    const float* __restrict__ in, float* __restrict__ hbuf,
    __bf16* __restrict__ hb, int n)
{
  int i = (blockIdx.x * blockDim.x + threadIdx.x) * 8;
  if (i >= n) return;
  float4 a = *(const float4*)(in + i);
  float4 b = *(const float4*)(in + i + 4);
  *(float4*)(hbuf + i) = a;
  *(float4*)(hbuf + i + 4) = b;
  __bf16 o[8] = {(__bf16)a.x, (__bf16)a.y, (__bf16)a.z, (__bf16)a.w,
                 (__bf16)b.x, (__bf16)b.y, (__bf16)b.z, (__bf16)b.w};
  *(uint4*)(hb + i) = *(uint4*)o;
}

// ---------------------------------------------------------------------------
// CSR build: histogram of dst -> exclusive scan (also re-zeros cnt) -> scatter.
// ---------------------------------------------------------------------------
__global__ __launch_bounds__(256) void hist_kernel(
    const int* __restrict__ dst, int* __restrict__ cnt, int E)
{
  int e = blockIdx.x * blockDim.x + threadIdx.x;
  if (e < E) atomicAdd(&cnt[dst[e]], 1);
}

__global__ __launch_bounds__(1024) void scan_kernel(
    int* __restrict__ cnt, int* __restrict__ rowstart)
{
  __shared__ int part[1024];
  const int t = threadIdx.x;
  const int CHUNK = (NN + 1023) / 1024;  // 20
  const int base = t * CHUNK;
  int s = 0;
#pragma unroll
  for (int i = 0; i < CHUNK; ++i) {
    int idx = base + i;
    if (idx < NN) s += cnt[idx];
  }
  part[t] = s;
  __syncthreads();
  for (int off = 1; off < 1024; off <<= 1) {
    int v = (t >= off) ? part[t - off] : 0;
    __syncthreads();
    part[t] += v;
    __syncthreads();
  }
  int run = part[t] - s;
#pragma unroll
  for (int i = 0; i < CHUNK; ++i) {
    int idx = base + i;
    if (idx < NN) {
      rowstart[idx] = run;
      run += cnt[idx];
      cnt[idx] = 0;  // reset for scatter's cursor (saves a memset dispatch)
    }
  }
  if (t == 1023) rowstart[NN] = part[1023];
}

__global__ __launch_bounds__(256) void scatter_kernel(
    const int* __restrict__ dst, const int* __restrict__ rowstart,
    int* __restrict__ cursor, int* __restrict__ eid, int E)
{
  int e = blockIdx.x * blockDim.x + threadIdx.x;
  if (e >= E) return;
  int d = dst[e];
  int pos = atomicAdd(&cursor[d], 1);
  eid[rowstart[d] + pos] = e;
}

// ---------------------------------------------------------------------------
// Fused per-node attention, single pass, one wave per dst node.
// qkv bf16 [NN][768]: q (cols 0..255) + kv-interleaved (cols 256..767,
// lane's k/v 4-packs adjacent) -> ONE bf16x8 load per edge per lane.
// Next edge's kv prefetched while current is processed.
// ---------------------------------------------------------------------------
__global__ __launch_bounds__(256) void node_attn(
    const __bf16* __restrict__ qkv, const int* __restrict__ src,
    const int* __restrict__ rowstart, const int* __restrict__ eid,
    __bf16* __restrict__ agg)
{
  const int wave = threadIdx.x >> 6;
  const int lane = threadIdx.x & 63;
  const int d = blockIdx.x * 4 + wave;
  if (d >= NN) return;
  const int beg = rowstart[d], end = rowstart[d + 1];

  float qf0, qf1, qf2, qf3;
  {
    bf16x4 q4 = *(const bf16x4*)(qkv + (size_t)d * 768 + lane * 4);
    qf0 = (float)q4[0]; qf1 = (float)q4[1];
    qf2 = (float)q4[2]; qf3 = (float)q4[3];
  }
  const float scale = 0.17677669529663687f;  // 1/sqrt(32)
  float z = 0.f;
  float a0 = 0.f, a1 = 0.f, a2 = 0.f, a3 = 0.f;

  for (int c = beg; c < end; c += 64) {
    const int n = min(64, end - c);
    const int myi = c + lane;
    const int s_l = (myi < end) ? src[eid[myi]] : 0;

    int s = __shfl(s_l, 0);
    bf16x8 kv = *(const bf16x8*)(qkv + (size_t)s * 768 + 256 + lane * 8);
    for (int i = 0; i < n; ++i) {
      bf16x8 kvn = kv;
      if (i + 1 < n) {  // prefetch next edge's kv while processing current
        int sn = __shfl(s_l, i + 1);
        kvn = *(const bf16x8*)(qkv + (size_t)sn * 768 + 256 + lane * 8);
      }
      float p = qf0 * (float)kv[0] + qf1 * (float)kv[1] +
                qf2 * (float)kv[2] + qf3 * (float)kv[3];
      p += __shfl_xor(p, 1);
      p += __shfl_xor(p, 2);
      p += __shfl_xor(p, 4);
      float a = __expf(p * scale);
      z += a;
      a0 += a * (float)kv[4];
      a1 += a * (float)kv[5];
      a2 += a * (float)kv[6];
      a3 += a * (float)kv[7];
      kv = kvn;
    }
  }
  const float inv = 1.f / (z + 1e-9f);
  __bf16 o[4] = {(__bf16)(a0 * inv), (__bf16)(a1 * inv),
                 (__bf16)(a2 * inv), (__bf16)(a3 * inv)};
  *(uint2*)(agg + (size_t)d * DIM + lane * 4) = *(uint2*)o;
}

// ---------------------------------------------------------------------------
// Residual + LayerNorm: h (fp32, in place) and bf16 copy for the next GEMM.
// ---------------------------------------------------------------------------
__global__ __launch_bounds__(256) void ln_residual(
    const float* __restrict__ attn, float* __restrict__ h,
    __bf16* __restrict__ hb,
    const float* __restrict__ g, const float* __restrict__ b, int n)
{
  int row = (blockIdx.x * blockDim.x + threadIdx.x) >> 6;
  int lane = threadIdx.x & 63;
  if (row >= n) return;
  float4 a4 = ((const float4*)(attn + (size_t)row * DIM))[lane];
  float4 h4 = ((const float4*)(h + (size_t)row * DIM))[lane];
  float x0 = a4.x + h4.x, x1 = a4.y + h4.y, x2 = a4.z + h4.z, x3 = a4.w + h4.w;
  float sum = x0 + x1 + x2 + x3;
#pragma unroll
  for (int off = 1; off < 64; off <<= 1) sum += __shfl_xor(sum, off);
  float mu = sum * (1.f / DIM);
  float d0 = x0 - mu, d1 = x1 - mu, d2 = x2 - mu, d3 = x3 - mu;
  float sq = d0 * d0 + d1 * d1 + d2 * d2 + d3 * d3;
#pragma unroll
  for (int off = 1; off < 64; off <<= 1) sq += __shfl_xor(sq, off);
  float inv = rsqrtf(sq * (1.f / DIM) + 1e-5f);
  float4 g4 = ((const float4*)g)[lane];
  float4 b4 = ((const float4*)b)[lane];
  float4 o;
  o.x = d0 * inv * g4.x + b4.x;
  o.y = d1 * inv * g4.y + b4.y;
  o.z = d2 * inv * g4.z + b4.z;
  o.w = d3 * inv * g4.w + b4.w;
  ((float4*)(h + (size_t)row * DIM))[lane] = o;
  __bf16 ob[4] = {(__bf16)o.x, (__bf16)o.y, (__bf16)o.z, (__bf16)o.w};
  *(uint2*)(hb + (size_t)row * DIM + lane * 4) = *(uint2*)ob;
}

// ---------------------------------------------------------------------------
extern "C" void kernel_launch(void* const* d_in, const int* in_sizes, int n_in,
                              void* d_out, int out_size, void* d_ws, size_t ws_size,
                              hipStream_t stream)
{
  const float* h_in = (const float*)d_in[0];
  const int*   src  = (const int*)d_in[1];
  const int*   dst  = (const int*)d_in[2];
  const float* Wq   = (const float*)d_in[3];
  const float* Wk   = (const float*)d_in[4];
  const float* Wv   = (const float*)d_in[5];
  const float* Wo   = (const float*)d_in[6];
  const float* ln_g = (const float*)d_in[7];
  const float* ln_b = (const float*)d_in[8];
  const float* w1   = (const float*)d_in[9];
  const float* b1   = (const float*)d_in[10];
  const float* w2   = (const float*)d_in[11];
  const float* b2   = (const float*)d_in[12];
  float* out = (float*)d_out;

  // workspace layout (fp32-equivalent units):
  //  hbuf 5.12M | big 15.36M (qkv bf16 / attnout fp32 / ffn bf16) |
  //  hbf 2.56M bf16 | weights bf16 1.05M(bf16) | CSR ints
  float*  ws   = (float*)d_ws;
  float*  hbuf = ws;                                  // NN*DIM fp32
  float*  big  = hbuf + (size_t)NN * DIM;             // 15.36M floats
  __bf16* hbf  = (__bf16*)(big + (size_t)NN * 768);   // NN*DIM bf16
  __bf16* wbf  = hbf + (size_t)NN * DIM;              // 1.05M bf16
  int*    cnt      = (int*)(wbf + 1048576);           // NN
  int*    rowstart = cnt + NN;                        // NN+1
  int*    eid      = rowstart + NN + 1;               // NE

  __bf16* qkvb    = (__bf16*)big;               // NN*768 bf16
  float*  attnout = big;                        // NN*DIM fp32 (aliases qkvb)
  __bf16* ffnb    = (__bf16*)big;               // NN*HUS bf16 (FFN hidden)

  __bf16* wqkvt = wbf;                          // 2 x [768][256] (kv permuted)
  __bf16* wot   = wqkvt + 2 * 768 * 256;        // 2 x [256][256]
  __bf16* w1t   = wot + 2 * 256 * 256;          // [1024][256]
  __bf16* w2t   = w1t + 1024 * 256;             // [256][1024]

  const dim3 blk(256);
  const int  g_edge = (NE + 255) / 256;
  const int  g_node = (NN + 3) / 4;

  // one-time prep: weights (1 dispatch), h init (1), CSR (4)
  transpose_all<<<1024, blk, 0, stream>>>(Wq, Wk, Wv, Wo, w1, w2,
                                          wqkvt, wot, w1t, w2t);
  init_h<<<(NN * DIM / 8 + 255) / 256, blk, 0, stream>>>(
      h_in, hbuf, hbf, NN * DIM);

  hipMemsetAsync(cnt, 0, NN * sizeof(int), stream);
  hist_kernel<<<g_edge, blk, 0, stream>>>(dst, cnt, NE);
  scan_kernel<<<1, 1024, 0, stream>>>(cnt, rowstart);
  scatter_kernel<<<g_edge, blk, 0, stream>>>(dst, rowstart, cnt, eid, NE);

  const dim3 g_qkv(6, (NN + 127) / 128);   // N=768
  const dim3 g_n256(2, (NN + 127) / 128);  // N=256
  const dim3 g_ffn1(8, (NN + 127) / 128);  // N=1024

  for (int l = 0; l < NLAYER; ++l) {
    // fused q|kv projection -> bf16 qkv (ld 768), kv lane-interleaved
    gemm_bf16<<<g_qkv, blk, 0, stream>>>(
        hbf, DIM, wqkvt + (size_t)l * 196608, DIM, (float*)qkvb, 768,
        nullptr, NN, 768, DIM, 0, 1);

    // single-pass attention; agg -> bf16 into hbf (h input no longer needed)
    node_attn<<<g_node, blk, 0, stream>>>(qkvb, src, rowstart, eid, hbf);

    // output projection (qkvb dead -> attnout aliases it)
    gemm_bf16<<<g_n256, blk, 0, stream>>>(
        hbf, DIM, wot + (size_t)l * 65536, DIM, attnout, DIM,
        nullptr, NN, DIM, DIM, 0, 0);

    // residual + LN -> hbuf (fp32) and hbf (bf16 for next GEMM)
    ln_residual<<<g_node, blk, 0, stream>>>(
        attnout, hbuf, hbf, ln_g + l * DIM, ln_b + l * DIM, NN);
  }

  // FFN1: relu(h@w1+b1) -> bf16 hidden
  gemm_bf16<<<g_ffn1, blk, 0, stream>>>(
      hbf, DIM, w1t, DIM, (float*)ffnb, HUS, b1, NN, HUS, DIM, 1, 1);
  // FFN2: hidden @ w2 + b2 -> out (fp32)
  gemm_bf16<<<g_n256, blk, 0, stream>>>(
      ffnb, HUS, w2t, HUS, out, DIM, b2, NN, DIM, HUS, 0, 0);
}

// Round 6
// 474.632 us; speedup vs baseline: 6.7607x; 1.0068x over previous
//
#include <hip/hip_runtime.h>
#include <cstddef>

// Problem constants (from reference)
#define NN 20000      // nodes
#define NE 320000     // edges
#define DIM 256       // model dim
#define NHEAD 8
#define DHEAD 32      // DK == DV == 32
#define NLAYER 2
#define HUS 1024

typedef __bf16 bf16x8 __attribute__((ext_vector_type(8)));
typedef __bf16 bf16x4 __attribute__((ext_vector_type(4)));
typedef float  f32x4  __attribute__((ext_vector_type(4)));

// async global->LDS, 16B per lane; LDS dest must be wave-uniform base + lane*16
#define GLDS16(g, l) __builtin_amdgcn_global_load_lds(                        \
    (const __attribute__((address_space(1))) void*)(g),                       \
    (__attribute__((address_space(3))) void*)(l), 16, 0, 0)

// ---------------------------------------------------------------------------
// bf16 MFMA GEMM, templated on BN: C[M,N] = A[M,K] @ Bt[N,K]^T
// fp32 accumulate; optional bias/relu; optional bf16 output.
// BM=128, BK=32, 256 threads = 4 waves 2x2; wave = 64 x BN/2 via
// 4 x (BN/32) mfma_f32_16x16x32_bf16. Staging via global_load_lds width=16.
// C/D layout: col = lane&15, row = quad*4 + reg.
// ---------------------------------------------------------------------------
template <int BN_T>
__global__ __launch_bounds__(256) void gemm_bf16_t(
    const __bf16* __restrict__ A, int lda,
    const __bf16* __restrict__ Bt, int ldb,
    float* __restrict__ C, int ldc,
    const float* __restrict__ bias,
    int M, int N, int K, int relu, int outbf)
{
  constexpr int NT = BN_T / 32;          // n-tiles per wave
  __shared__ __align__(16) __bf16 As[128 * 32];
  __shared__ __align__(16) __bf16 Bs[BN_T * 32];
  const int tid  = threadIdx.x;
  const int wave = tid >> 6;
  const int lane = tid & 63;
  const int bm = blockIdx.y * 128;
  const int bn = blockIdx.x * BN_T;
  const int wm = (wave >> 1) * 64;
  const int wn = (wave & 1) * (BN_T / 2);
  const int quad  = lane >> 4;
  const int col15 = lane & 15;

  // A staging: 512 chunks of 16B, 2/thread
  const int ar1 = tid >> 2, ao1 = (tid & 3) * 8;
  const int ar2 = (tid + 256) >> 2, ao2 = ((tid + 256) & 3) * 8;
  const bool mok1 = (bm + ar1) < M;
  const bool mok2 = (bm + ar2) < M;
  const __bf16* ag1 = A + (size_t)(bm + ar1) * lda + ao1;
  const __bf16* ag2 = A + (size_t)(bm + ar2) * lda + ao2;
  __bf16* al1 = As + tid * 8;
  __bf16* al2 = As + (tid + 256) * 8;

  f32x4 acc[4][NT];
#pragma unroll
  for (int i = 0; i < 4; ++i)
#pragma unroll
    for (int j = 0; j < NT; ++j) acc[i][j] = (f32x4){0.f, 0.f, 0.f, 0.f};

  for (int k0 = 0; k0 < K; k0 += 32) {
    if (mok1) GLDS16(ag1 + k0, al1);
    if (mok2) GLDS16(ag2 + k0, al2);
#pragma unroll
    for (int i = 0; i < BN_T / 64; ++i) {   // B: BN_T*4 chunks
      int c = tid + i * 256;
      GLDS16(Bt + (size_t)(bn + (c >> 2)) * ldb + (c & 3) * 8 + k0,
             Bs + c * 8);
    }
    __syncthreads();

    bf16x8 af[4], bfr[NT];
    const int ko = quad * 8;
#pragma unroll
    for (int mt = 0; mt < 4; ++mt)
      af[mt] = *(const bf16x8*)(&As[(wm + mt * 16 + col15) * 32 + ko]);
#pragma unroll
    for (int nt = 0; nt < NT; ++nt)
      bfr[nt] = *(const bf16x8*)(&Bs[(wn + nt * 16 + col15) * 32 + ko]);
#pragma unroll
    for (int mt = 0; mt < 4; ++mt)
#pragma unroll
      for (int nt = 0; nt < NT; ++nt)
        acc[mt][nt] = __builtin_amdgcn_mfma_f32_16x16x32_bf16(
            af[mt], bfr[nt], acc[mt][nt], 0, 0, 0);
    __syncthreads();
  }

  __bf16* Cb = (__bf16*)C;
#pragma unroll
  for (int nt = 0; nt < NT; ++nt) {
    int gc = bn + wn + nt * 16 + col15;
    float bv = bias ? bias[gc] : 0.f;
#pragma unroll
    for (int mt = 0; mt < 4; ++mt) {
      int rbase = bm + wm + mt * 16 + quad * 4;
#pragma unroll
      for (int r = 0; r < 4; ++r) {
        int gr = rbase + r;
        if (gr < M) {
          float o = acc[mt][nt][r] + bv;
          if (relu) o = fmaxf(o, 0.f);
          if (outbf) Cb[(size_t)gr * ldc + gc] = (__bf16)o;
          else       C[(size_t)gr * ldc + gc] = o;
        }
      }
    }
  }
}

// ---------------------------------------------------------------------------
// Fused Wo-GEMM + residual + LayerNorm.
// C = agg[M,256] @ wot[256,256]^T; h <- LN(C + h)*g + b (fp32), hb <- bf16.
// BM=64, BN=256 (full row per block -> LN in-block), BK=32, 256 threads;
// waves 2x2: wave = 32 rows x 128 cols = 2x8 mfma tiles.
// Row stats: per-wave shfl over col15, cross-wave via 1KB LDS.
// In-place h safe: each block reads only its own 64 rows, writes after barrier.
// ---------------------------------------------------------------------------
__global__ __launch_bounds__(256) void gemm_wo_ln(
    const __bf16* __restrict__ A,   // agg bf16 [M][256]
    const __bf16* __restrict__ Bt,  // wot [256][256]
    float* __restrict__ h,          // fp32 residual in / LN out
    __bf16* __restrict__ hb,        // bf16 LN out
    const float* __restrict__ g, const float* __restrict__ bb, int M)
{
  __shared__ __align__(16) __bf16 As[64 * 32];
  __shared__ __align__(16) __bf16 Bs[256 * 32];
  __shared__ float red_s[64][2], red_q[64][2];
  const int tid  = threadIdx.x;
  const int wave = tid >> 6;
  const int lane = tid & 63;
  const int quad  = lane >> 4;
  const int col15 = lane & 15;
  const int bm = blockIdx.x * 64;
  const int wm = (wave >> 1) * 32;
  const int wn = (wave & 1) * 128;
  const int ch = wave & 1;

  // A staging: 256 chunks, 1/thread
  const int arow = tid >> 2, aoff = (tid & 3) * 8;
  const bool aok = (bm + arow) < M;
  const __bf16* agp = A + (size_t)(bm + arow) * 256 + aoff;
  __bf16* alp = As + tid * 8;

  f32x4 acc[2][8];
#pragma unroll
  for (int i = 0; i < 2; ++i)
#pragma unroll
    for (int j = 0; j < 8; ++j) acc[i][j] = (f32x4){0.f, 0.f, 0.f, 0.f};

  for (int k0 = 0; k0 < 256; k0 += 32) {
    if (aok) GLDS16(agp + k0, alp);
#pragma unroll
    for (int i = 0; i < 4; ++i) {   // B: 1024 chunks
      int c = tid + i * 256;
      GLDS16(Bt + (size_t)(c >> 2) * 256 + (c & 3) * 8 + k0, Bs + c * 8);
    }
    __syncthreads();
    bf16x8 af[2], bfr[8];
    const int ko = quad * 8;
#pragma unroll
    for (int mt = 0; mt < 2; ++mt)
      af[mt] = *(const bf16x8*)(&As[(wm + mt * 16 + col15) * 32 + ko]);
#pragma unroll
    for (int nt = 0; nt < 8; ++nt)
      bfr[nt] = *(const bf16x8*)(&Bs[(wn + nt * 16 + col15) * 32 + ko]);
#pragma unroll
    for (int mt = 0; mt < 2; ++mt)
#pragma unroll
      for (int nt = 0; nt < 8; ++nt)
        acc[mt][nt] = __builtin_amdgcn_mfma_f32_16x16x32_bf16(
            af[mt], bfr[nt], acc[mt][nt], 0, 0, 0);
    __syncthreads();
  }

  // residual add (in place into acc) + per-row sum / sumsq
#pragma unroll
  for (int mt = 0; mt < 2; ++mt)
#pragma unroll
    for (int r = 0; r < 4; ++r) {
      const int lr = wm + mt * 16 + quad * 4 + r;   // 0..63
      const int gr = bm + lr;
      float s = 0.f, q = 0.f;
#pragma unroll
      for (int nt = 0; nt < 8; ++nt) {
        int gc = wn + nt * 16 + col15;
        float x = acc[mt][nt][r];
        if (gr < M) x += h[(size_t)gr * 256 + gc];
        acc[mt][nt][r] = x;
        s += x; q += x * x;
      }
      s += __shfl_xor(s, 1); q += __shfl_xor(q, 1);
      s += __shfl_xor(s, 2); q += __shfl_xor(q, 2);
      s += __shfl_xor(s, 4); q += __shfl_xor(q, 4);
      s += __shfl_xor(s, 8); q += __shfl_xor(q, 8);
      if (col15 == 0) { red_s[lr][ch] = s; red_q[lr][ch] = q; }
    }
  __syncthreads();

#pragma unroll
  for (int mt = 0; mt < 2; ++mt)
#pragma unroll
    for (int r = 0; r < 4; ++r) {
      const int lr = wm + mt * 16 + quad * 4 + r;
      const int gr = bm + lr;
      if (gr >= M) continue;
      float s = red_s[lr][0] + red_s[lr][1];
      float q = red_q[lr][0] + red_q[lr][1];
      float mu  = s * (1.f / 256);
      float var = q * (1.f / 256) - mu * mu;
      float inv = rsqrtf(var + 1e-5f);
#pragma unroll
      for (int nt = 0; nt < 8; ++nt) {
        int gc = wn + nt * 16 + col15;
        float o = (acc[mt][nt][r] - mu) * inv * g[gc] + bb[gc];
        h[(size_t)gr * 256 + gc] = o;
        hb[(size_t)gr * 256 + gc] = (__bf16)o;
      }
    }
}

// ---------------------------------------------------------------------------
// PREP mega-kernel: one dispatch for
//  blocks 0..1023    : 10 weight transposes (fp32->bf16, kv-permuted)
//  blocks 1024..3523 : h init (fp32 copy + bf16 cast)
//  blocks 3524..4773 : dst histogram (cnt pre-zeroed by memset)
// Wk/Wv permutation: within the 512-wide kv block, cols 8g..8g+3 = k[4g..],
// 8g+4..8g+7 = v[4g..] -> node_attn reads one bf16x8 per lane.
// ---------------------------------------------------------------------------
__global__ __launch_bounds__(256) void prep_kernel(
    const float* __restrict__ Wq, const float* __restrict__ Wk,
    const float* __restrict__ Wv, const float* __restrict__ Wo,
    const float* __restrict__ w1, const float* __restrict__ w2,
    __bf16* __restrict__ wqkvt, __bf16* __restrict__ wot,
    __bf16* __restrict__ w1t, __bf16* __restrict__ w2t,
    const float* __restrict__ h_in, float* __restrict__ hbuf,
    __bf16* __restrict__ hb,
    const int* __restrict__ dst, int* __restrict__ cnt)
{
  __shared__ float t[32][33];
  const int b = blockIdx.x;
  if (b >= 3524) {               // ---- histogram ----
    int e = (b - 3524) * 256 + threadIdx.x;
    if (e < NE) atomicAdd(&cnt[dst[e]], 1);
    return;
  }
  if (b >= 1024) {               // ---- h init ----
    int i = ((b - 1024) * 256 + threadIdx.x) * 8;
    if (i >= NN * DIM) return;
    float4 a = *(const float4*)(h_in + i);
    float4 c = *(const float4*)(h_in + i + 4);
    *(float4*)(hbuf + i) = a;
    *(float4*)(hbuf + i + 4) = c;
    __bf16 o[8] = {(__bf16)a.x, (__bf16)a.y, (__bf16)a.z, (__bf16)a.w,
                   (__bf16)c.x, (__bf16)c.y, (__bf16)c.z, (__bf16)c.w};
    *(uint4*)(hb + i) = *(uint4*)o;
    return;
  }
  // ---- weight transposes ----
  const float* src;
  __bf16* dstp;
  int N, Kd, bk, bn, mode = 0;  // mode 0: identity, 1: k-perm, 2: v-perm
  if (b < 512) {
    int m = b >> 6, tt = b & 63;
    bk = (tt & 7) * 32; bn = (tt >> 3) * 32;
    N = 256; Kd = 256;
    int l = m & 1, w = m >> 1;  // w: 0=Wq 1=Wk 2=Wv 3=Wo
    const float* Ws[4] = {Wq, Wk, Wv, Wo};
    src = Ws[w] + (size_t)l * 65536;
    if (w == 3) dstp = wot + (size_t)l * 65536;
    else { dstp = wqkvt + (size_t)l * 196608; mode = (w == 0) ? 0 : w; }
  } else if (b < 768) {
    int tt = b - 512;
    bk = (tt & 7) * 32; bn = (tt >> 3) * 32;
    N = 1024; Kd = 256; src = w1; dstp = w1t;
  } else {
    int tt = b - 768;
    bk = (tt >> 3) * 32; bn = (tt & 7) * 32;
    N = 256; Kd = 1024; src = w2; dstp = w2t;
  }
  const int tx = threadIdx.x & 31, ty = threadIdx.x >> 5;
#pragma unroll
  for (int i = 0; i < 32; i += 8)
    t[ty + i][tx] = src[(size_t)(bk + ty + i) * N + bn + tx];
  __syncthreads();
#pragma unroll
  for (int i = 0; i < 32; i += 8) {
    int n = bn + ty + i;
    int r = (mode == 0) ? n
          : 256 + ((n >> 2) * 8) + (n & 3) + (mode == 2 ? 4 : 0);
    dstp[(size_t)r * Kd + bk + tx] = (__bf16)t[tx][ty + i];
  }
}

// ---------------------------------------------------------------------------
// CSR build: scan (re-zeros cnt for cursor reuse) + scatter.
// ---------------------------------------------------------------------------
__global__ __launch_bounds__(1024) void scan_kernel(
    int* __restrict__ cnt, int* __restrict__ rowstart)
{
  __shared__ int part[1024];
  const int t = threadIdx.x;
  const int CHUNK = (NN + 1023) / 1024;  // 20
  const int base = t * CHUNK;
  int s = 0;
#pragma unroll
  for (int i = 0; i < CHUNK; ++i) {
    int idx = base + i;
    if (idx < NN) s += cnt[idx];
  }
  part[t] = s;
  __syncthreads();
  for (int off = 1; off < 1024; off <<= 1) {
    int v = (t >= off) ? part[t - off] : 0;
    __syncthreads();
    part[t] += v;
    __syncthreads();
  }
  int run = part[t] - s;
#pragma unroll
  for (int i = 0; i < CHUNK; ++i) {
    int idx = base + i;
    if (idx < NN) {
      rowstart[idx] = run;
      run += cnt[idx];
      cnt[idx] = 0;  // reset for scatter's cursor
    }
  }
  if (t == 1023) rowstart[NN] = part[1023];
}

__global__ __launch_bounds__(256) void scatter_kernel(
    const int* __restrict__ dst, const int* __restrict__ rowstart,
    int* __restrict__ cursor, int* __restrict__ eid, int E)
{
  int e = blockIdx.x * blockDim.x + threadIdx.x;
  if (e >= E) return;
  int d = dst[e];
  int pos = atomicAdd(&cursor[d], 1);
  eid[rowstart[d] + pos] = e;
}

// ---------------------------------------------------------------------------
// Fused per-node attention, single pass, one wave per dst node.
// qkv bf16 [NN][768]: q (cols 0..255) + kv-interleaved (cols 256..767).
// ---------------------------------------------------------------------------
__global__ __launch_bounds__(256) void node_attn(
    const __bf16* __restrict__ qkv, const int* __restrict__ src,
    const int* __restrict__ rowstart, const int* __restrict__ eid,
    __bf16* __restrict__ agg)
{
  const int wave = threadIdx.x >> 6;
  const int lane = threadIdx.x & 63;
  const int d = blockIdx.x * 4 + wave;
  if (d >= NN) return;
  const int beg = rowstart[d], end = rowstart[d + 1];

  float qf0, qf1, qf2, qf3;
  {
    bf16x4 q4 = *(const bf16x4*)(qkv + (size_t)d * 768 + lane * 4);
    qf0 = (float)q4[0]; qf1 = (float)q4[1];
    qf2 = (float)q4[2]; qf3 = (float)q4[3];
  }
  const float scale = 0.17677669529663687f;  // 1/sqrt(32)
  float z = 0.f;
  float a0 = 0.f, a1 = 0.f, a2 = 0.f, a3 = 0.f;

  for (int c = beg; c < end; c += 64) {
    const int n = min(64, end - c);
    const int myi = c + lane;
    const int s_l = (myi < end) ? src[eid[myi]] : 0;

    int s = __shfl(s_l, 0);
    bf16x8 kv = *(const bf16x8*)(qkv + (size_t)s * 768 + 256 + lane * 8);
    for (int i = 0; i < n; ++i) {
      bf16x8 kvn = kv;
      if (i + 1 < n) {
        int sn = __shfl(s_l, i + 1);
        kvn = *(const bf16x8*)(qkv + (size_t)sn * 768 + 256 + lane * 8);
      }
      float p = qf0 * (float)kv[0] + qf1 * (float)kv[1] +
                qf2 * (float)kv[2] + qf3 * (float)kv[3];
      p += __shfl_xor(p, 1);
      p += __shfl_xor(p, 2);
      p += __shfl_xor(p, 4);
      float a = __expf(p * scale);
      z += a;
      a0 += a * (float)kv[4];
      a1 += a * (float)kv[5];
      a2 += a * (float)kv[6];
      a3 += a * (float)kv[7];
      kv = kvn;
    }
  }
  const float inv = 1.f / (z + 1e-9f);
  __bf16 o[4] = {(__bf16)(a0 * inv), (__bf16)(a1 * inv),
                 (__bf16)(a2 * inv), (__bf16)(a3 * inv)};
  *(uint2*)(agg + (size_t)d * DIM + lane * 4) = *(uint2*)o;
}

// ---------------------------------------------------------------------------
extern "C" void kernel_launch(void* const* d_in, const int* in_sizes, int n_in,
                              void* d_out, int out_size, void* d_ws, size_t ws_size,
                              hipStream_t stream)
{
  const float* h_in = (const float*)d_in[0];
  const int*   src  = (const int*)d_in[1];
  const int*   dst  = (const int*)d_in[2];
  const float* Wq   = (const float*)d_in[3];
  const float* Wk   = (const float*)d_in[4];
  const float* Wv   = (const float*)d_in[5];
  const float* Wo   = (const float*)d_in[6];
  const float* ln_g = (const float*)d_in[7];
  const float* ln_b = (const float*)d_in[8];
  const float* w1   = (const float*)d_in[9];
  const float* b1   = (const float*)d_in[10];
  const float* w2   = (const float*)d_in[11];
  const float* b2   = (const float*)d_in[12];
  float* out = (float*)d_out;

  // workspace layout (fp32-equivalent units):
  //  hbuf 5.12M | big 15.36M (qkv bf16 / ffn bf16) | hbf 2.56M bf16 |
  //  weights bf16 | CSR ints
  float*  ws   = (float*)d_ws;
  float*  hbuf = ws;                                  // NN*DIM fp32
  float*  big  = hbuf + (size_t)NN * DIM;             // 15.36M floats
  __bf16* hbf  = (__bf16*)(big + (size_t)NN * 768);   // NN*DIM bf16
  __bf16* wbf  = hbf + (size_t)NN * DIM;              // 1.05M bf16
  int*    cnt      = (int*)(wbf + 1048576);           // NN
  int*    rowstart = cnt + NN;                        // NN+1
  int*    eid      = rowstart + NN + 1;               // NE

  __bf16* qkvb = (__bf16*)big;               // NN*768 bf16
  __bf16* ffnb = (__bf16*)big;               // NN*HUS bf16 (FFN hidden)

  __bf16* wqkvt = wbf;                       // 2 x [768][256] (kv permuted)
  __bf16* wot   = wqkvt + 2 * 768 * 256;     // 2 x [256][256]
  __bf16* w1t   = wot + 2 * 256 * 256;       // [1024][256]
  __bf16* w2t   = w1t + 1024 * 256;          // [256][1024]

  const dim3 blk(256);
  const int  g_node = (NN + 3) / 4;

  // prep: memset + mega-prep (transposes | h-init | hist) + scan + scatter
  hipMemsetAsync(cnt, 0, NN * sizeof(int), stream);
  prep_kernel<<<4774, blk, 0, stream>>>(Wq, Wk, Wv, Wo, w1, w2,
                                        wqkvt, wot, w1t, w2t,
                                        h_in, hbuf, hbf, dst, cnt);
  scan_kernel<<<1, 1024, 0, stream>>>(cnt, rowstart);
  scatter_kernel<<<(NE + 255) / 256, blk, 0, stream>>>(
      dst, rowstart, cnt, eid, NE);

  const dim3 g_qkv(6, (NN + 127) / 128);   // N=768, BN=128
  const dim3 g_ffn1(8, (NN + 127) / 128);  // N=1024, BN=128
  const dim3 g_ffn2(4, (NN + 127) / 128);  // N=256, BN=64 -> 628 blocks
  const int  g_woln = (NN + 63) / 64;      // 313 blocks

  for (int l = 0; l < NLAYER; ++l) {
    // fused q|kv projection -> bf16 qkv (ld 768), kv lane-interleaved
    gemm_bf16_t<128><<<g_qkv, blk, 0, stream>>>(
        hbf, DIM, wqkvt + (size_t)l * 196608, DIM, (float*)qkvb, 768,
        nullptr, NN, 768, DIM, 0, 1);

    // single-pass attention; agg -> bf16 into hbf
    node_attn<<<g_node, blk, 0, stream>>>(qkvb, src, rowstart, eid, hbf);

    // fused Wo-GEMM + residual + LN -> hbuf (fp32) + hbf (bf16)
    gemm_wo_ln<<<g_woln, blk, 0, stream>>>(
        hbf, wot + (size_t)l * 65536, hbuf, hbf,
        ln_g + l * DIM, ln_b + l * DIM, NN);
  }

  // FFN1: relu(h@w1+b1) -> bf16 hidden
  gemm_bf16_t<128><<<g_ffn1, blk, 0, stream>>>(
      hbf, DIM, w1t, DIM, (float*)ffnb, HUS, b1, NN, HUS, DIM, 1, 1);
  // FFN2: hidden @ w2 + b2 -> out (fp32)
  gemm_bf16_t<64><<<g_ffn2, blk, 0, stream>>>(
      ffnb, HUS, w2t, HUS, out, DIM, b2, NN, DIM, HUS, 0, 0);
}

// Round 7
// 431.889 us; speedup vs baseline: 7.4298x; 1.0990x over previous
//
#include <hip/hip_runtime.h>
#include <cstddef>

// Problem constants (from reference)
#define NN 20000      // nodes
#define NE 320000     // edges
#define DIM 256       // model dim
#define NHEAD 8
#define DHEAD 32      // DK == DV == 32
#define NLAYER 2
#define HUS 1024

typedef __bf16 bf16x8 __attribute__((ext_vector_type(8)));
typedef __bf16 bf16x4 __attribute__((ext_vector_type(4)));
typedef float  f32x4  __attribute__((ext_vector_type(4)));

// async global->LDS, 16B per lane; LDS dest must be wave-uniform base + lane*16
#define GLDS16(g, l) __builtin_amdgcn_global_load_lds(                        \
    (const __attribute__((address_space(1))) void*)(g),                       \
    (__attribute__((address_space(3))) void*)(l), 16, 0, 0)

// ---------------------------------------------------------------------------
// bf16 MFMA GEMM: C[M,N] = A[M,K] @ Bt[N,K]^T  (A, Bt bf16 row-major)
// BM=128, BN_T columns, 256 threads = 4 waves 2x2.
// K-loop processes TWO BK=32 tiles per barrier pair (half the barriers of
// the 1-tile version; keeps the proven [row][32] LDS bank geometry and
// global_load_lds lane-affinity). TAG only differentiates kernel names
// for rocprof attribution.
// C/D layout: col = lane&15, row = quad*4 + reg.
// ---------------------------------------------------------------------------
template <int BN_T, int TAG>
__global__ __launch_bounds__(256) void gemm_bf16_t(
    const __bf16* __restrict__ A, int lda,
    const __bf16* __restrict__ Bt, int ldb,
    float* __restrict__ C, int ldc,
    const float* __restrict__ bias,
    int M, int N, int K, int relu, int outbf)
{
  constexpr int NT = BN_T / 32;          // n-tiles per wave
  __shared__ __align__(16) __bf16 As[2][128 * 32];
  __shared__ __align__(16) __bf16 Bs[2][BN_T * 32];
  const int tid  = threadIdx.x;
  const int wave = tid >> 6;
  const int lane = tid & 63;
  const int bm = blockIdx.y * 128;
  const int bn = blockIdx.x * BN_T;
  const int wm = (wave >> 1) * 64;
  const int wn = (wave & 1) * (BN_T / 2);
  const int quad  = lane >> 4;
  const int col15 = lane & 15;

  // A staging per 32-tile: 512 chunks of 16B, 2/thread
  const int ar1 = tid >> 2, ao1 = (tid & 3) * 8;
  const int ar2 = (tid + 256) >> 2, ao2 = ((tid + 256) & 3) * 8;
  const bool mok1 = (bm + ar1) < M;
  const bool mok2 = (bm + ar2) < M;
  const __bf16* ag1 = A + (size_t)(bm + ar1) * lda + ao1;
  const __bf16* ag2 = A + (size_t)(bm + ar2) * lda + ao2;

  f32x4 acc[4][NT];
#pragma unroll
  for (int i = 0; i < 4; ++i)
#pragma unroll
    for (int j = 0; j < NT; ++j) acc[i][j] = (f32x4){0.f, 0.f, 0.f, 0.f};

  for (int k0 = 0; k0 < K; k0 += 64) {
#pragma unroll
    for (int t = 0; t < 2; ++t) {
      if (mok1) GLDS16(ag1 + k0 + t * 32, &As[t][tid * 8]);
      if (mok2) GLDS16(ag2 + k0 + t * 32, &As[t][(tid + 256) * 8]);
#pragma unroll
      for (int i = 0; i < BN_T / 64; ++i) {   // B: BN_T*4 chunks per tile
        int c = tid + i * 256;
        GLDS16(Bt + (size_t)(bn + (c >> 2)) * ldb + (c & 3) * 8 + k0 + t * 32,
               &Bs[t][c * 8]);
      }
    }
    __syncthreads();

    const int ko = quad * 8;
#pragma unroll
    for (int t = 0; t < 2; ++t) {
      bf16x8 af[4], bfr[NT];
#pragma unroll
      for (int mt = 0; mt < 4; ++mt)
        af[mt] = *(const bf16x8*)(&As[t][(wm + mt * 16 + col15) * 32 + ko]);
#pragma unroll
      for (int nt = 0; nt < NT; ++nt)
        bfr[nt] = *(const bf16x8*)(&Bs[t][(wn + nt * 16 + col15) * 32 + ko]);
#pragma unroll
      for (int mt = 0; mt < 4; ++mt)
#pragma unroll
        for (int nt = 0; nt < NT; ++nt)
          acc[mt][nt] = __builtin_amdgcn_mfma_f32_16x16x32_bf16(
              af[mt], bfr[nt], acc[mt][nt], 0, 0, 0);
    }
    __syncthreads();
  }

  __bf16* Cb = (__bf16*)C;
#pragma unroll
  for (int nt = 0; nt < NT; ++nt) {
    int gc = bn + wn + nt * 16 + col15;
    float bv = bias ? bias[gc] : 0.f;
#pragma unroll
    for (int mt = 0; mt < 4; ++mt) {
      int rbase = bm + wm + mt * 16 + quad * 4;
#pragma unroll
      for (int r = 0; r < 4; ++r) {
        int gr = rbase + r;
        if (gr < M) {
          float o = acc[mt][nt][r] + bv;
          if (relu) o = fmaxf(o, 0.f);
          if (outbf) Cb[(size_t)gr * ldc + gc] = (__bf16)o;
          else       C[(size_t)gr * ldc + gc] = o;
        }
      }
    }
  }
}

// ---------------------------------------------------------------------------
// Fused Wo-GEMM + residual + LayerNorm.
// C = agg[M,256] @ wot[256,256]^T; h <- LN(C + h)*g + b (fp32), hb <- bf16.
// BM=32 (M=20000 = 625*32 exactly, no guards), BN=256 (full row per block),
// 2x BK=32 tiles per barrier pair. Waves 2x2: wave = 16 rows x 128 cols.
// Row stats: shfl over 16 lanes + cross-wave via LDS.
// ---------------------------------------------------------------------------
__global__ __launch_bounds__(256) void gemm_wo_ln(
    const __bf16* __restrict__ A,   // agg bf16 [M][256]
    const __bf16* __restrict__ Bt,  // wot [256][256]
    float* __restrict__ h,          // fp32 residual in / LN out
    __bf16* __restrict__ hb,        // bf16 LN out
    const float* __restrict__ g, const float* __restrict__ bb)
{
  __shared__ __align__(16) __bf16 As[2][32 * 32];
  __shared__ __align__(16) __bf16 Bs[2][256 * 32];
  __shared__ float red_s[32][2], red_q[32][2];
  const int tid  = threadIdx.x;
  const int wave = tid >> 6;
  const int lane = tid & 63;
  const int quad  = lane >> 4;
  const int col15 = lane & 15;
  const int bm = blockIdx.x * 32;
  const int wm = (wave >> 1) * 16;
  const int wn = (wave & 1) * 128;
  const int ch = wave & 1;

  // A staging: 128 chunks per tile; tid<128 -> tile0, else tile1
  const int at   = tid >> 7;
  const int ac   = tid & 127;
  const int arow = ac >> 2, aoff = (ac & 3) * 8;
  const __bf16* agp = A + (size_t)(bm + arow) * 256 + aoff;

  f32x4 acc[8];
#pragma unroll
  for (int j = 0; j < 8; ++j) acc[j] = (f32x4){0.f, 0.f, 0.f, 0.f};

  for (int k0 = 0; k0 < 256; k0 += 64) {
    GLDS16(agp + k0 + at * 32, &As[at][ac * 8]);
#pragma unroll
    for (int i = 0; i < 8; ++i) {   // B: 1024 chunks per tile, 2 tiles
      int c = tid + i * 256;
      int t = c >> 10, idx = c & 1023;
      GLDS16(Bt + (size_t)(idx >> 2) * 256 + (idx & 3) * 8 + k0 + t * 32,
             &Bs[t][idx * 8]);
    }
    __syncthreads();
    const int ko = quad * 8;
#pragma unroll
    for (int t = 0; t < 2; ++t) {
      bf16x8 af = *(const bf16x8*)(&As[t][(wm + col15) * 32 + ko]);
#pragma unroll
      for (int nt = 0; nt < 8; ++nt) {
        bf16x8 bfr = *(const bf16x8*)(&Bs[t][(wn + nt * 16 + col15) * 32 + ko]);
        acc[nt] = __builtin_amdgcn_mfma_f32_16x16x32_bf16(af, bfr, acc[nt],
                                                          0, 0, 0);
      }
    }
    __syncthreads();
  }

  // residual add + per-row sum / sumsq (rows lr = wm + quad*4 + r)
#pragma unroll
  for (int r = 0; r < 4; ++r) {
    const int lr = wm + quad * 4 + r;
    const int gr = bm + lr;
    float s = 0.f, q = 0.f;
#pragma unroll
    for (int nt = 0; nt < 8; ++nt) {
      int gc = wn + nt * 16 + col15;
      float x = acc[nt][r] + h[(size_t)gr * 256 + gc];
      acc[nt][r] = x;
      s += x; q += x * x;
    }
    s += __shfl_xor(s, 1); q += __shfl_xor(q, 1);
    s += __shfl_xor(s, 2); q += __shfl_xor(q, 2);
    s += __shfl_xor(s, 4); q += __shfl_xor(q, 4);
    s += __shfl_xor(s, 8); q += __shfl_xor(q, 8);
    if (col15 == 0) { red_s[lr][ch] = s; red_q[lr][ch] = q; }
  }
  __syncthreads();

#pragma unroll
  for (int r = 0; r < 4; ++r) {
    const int lr = wm + quad * 4 + r;
    const int gr = bm + lr;
    float s = red_s[lr][0] + red_s[lr][1];
    float q = red_q[lr][0] + red_q[lr][1];
    float mu  = s * (1.f / 256);
    float var = q * (1.f / 256) - mu * mu;
    float inv = rsqrtf(var + 1e-5f);
#pragma unroll
    for (int nt = 0; nt < 8; ++nt) {
      int gc = wn + nt * 16 + col15;
      float o = (acc[nt][r] - mu) * inv * g[gc] + bb[gc];
      h[(size_t)gr * 256 + gc] = o;
      hb[(size_t)gr * 256 + gc] = (__bf16)o;
    }
  }
}

// ---------------------------------------------------------------------------
// PREP mega-kernel: one dispatch for
//  blocks 0..1023    : 10 weight transposes (fp32->bf16, kv-permuted)
//  blocks 1024..3523 : h init (fp32 copy + bf16 cast)
//  blocks 3524..4773 : dst histogram (cnt pre-zeroed by memset)
// ---------------------------------------------------------------------------
__global__ __launch_bounds__(256) void prep_kernel(
    const float* __restrict__ Wq, const float* __restrict__ Wk,
    const float* __restrict__ Wv, const float* __restrict__ Wo,
    const float* __restrict__ w1, const float* __restrict__ w2,
    __bf16* __restrict__ wqkvt, __bf16* __restrict__ wot,
    __bf16* __restrict__ w1t, __bf16* __restrict__ w2t,
    const float* __restrict__ h_in, float* __restrict__ hbuf,
    __bf16* __restrict__ hb,
    const int* __restrict__ dst, int* __restrict__ cnt)
{
  __shared__ float t[32][33];
  const int b = blockIdx.x;
  if (b >= 3524) {               // ---- histogram ----
    int e = (b - 3524) * 256 + threadIdx.x;
    if (e < NE) atomicAdd(&cnt[dst[e]], 1);
    return;
  }
  if (b >= 1024) {               // ---- h init ----
    int i = ((b - 1024) * 256 + threadIdx.x) * 8;
    if (i >= NN * DIM) return;
    float4 a = *(const float4*)(h_in + i);
    float4 c = *(const float4*)(h_in + i + 4);
    *(float4*)(hbuf + i) = a;
    *(float4*)(hbuf + i + 4) = c;
    __bf16 o[8] = {(__bf16)a.x, (__bf16)a.y, (__bf16)a.z, (__bf16)a.w,
                   (__bf16)c.x, (__bf16)c.y, (__bf16)c.z, (__bf16)c.w};
    *(uint4*)(hb + i) = *(uint4*)o;
    return;
  }
  // ---- weight transposes ----
  const float* src;
  __bf16* dstp;
  int N, Kd, bk, bn, mode = 0;  // mode 0: identity, 1: k-perm, 2: v-perm
  if (b < 512) {
    int m = b >> 6, tt = b & 63;
    bk = (tt & 7) * 32; bn = (tt >> 3) * 32;
    N = 256; Kd = 256;
    int l = m & 1, w = m >> 1;  // w: 0=Wq 1=Wk 2=Wv 3=Wo
    const float* Ws[4] = {Wq, Wk, Wv, Wo};
    src = Ws[w] + (size_t)l * 65536;
    if (w == 3) dstp = wot + (size_t)l * 65536;
    else { dstp = wqkvt + (size_t)l * 196608; mode = (w == 0) ? 0 : w; }
  } else if (b < 768) {
    int tt = b - 512;
    bk = (tt & 7) * 32; bn = (tt >> 3) * 32;
    N = 1024; Kd = 256; src = w1; dstp = w1t;
  } else {
    int tt = b - 768;
    bk = (tt >> 3) * 32; bn = (tt & 7) * 32;
    N = 256; Kd = 1024; src = w2; dstp = w2t;
  }
  const int tx = threadIdx.x & 31, ty = threadIdx.x >> 5;
#pragma unroll
  for (int i = 0; i < 32; i += 8)
    t[ty + i][tx] = src[(size_t)(bk + ty + i) * N + bn + tx];
  __syncthreads();
#pragma unroll
  for (int i = 0; i < 32; i += 8) {
    int n = bn + ty + i;
    int r = (mode == 0) ? n
          : 256 + ((n >> 2) * 8) + (n & 3) + (mode == 2 ? 4 : 0);
    dstp[(size_t)r * Kd + bk + tx] = (__bf16)t[tx][ty + i];
  }
}

// ---------------------------------------------------------------------------
// CSR build: scan (re-zeros cnt for cursor reuse) + scatter.
// ---------------------------------------------------------------------------
__global__ __launch_bounds__(1024) void scan_kernel(
    int* __restrict__ cnt, int* __restrict__ rowstart)
{
  __shared__ int part[1024];
  const int t = threadIdx.x;
  const int CHUNK = (NN + 1023) / 1024;  // 20
  const int base = t * CHUNK;
  int s = 0;
#pragma unroll
  for (int i = 0; i < CHUNK; ++i) {
    int idx = base + i;
    if (idx < NN) s += cnt[idx];
  }
  part[t] = s;
  __syncthreads();
  for (int off = 1; off < 1024; off <<= 1) {
    int v = (t >= off) ? part[t - off] : 0;
    __syncthreads();
    part[t] += v;
    __syncthreads();
  }
  int run = part[t] - s;
#pragma unroll
  for (int i = 0; i < CHUNK; ++i) {
    int idx = base + i;
    if (idx < NN) {
      rowstart[idx] = run;
      run += cnt[idx];
      cnt[idx] = 0;  // reset for scatter's cursor
    }
  }
  if (t == 1023) rowstart[NN] = part[1023];
}

__global__ __launch_bounds__(256) void scatter_kernel(
    const int* __restrict__ dst, const int* __restrict__ rowstart,
    int* __restrict__ cursor, int* __restrict__ eid, int E)
{
  int e = blockIdx.x * blockDim.x + threadIdx.x;
  if (e >= E) return;
  int d = dst[e];
  int pos = atomicAdd(&cursor[d], 1);
  eid[rowstart[d] + pos] = e;
}

// ---------------------------------------------------------------------------
// Fused per-node attention, single pass, one wave per dst node.
// qkv bf16 [NN][768]: q (cols 0..255) + kv-interleaved (cols 256..767).
// ---------------------------------------------------------------------------
__global__ __launch_bounds__(256) void node_attn(
    const __bf16* __restrict__ qkv, const int* __restrict__ src,
    const int* __restrict__ rowstart, const int* __restrict__ eid,
    __bf16* __restrict__ agg)
{
  const int wave = threadIdx.x >> 6;
  const int lane = threadIdx.x & 63;
  const int d = blockIdx.x * 4 + wave;
  if (d >= NN) return;
  const int beg = rowstart[d], end = rowstart[d + 1];

  float qf0, qf1, qf2, qf3;
  {
    bf16x4 q4 = *(const bf16x4*)(qkv + (size_t)d * 768 + lane * 4);
    qf0 = (float)q4[0]; qf1 = (float)q4[1];
    qf2 = (float)q4[2]; qf3 = (float)q4[3];
  }
  const float scale = 0.17677669529663687f;  // 1/sqrt(32)
  float z = 0.f;
  float a0 = 0.f, a1 = 0.f, a2 = 0.f, a3 = 0.f;

  for (int c = beg; c < end; c += 64) {
    const int n = min(64, end - c);
    const int myi = c + lane;
    const int s_l = (myi < end) ? src[eid[myi]] : 0;

    int s = __shfl(s_l, 0);
    bf16x8 kv = *(const bf16x8*)(qkv + (size_t)s * 768 + 256 + lane * 8);
    for (int i = 0; i < n; ++i) {
      bf16x8 kvn = kv;
      if (i + 1 < n) {
        int sn = __shfl(s_l, i + 1);
        kvn = *(const bf16x8*)(qkv + (size_t)sn * 768 + 256 + lane * 8);
      }
      float p = qf0 * (float)kv[0] + qf1 * (float)kv[1] +
                qf2 * (float)kv[2] + qf3 * (float)kv[3];
      p += __shfl_xor(p, 1);
      p += __shfl_xor(p, 2);
      p += __shfl_xor(p, 4);
      float a = __expf(p * scale);
      z += a;
      a0 += a * (float)kv[4];
      a1 += a * (float)kv[5];
      a2 += a * (float)kv[6];
      a3 += a * (float)kv[7];
      kv = kvn;
    }
  }
  const float inv = 1.f / (z + 1e-9f);
  __bf16 o[4] = {(__bf16)(a0 * inv), (__bf16)(a1 * inv),
                 (__bf16)(a2 * inv), (__bf16)(a3 * inv)};
  *(uint2*)(agg + (size_t)d * DIM + lane * 4) = *(uint2*)o;
}

// ---------------------------------------------------------------------------
extern "C" void kernel_launch(void* const* d_in, const int* in_sizes, int n_in,
                              void* d_out, int out_size, void* d_ws, size_t ws_size,
                              hipStream_t stream)
{
  const float* h_in = (const float*)d_in[0];
  const int*   src  = (const int*)d_in[1];
  const int*   dst  = (const int*)d_in[2];
  const float* Wq   = (const float*)d_in[3];
  const float* Wk   = (const float*)d_in[4];
  const float* Wv   = (const float*)d_in[5];
  const float* Wo   = (const float*)d_in[6];
  const float* ln_g = (const float*)d_in[7];
  const float* ln_b = (const float*)d_in[8];
  const float* w1   = (const float*)d_in[9];
  const float* b1   = (const float*)d_in[10];
  const float* w2   = (const float*)d_in[11];
  const float* b2   = (const float*)d_in[12];
  float* out = (float*)d_out;

  // workspace layout (fp32-equivalent units)
  float*  ws   = (float*)d_ws;
  float*  hbuf = ws;                                  // NN*DIM fp32
  float*  big  = hbuf + (size_t)NN * DIM;             // 15.36M floats
  __bf16* hbf  = (__bf16*)(big + (size_t)NN * 768);   // NN*DIM bf16
  __bf16* wbf  = hbf + (size_t)NN * DIM;              // 1.05M bf16
  int*    cnt      = (int*)(wbf + 1048576);           // NN
  int*    rowstart = cnt + NN;                        // NN+1
  int*    eid      = rowstart + NN + 1;               // NE

  __bf16* qkvb = (__bf16*)big;               // NN*768 bf16
  __bf16* ffnb = (__bf16*)big;               // NN*HUS bf16 (FFN hidden)

  __bf16* wqkvt = wbf;                       // 2 x [768][256] (kv permuted)
  __bf16* wot   = wqkvt + 2 * 768 * 256;     // 2 x [256][256]
  __bf16* w1t   = wot + 2 * 256 * 256;       // [1024][256]
  __bf16* w2t   = w1t + 1024 * 256;          // [256][1024]

  const dim3 blk(256);
  const int  g_node = (NN + 3) / 4;

  // prep: memset + mega-prep (transposes | h-init | hist) + scan + scatter
  hipMemsetAsync(cnt, 0, NN * sizeof(int), stream);
  prep_kernel<<<4774, blk, 0, stream>>>(Wq, Wk, Wv, Wo, w1, w2,
                                        wqkvt, wot, w1t, w2t,
                                        h_in, hbuf, hbf, dst, cnt);
  scan_kernel<<<1, 1024, 0, stream>>>(cnt, rowstart);
  scatter_kernel<<<(NE + 255) / 256, blk, 0, stream>>>(
      dst, rowstart, cnt, eid, NE);

  const dim3 g_qkv(6, (NN + 127) / 128);   // N=768
  const dim3 g_ffn1(8, (NN + 127) / 128);  // N=1024
  const dim3 g_ffn2(2, (NN + 127) / 128);  // N=256
  const int  g_woln = NN / 32;             // 625 blocks (exact)

  for (int l = 0; l < NLAYER; ++l) {
    // fused q|kv projection -> bf16 qkv (ld 768), kv lane-interleaved
    gemm_bf16_t<128, 0><<<g_qkv, blk, 0, stream>>>(
        hbf, DIM, wqkvt + (size_t)l * 196608, DIM, (float*)qkvb, 768,
        nullptr, NN, 768, DIM, 0, 1);

    // single-pass attention; agg -> bf16 into hbf
    node_attn<<<g_node, blk, 0, stream>>>(qkvb, src, rowstart, eid, hbf);

    // fused Wo-GEMM + residual + LN -> hbuf (fp32) + hbf (bf16)
    gemm_wo_ln<<<g_woln, blk, 0, stream>>>(
        hbf, wot + (size_t)l * 65536, hbuf, hbf,
        ln_g + l * DIM, ln_b + l * DIM);
  }

  // FFN1: relu(h@w1+b1) -> bf16 hidden
  gemm_bf16_t<128, 1><<<g_ffn1, blk, 0, stream>>>(
      hbf, DIM, w1t, DIM, (float*)ffnb, HUS, b1, NN, HUS, DIM, 1, 1);
  // FFN2: hidden @ w2 + b2 -> out (fp32)
  gemm_bf16_t<128, 2><<<g_ffn2, blk, 0, stream>>>(
      ffnb, HUS, w2t, HUS, out, DIM, b2, NN, DIM, HUS, 0, 0);
}

// Round 8
// 380.064 us; speedup vs baseline: 8.4429x; 1.1364x over previous
//
#include <hip/hip_runtime.h>
#include <cstddef>

// Problem constants (from reference)
#define NN 20000      // nodes
#define NE 320000     // edges
#define DIM 256       // model dim
#define NHEAD 8
#define DHEAD 32      // DK == DV == 32
#define NLAYER 2
#define HUS 1024

typedef __bf16 bf16x8 __attribute__((ext_vector_type(8)));
typedef __bf16 bf16x4 __attribute__((ext_vector_type(4)));
typedef float  f32x4  __attribute__((ext_vector_type(4)));

// async global->LDS, 16B per lane; LDS dest must be wave-uniform base + lane*16
#define GLDS16(g, l) __builtin_amdgcn_global_load_lds(                        \
    (const __attribute__((address_space(1))) void*)(g),                       \
    (__attribute__((address_space(3))) void*)(l), 16, 0, 0)

// ---------------------------------------------------------------------------
// bf16 MFMA GEMM: C[M,N] = A[M,K] @ Bt[N,K]^T  (A, Bt bf16 row-major)
// BM=128, BN=128, 256 threads = 4 waves 2x2; 2x BK=32 tiles per barrier.
// EPILOGUE: LDS-restaged. MFMA C/D layout (col=lane&15, row=quad*4+reg)
// scatters 2B/4B stores in 32B strips -> HBM RMW (~2x write amp, measured
// 77MB written for 41MB logical in R7). Instead each wave stages its
// 16x64 fp32 quarter into LDS (stride 68 floats -> 2-way banks = free),
// reads back row-contiguous, stores 16B/lane coalesced.
// ---------------------------------------------------------------------------
template <int TAG>
__global__ __launch_bounds__(256) void gemm_bf16_t(
    const __bf16* __restrict__ A, int lda,
    const __bf16* __restrict__ Bt, int ldb,
    float* __restrict__ C, int ldc,
    const float* __restrict__ bias,
    int M, int N, int K, int relu, int outbf)
{
  __shared__ __align__(16) __bf16 smem[2][256 * 32];  // [t][As(128*32)|Bs(128*32)]
  const int tid  = threadIdx.x;
  const int wave = tid >> 6;
  const int lane = tid & 63;
  const int bm = blockIdx.y * 128;
  const int bn = blockIdx.x * 128;
  const int wm = (wave >> 1) * 64;
  const int wn = (wave & 1) * 64;
  const int quad  = lane >> 4;
  const int col15 = lane & 15;

  // A staging per 32-tile: 512 chunks of 16B, 2/thread
  const int ar1 = tid >> 2, ao1 = (tid & 3) * 8;
  const int ar2 = (tid + 256) >> 2, ao2 = ((tid + 256) & 3) * 8;
  const bool mok1 = (bm + ar1) < M;
  const bool mok2 = (bm + ar2) < M;
  const __bf16* ag1 = A + (size_t)(bm + ar1) * lda + ao1;
  const __bf16* ag2 = A + (size_t)(bm + ar2) * lda + ao2;

  f32x4 acc[4][4];
#pragma unroll
  for (int i = 0; i < 4; ++i)
#pragma unroll
    for (int j = 0; j < 4; ++j) acc[i][j] = (f32x4){0.f, 0.f, 0.f, 0.f};

  for (int k0 = 0; k0 < K; k0 += 64) {
#pragma unroll
    for (int t = 0; t < 2; ++t) {
      if (mok1) GLDS16(ag1 + k0 + t * 32, &smem[t][tid * 8]);
      if (mok2) GLDS16(ag2 + k0 + t * 32, &smem[t][(tid + 256) * 8]);
#pragma unroll
      for (int i = 0; i < 2; ++i) {   // B: 512 chunks per tile
        int c = tid + i * 256;
        GLDS16(Bt + (size_t)(bn + (c >> 2)) * ldb + (c & 3) * 8 + k0 + t * 32,
               &smem[t][4096 + c * 8]);
      }
    }
    __syncthreads();

    const int ko = quad * 8;
#pragma unroll
    for (int t = 0; t < 2; ++t) {
      bf16x8 af[4], bfr[4];
#pragma unroll
      for (int mt = 0; mt < 4; ++mt)
        af[mt] = *(const bf16x8*)(&smem[t][(wm + mt * 16 + col15) * 32 + ko]);
#pragma unroll
      for (int nt = 0; nt < 4; ++nt)
        bfr[nt] = *(const bf16x8*)(
            &smem[t][4096 + (wn + nt * 16 + col15) * 32 + ko]);
#pragma unroll
      for (int mt = 0; mt < 4; ++mt)
#pragma unroll
        for (int nt = 0; nt < 4; ++nt)
          acc[mt][nt] = __builtin_amdgcn_mfma_f32_16x16x32_bf16(
              af[mt], bfr[nt], acc[mt][nt], 0, 0, 0);
    }
    __syncthreads();
  }

  // ---- LDS-restaged epilogue ----
  float bv[4];
#pragma unroll
  for (int nt = 0; nt < 4; ++nt)
    bv[nt] = bias ? bias[bn + wn + nt * 16 + col15] : 0.f;

  float* stg = ((float*)&smem[0][0]) + wave * 2048;  // 8 KB/wave
  __bf16* Cb = (__bf16*)C;

#pragma unroll
  for (int mt = 0; mt < 4; ++mt) {
    __syncthreads();  // prior quarter's reads complete (uniform across waves)
#pragma unroll
    for (int nt = 0; nt < 4; ++nt)
#pragma unroll
      for (int r = 0; r < 4; ++r) {
        float o = acc[mt][nt][r] + bv[nt];
        if (relu) o = fmaxf(o, 0.f);
        stg[(quad * 4 + r) * 68 + nt * 16 + col15] = o;
      }
    // same-wave LDS write->read: DS pipe is in-order per wave
    const int rbase = bm + wm + mt * 16;
    if (outbf) {
#pragma unroll
      for (int it = 0; it < 2; ++it) {
        int t = it * 64 + lane;
        int row = t >> 3, cg = t & 7;
        int gr = rbase + row;
        if (gr < M) {
          f32x4 x = *(const f32x4*)(stg + row * 68 + cg * 8);
          f32x4 y = *(const f32x4*)(stg + row * 68 + cg * 8 + 4);
          __bf16 o8[8] = {(__bf16)x[0], (__bf16)x[1], (__bf16)x[2], (__bf16)x[3],
                          (__bf16)y[0], (__bf16)y[1], (__bf16)y[2], (__bf16)y[3]};
          *(uint4*)(Cb + (size_t)gr * ldc + bn + wn + cg * 8) = *(uint4*)o8;
        }
      }
    } else {
#pragma unroll
      for (int it = 0; it < 4; ++it) {
        int t = it * 64 + lane;
        int row = t >> 4, cg = t & 15;
        int gr = rbase + row;
        if (gr < M) {
          f32x4 x = *(const f32x4*)(stg + row * 68 + cg * 4);
          *(f32x4*)(C + (size_t)gr * ldc + bn + wn + cg * 4) = x;
        }
      }
    }
  }
}

// ---------------------------------------------------------------------------
// Fused Wo-GEMM + residual + LayerNorm, LDS-restaged output.
// C = agg[M,256] @ wot[256,256]^T; h <- LN(C + h)*g + b (fp32), hb <- bf16.
// BM=32 (M = 625*32 exactly), BN=256; 2x BK=32 per barrier pair.
// Output staged as 32 x 256 fp32 (stride 260) then full-row coalesced stores.
// ---------------------------------------------------------------------------
__global__ __launch_bounds__(256) void gemm_wo_ln(
    const __bf16* __restrict__ A,   // agg bf16 [M][256]
    const __bf16* __restrict__ Bt,  // wot [256][256]
    float* __restrict__ h,          // fp32 residual in / LN out
    __bf16* __restrict__ hb,        // bf16 LN out
    const float* __restrict__ g, const float* __restrict__ bb)
{
  __shared__ __align__(16) __bf16 smem[2][288 * 32];  // [t][As(32*32)|Bs(256*32)]
  __shared__ float red_s[32][2], red_q[32][2];
  const int tid  = threadIdx.x;
  const int wave = tid >> 6;
  const int lane = tid & 63;
  const int quad  = lane >> 4;
  const int col15 = lane & 15;
  const int bm = blockIdx.x * 32;
  const int wm = (wave >> 1) * 16;
  const int wn = (wave & 1) * 128;
  const int ch = wave & 1;

  const int at   = tid >> 7;
  const int ac   = tid & 127;
  const int arow = ac >> 2, aoff = (ac & 3) * 8;
  const __bf16* agp = A + (size_t)(bm + arow) * 256 + aoff;

  f32x4 acc[8];
#pragma unroll
  for (int j = 0; j < 8; ++j) acc[j] = (f32x4){0.f, 0.f, 0.f, 0.f};

  for (int k0 = 0; k0 < 256; k0 += 64) {
    GLDS16(agp + k0 + at * 32, &smem[at][ac * 8]);
#pragma unroll
    for (int i = 0; i < 8; ++i) {   // B: 1024 chunks per tile, 2 tiles
      int c = tid + i * 256;
      int t = c >> 10, idx = c & 1023;
      GLDS16(Bt + (size_t)(idx >> 2) * 256 + (idx & 3) * 8 + k0 + t * 32,
             &smem[t][1024 + idx * 8]);
    }
    __syncthreads();
    const int ko = quad * 8;
#pragma unroll
    for (int t = 0; t < 2; ++t) {
      bf16x8 af = *(const bf16x8*)(&smem[t][(wm + col15) * 32 + ko]);
#pragma unroll
      for (int nt = 0; nt < 8; ++nt) {
        bf16x8 bfr = *(const bf16x8*)(
            &smem[t][1024 + (wn + nt * 16 + col15) * 32 + ko]);
        acc[nt] = __builtin_amdgcn_mfma_f32_16x16x32_bf16(af, bfr, acc[nt],
                                                          0, 0, 0);
      }
    }
    __syncthreads();
  }

  // residual add + per-row sum / sumsq (rows lr = wm + quad*4 + r)
#pragma unroll
  for (int r = 0; r < 4; ++r) {
    const int lr = wm + quad * 4 + r;
    const int gr = bm + lr;
    float s = 0.f, q = 0.f;
#pragma unroll
    for (int nt = 0; nt < 8; ++nt) {
      int gc = wn + nt * 16 + col15;
      float x = acc[nt][r] + h[(size_t)gr * 256 + gc];
      acc[nt][r] = x;
      s += x; q += x * x;
    }
    s += __shfl_xor(s, 1); q += __shfl_xor(q, 1);
    s += __shfl_xor(s, 2); q += __shfl_xor(q, 2);
    s += __shfl_xor(s, 4); q += __shfl_xor(q, 4);
    s += __shfl_xor(s, 8); q += __shfl_xor(q, 8);
    if (col15 == 0) { red_s[lr][ch] = s; red_q[lr][ch] = q; }
  }
  __syncthreads();

  // LN -> stage (As/Bs dead; 32 x 256 fp32, stride 260)
  float* stg = (float*)&smem[0][0];
#pragma unroll
  for (int r = 0; r < 4; ++r) {
    const int lr = wm + quad * 4 + r;
    float s = red_s[lr][0] + red_s[lr][1];
    float q = red_q[lr][0] + red_q[lr][1];
    float mu  = s * (1.f / 256);
    float var = q * (1.f / 256) - mu * mu;
    float inv = rsqrtf(var + 1e-5f);
#pragma unroll
    for (int nt = 0; nt < 8; ++nt) {
      int gc = wn + nt * 16 + col15;
      stg[lr * 260 + gc] = (acc[nt][r] - mu) * inv * g[gc] + bb[gc];
    }
  }
  __syncthreads();

  // coalesced write-out: fp32 h (full 1KB rows) + bf16 hb (512B rows)
#pragma unroll
  for (int it = 0; it < 8; ++it) {
    int t = it * 256 + tid;
    int row = t >> 6, cg = t & 63;
    f32x4 x = *(const f32x4*)(stg + row * 260 + cg * 4);
    *(f32x4*)(h + (size_t)(bm + row) * 256 + cg * 4) = x;
  }
#pragma unroll
  for (int it = 0; it < 4; ++it) {
    int t = it * 256 + tid;
    int row = t >> 5, cg = t & 31;
    f32x4 x = *(const f32x4*)(stg + row * 260 + cg * 8);
    f32x4 y = *(const f32x4*)(stg + row * 260 + cg * 8 + 4);
    __bf16 o8[8] = {(__bf16)x[0], (__bf16)x[1], (__bf16)x[2], (__bf16)x[3],
                    (__bf16)y[0], (__bf16)y[1], (__bf16)y[2], (__bf16)y[3]};
    *(uint4*)(hb + (size_t)(bm + row) * 256 + cg * 8) = *(uint4*)o8;
  }
}

// ---------------------------------------------------------------------------
// PREP mega-kernel: one dispatch for
//  blocks 0..1023    : 10 weight transposes (fp32->bf16, kv-permuted)
//  blocks 1024..3523 : h init (fp32 copy + bf16 cast)
//  blocks 3524..4773 : dst histogram (cnt pre-zeroed by memset)
// ---------------------------------------------------------------------------
__global__ __launch_bounds__(256) void prep_kernel(
    const float* __restrict__ Wq, const float* __restrict__ Wk,
    const float* __restrict__ Wv, const float* __restrict__ Wo,
    const float* __restrict__ w1, const float* __restrict__ w2,
    __bf16* __restrict__ wqkvt, __bf16* __restrict__ wot,
    __bf16* __restrict__ w1t, __bf16* __restrict__ w2t,
    const float* __restrict__ h_in, float* __restrict__ hbuf,
    __bf16* __restrict__ hb,
    const int* __restrict__ dst, int* __restrict__ cnt)
{
  __shared__ float t[32][33];
  const int b = blockIdx.x;
  if (b >= 3524) {               // ---- histogram ----
    int e = (b - 3524) * 256 + threadIdx.x;
    if (e < NE) atomicAdd(&cnt[dst[e]], 1);
    return;
  }
  if (b >= 1024) {               // ---- h init ----
    int i = ((b - 1024) * 256 + threadIdx.x) * 8;
    if (i >= NN * DIM) return;
    float4 a = *(const float4*)(h_in + i);
    float4 c = *(const float4*)(h_in + i + 4);
    *(float4*)(hbuf + i) = a;
    *(float4*)(hbuf + i + 4) = c;
    __bf16 o[8] = {(__bf16)a.x, (__bf16)a.y, (__bf16)a.z, (__bf16)a.w,
                   (__bf16)c.x, (__bf16)c.y, (__bf16)c.z, (__bf16)c.w};
    *(uint4*)(hb + i) = *(uint4*)o;
    return;
  }
  // ---- weight transposes ----
  const float* src;
  __bf16* dstp;
  int N, Kd, bk, bn, mode = 0;  // mode 0: identity, 1: k-perm, 2: v-perm
  if (b < 512) {
    int m = b >> 6, tt = b & 63;
    bk = (tt & 7) * 32; bn = (tt >> 3) * 32;
    N = 256; Kd = 256;
    int l = m & 1, w = m >> 1;  // w: 0=Wq 1=Wk 2=Wv 3=Wo
    const float* Ws[4] = {Wq, Wk, Wv, Wo};
    src = Ws[w] + (size_t)l * 65536;
    if (w == 3) dstp = wot + (size_t)l * 65536;
    else { dstp = wqkvt + (size_t)l * 196608; mode = (w == 0) ? 0 : w; }
  } else if (b < 768) {
    int tt = b - 512;
    bk = (tt & 7) * 32; bn = (tt >> 3) * 32;
    N = 1024; Kd = 256; src = w1; dstp = w1t;
  } else {
    int tt = b - 768;
    bk = (tt >> 3) * 32; bn = (tt & 7) * 32;
    N = 256; Kd = 1024; src = w2; dstp = w2t;
  }
  const int tx = threadIdx.x & 31, ty = threadIdx.x >> 5;
#pragma unroll
  for (int i = 0; i < 32; i += 8)
    t[ty + i][tx] = src[(size_t)(bk + ty + i) * N + bn + tx];
  __syncthreads();
#pragma unroll
  for (int i = 0; i < 32; i += 8) {
    int n = bn + ty + i;
    int r = (mode == 0) ? n
          : 256 + ((n >> 2) * 8) + (n & 3) + (mode == 2 ? 4 : 0);
    dstp[(size_t)r * Kd + bk + tx] = (__bf16)t[tx][ty + i];
  }
}

// ---------------------------------------------------------------------------
// CSR build: scan (re-zeros cnt for cursor reuse) + scatter.
// ---------------------------------------------------------------------------
__global__ __launch_bounds__(1024) void scan_kernel(
    int* __restrict__ cnt, int* __restrict__ rowstart)
{
  __shared__ int part[1024];
  const int t = threadIdx.x;
  const int CHUNK = (NN + 1023) / 1024;  // 20
  const int base = t * CHUNK;
  int s = 0;
#pragma unroll
  for (int i = 0; i < CHUNK; ++i) {
    int idx = base + i;
    if (idx < NN) s += cnt[idx];
  }
  part[t] = s;
  __syncthreads();
  for (int off = 1; off < 1024; off <<= 1) {
    int v = (t >= off) ? part[t - off] : 0;
    __syncthreads();
    part[t] += v;
    __syncthreads();
  }
  int run = part[t] - s;
#pragma unroll
  for (int i = 0; i < CHUNK; ++i) {
    int idx = base + i;
    if (idx < NN) {
      rowstart[idx] = run;
      run += cnt[idx];
      cnt[idx] = 0;  // reset for scatter's cursor
    }
  }
  if (t == 1023) rowstart[NN] = part[1023];
}

__global__ __launch_bounds__(256) void scatter_kernel(
    const int* __restrict__ dst, const int* __restrict__ rowstart,
    int* __restrict__ cursor, int* __restrict__ eid, int E)
{
  int e = blockIdx.x * blockDim.x + threadIdx.x;
  if (e >= E) return;
  int d = dst[e];
  int pos = atomicAdd(&cursor[d], 1);
  eid[rowstart[d] + pos] = e;
}

// ---------------------------------------------------------------------------
// Fused per-node attention, single pass, one wave per dst node.
// qkv bf16 [NN][768]: q (cols 0..255) + kv-interleaved (cols 256..767).
// ---------------------------------------------------------------------------
__global__ __launch_bounds__(256) void node_attn(
    const __bf16* __restrict__ qkv, const int* __restrict__ src,
    const int* __restrict__ rowstart, const int* __restrict__ eid,
    __bf16* __restrict__ agg)
{
  const int wave = threadIdx.x >> 6;
  const int lane = threadIdx.x & 63;
  const int d = blockIdx.x * 4 + wave;
  if (d >= NN) return;
  const int beg = rowstart[d], end = rowstart[d + 1];

  float qf0, qf1, qf2, qf3;
  {
    bf16x4 q4 = *(const bf16x4*)(qkv + (size_t)d * 768 + lane * 4);
    qf0 = (float)q4[0]; qf1 = (float)q4[1];
    qf2 = (float)q4[2]; qf3 = (float)q4[3];
  }
  const float scale = 0.17677669529663687f;  // 1/sqrt(32)
  float z = 0.f;
  float a0 = 0.f, a1 = 0.f, a2 = 0.f, a3 = 0.f;

  for (int c = beg; c < end; c += 64) {
    const int n = min(64, end - c);
    const int myi = c + lane;
    const int s_l = (myi < end) ? src[eid[myi]] : 0;

    int s = __shfl(s_l, 0);
    bf16x8 kv = *(const bf16x8*)(qkv + (size_t)s * 768 + 256 + lane * 8);
    for (int i = 0; i < n; ++i) {
      bf16x8 kvn = kv;
      if (i + 1 < n) {
        int sn = __shfl(s_l, i + 1);
        kvn = *(const bf16x8*)(qkv + (size_t)sn * 768 + 256 + lane * 8);
      }
      float p = qf0 * (float)kv[0] + qf1 * (float)kv[1] +
                qf2 * (float)kv[2] + qf3 * (float)kv[3];
      p += __shfl_xor(p, 1);
      p += __shfl_xor(p, 2);
      p += __shfl_xor(p, 4);
      float a = __expf(p * scale);
      z += a;
      a0 += a * (float)kv[4];
      a1 += a * (float)kv[5];
      a2 += a * (float)kv[6];
      a3 += a * (float)kv[7];
      kv = kvn;
    }
  }
  const float inv = 1.f / (z + 1e-9f);
  __bf16 o[4] = {(__bf16)(a0 * inv), (__bf16)(a1 * inv),
                 (__bf16)(a2 * inv), (__bf16)(a3 * inv)};
  *(uint2*)(agg + (size_t)d * DIM + lane * 4) = *(uint2*)o;
}

// ---------------------------------------------------------------------------
extern "C" void kernel_launch(void* const* d_in, const int* in_sizes, int n_in,
                              void* d_out, int out_size, void* d_ws, size_t ws_size,
                              hipStream_t stream)
{
  const float* h_in = (const float*)d_in[0];
  const int*   src  = (const int*)d_in[1];
  const int*   dst  = (const int*)d_in[2];
  const float* Wq   = (const float*)d_in[3];
  const float* Wk   = (const float*)d_in[4];
  const float* Wv   = (const float*)d_in[5];
  const float* Wo   = (const float*)d_in[6];
  const float* ln_g = (const float*)d_in[7];
  const float* ln_b = (const float*)d_in[8];
  const float* w1   = (const float*)d_in[9];
  const float* b1   = (const float*)d_in[10];
  const float* w2   = (const float*)d_in[11];
  const float* b2   = (const float*)d_in[12];
  float* out = (float*)d_out;

  // workspace layout (fp32-equivalent units)
  float*  ws   = (float*)d_ws;
  float*  hbuf = ws;                                  // NN*DIM fp32
  float*  big  = hbuf + (size_t)NN * DIM;             // 15.36M floats
  __bf16* hbf  = (__bf16*)(big + (size_t)NN * 768);   // NN*DIM bf16
  __bf16* wbf  = hbf + (size_t)NN * DIM;              // 1.05M bf16
  int*    cnt      = (int*)(wbf + 1048576);           // NN
  int*    rowstart = cnt + NN;                        // NN+1
  int*    eid      = rowstart + NN + 1;               // NE

  __bf16* qkvb = (__bf16*)big;               // NN*768 bf16
  __bf16* ffnb = (__bf16*)big;               // NN*HUS bf16 (FFN hidden)

  __bf16* wqkvt = wbf;                       // 2 x [768][256] (kv permuted)
  __bf16* wot   = wqkvt + 2 * 768 * 256;     // 2 x [256][256]
  __bf16* w1t   = wot + 2 * 256 * 256;       // [1024][256]
  __bf16* w2t   = w1t + 1024 * 256;          // [256][1024]

  const dim3 blk(256);
  const int  g_node = (NN + 3) / 4;

  // prep: memset + mega-prep (transposes | h-init | hist) + scan + scatter
  hipMemsetAsync(cnt, 0, NN * sizeof(int), stream);
  prep_kernel<<<4774, blk, 0, stream>>>(Wq, Wk, Wv, Wo, w1, w2,
                                        wqkvt, wot, w1t, w2t,
                                        h_in, hbuf, hbf, dst, cnt);
  scan_kernel<<<1, 1024, 0, stream>>>(cnt, rowstart);
  scatter_kernel<<<(NE + 255) / 256, blk, 0, stream>>>(
      dst, rowstart, cnt, eid, NE);

  const dim3 g_qkv(6, (NN + 127) / 128);   // N=768
  const dim3 g_ffn1(8, (NN + 127) / 128);  // N=1024
  const dim3 g_ffn2(2, (NN + 127) / 128);  // N=256
  const int  g_woln = NN / 32;             // 625 blocks (exact)

  for (int l = 0; l < NLAYER; ++l) {
    // fused q|kv projection -> bf16 qkv (ld 768), kv lane-interleaved
    gemm_bf16_t<0><<<g_qkv, blk, 0, stream>>>(
        hbf, DIM, wqkvt + (size_t)l * 196608, DIM, (float*)qkvb, 768,
        nullptr, NN, 768, DIM, 0, 1);

    // single-pass attention; agg -> bf16 into hbf
    node_attn<<<g_node, blk, 0, stream>>>(qkvb, src, rowstart, eid, hbf);

    // fused Wo-GEMM + residual + LN -> hbuf (fp32) + hbf (bf16)
    gemm_wo_ln<<<g_woln, blk, 0, stream>>>(
        hbf, wot + (size_t)l * 65536, hbuf, hbf,
        ln_g + l * DIM, ln_b + l * DIM);
  }

  // FFN1: relu(h@w1+b1) -> bf16 hidden
  gemm_bf16_t<1><<<g_ffn1, blk, 0, stream>>>(
      hbf, DIM, w1t, DIM, (float*)ffnb, HUS, b1, NN, HUS, DIM, 1, 1);
  // FFN2: hidden @ w2 + b2 -> out (fp32)
  gemm_bf16_t<2><<<g_ffn2, blk, 0, stream>>>(
      ffnb, HUS, w2t, HUS, out, DIM, b2, NN, DIM, HUS, 0, 0);
}

// Round 9
// 354.053 us; speedup vs baseline: 9.0631x; 1.0735x over previous
//
#include <hip/hip_runtime.h>
#include <cstddef>

// Problem constants (from reference)
#define NN 20000      // nodes
#define NE 320000     // edges
#define DIM 256       // model dim
#define NHEAD 8
#define DHEAD 32      // DK == DV == 32
#define NLAYER 2
#define HUS 1024

typedef __bf16 bf16x8 __attribute__((ext_vector_type(8)));
typedef __bf16 bf16x4 __attribute__((ext_vector_type(4)));
typedef float  f32x4  __attribute__((ext_vector_type(4)));
typedef float  f32x2  __attribute__((ext_vector_type(2)));

// async global->LDS, 16B per lane; LDS dest must be wave-uniform base + lane*16
#define GLDS16(g, l) __builtin_amdgcn_global_load_lds(                        \
    (const __attribute__((address_space(1))) void*)(g),                       \
    (__attribute__((address_space(3))) void*)(l), 16, 0, 0)

// pack 4 fp32 -> 4 fp8 e4m3 (OCP on gfx950) in one uint
static __device__ inline unsigned pk_fp8x4(f32x4 x) {
  int v = 0;
  v = __builtin_amdgcn_cvt_pk_fp8_f32(x[0], x[1], v, false);
  v = __builtin_amdgcn_cvt_pk_fp8_f32(x[2], x[3], v, true);
  return (unsigned)v;
}

// ---------------------------------------------------------------------------
// bf16 MFMA GEMM: C[M,N] = A[M,K] @ Bt[N,K]^T  (A, Bt bf16 row-major)
// BM = BMT (128 or 64), BN=128, 256 threads = 4 waves 2x2; 2x BK=32 tiles
// per barrier pair. LDS-restaged epilogue (16B/lane coalesced stores).
// outmode: 0 = fp32, 1 = bf16, 2 = qkv-mixed (row = 1024B: 256 bf16 q at
// byte 0, 512 fp8 kv at byte 512; tiles bn<256 -> bf16, bn>=256 -> fp8).
// C/D layout: col = lane&15, row = quad*4 + reg.
// ---------------------------------------------------------------------------
template <int TAG, int BMT>
__global__ __launch_bounds__(256) void gemm_bf16_t(
    const __bf16* __restrict__ A, int lda,
    const __bf16* __restrict__ Bt, int ldb,
    void* __restrict__ C, int ldc,
    const float* __restrict__ bias,
    int M, int N, int K, int relu, int outmode)
{
  constexpr int MT = BMT / 32;            // m-tiles per wave
  constexpr int BOFF = BMT * 32;          // Bs offset (elems) within buffer
  __shared__ __align__(16) __bf16 smem[2][256 * 32];  // 32 KB total
  const int tid  = threadIdx.x;
  const int wave = tid >> 6;
  const int lane = tid & 63;
  const int bm = blockIdx.y * BMT;
  const int bn = blockIdx.x * 128;
  const int wm = (wave >> 1) * (BMT / 2);
  const int wn = (wave & 1) * 64;
  const int quad  = lane >> 4;
  const int col15 = lane & 15;

  // A staging per 32-tile: BMT*4 chunks of 16B
  const int ar1 = tid >> 2, ao1 = (tid & 3) * 8;
  const bool mok1 = (bm + ar1) < M;
  const __bf16* ag1 = A + (size_t)(bm + ar1) * lda + ao1;
  const int ar2 = (tid + 256) >> 2, ao2 = ((tid + 256) & 3) * 8;
  const bool mok2 = (BMT == 128) && ((bm + ar2) < M);
  const __bf16* ag2 = A + (size_t)(bm + ar2) * lda + ao2;

  f32x4 acc[MT][4];
#pragma unroll
  for (int i = 0; i < MT; ++i)
#pragma unroll
    for (int j = 0; j < 4; ++j) acc[i][j] = (f32x4){0.f, 0.f, 0.f, 0.f};

  for (int k0 = 0; k0 < K; k0 += 64) {
#pragma unroll
    for (int t = 0; t < 2; ++t) {
      if (mok1) GLDS16(ag1 + k0 + t * 32, &smem[t][tid * 8]);
      if (BMT == 128) {
        if (mok2) GLDS16(ag2 + k0 + t * 32, &smem[t][(tid + 256) * 8]);
      }
#pragma unroll
      for (int i = 0; i < 2; ++i) {   // B: 512 chunks per tile
        int c = tid + i * 256;
        GLDS16(Bt + (size_t)(bn + (c >> 2)) * ldb + (c & 3) * 8 + k0 + t * 32,
               &smem[t][BOFF + c * 8]);
      }
    }
    __syncthreads();

    const int ko = quad * 8;
#pragma unroll
    for (int t = 0; t < 2; ++t) {
      bf16x8 af[MT], bfr[4];
#pragma unroll
      for (int mt = 0; mt < MT; ++mt)
        af[mt] = *(const bf16x8*)(&smem[t][(wm + mt * 16 + col15) * 32 + ko]);
#pragma unroll
      for (int nt = 0; nt < 4; ++nt)
        bfr[nt] = *(const bf16x8*)(
            &smem[t][BOFF + (wn + nt * 16 + col15) * 32 + ko]);
#pragma unroll
      for (int mt = 0; mt < MT; ++mt)
#pragma unroll
        for (int nt = 0; nt < 4; ++nt)
          acc[mt][nt] = __builtin_amdgcn_mfma_f32_16x16x32_bf16(
              af[mt], bfr[nt], acc[mt][nt], 0, 0, 0);
    }
    __syncthreads();
  }

  // ---- LDS-restaged epilogue ----
  float bv[4];
#pragma unroll
  for (int nt = 0; nt < 4; ++nt)
    bv[nt] = bias ? bias[bn + wn + nt * 16 + col15] : 0.f;

  float* stg = ((float*)&smem[0][0]) + wave * 2048;  // 8 KB/wave

#pragma unroll
  for (int mt = 0; mt < MT; ++mt) {
    __syncthreads();  // uniform; protects smem reuse across quarters
#pragma unroll
    for (int nt = 0; nt < 4; ++nt)
#pragma unroll
      for (int r = 0; r < 4; ++r) {
        float o = acc[mt][nt][r] + bv[nt];
        if (relu) o = fmaxf(o, 0.f);
        stg[(quad * 4 + r) * 68 + nt * 16 + col15] = o;
      }
    const int rbase = bm + wm + mt * 16;
    if (outmode == 0) {                       // fp32 out
      float* Cf = (float*)C;
#pragma unroll
      for (int it = 0; it < 4; ++it) {
        int t = it * 64 + lane;
        int row = t >> 4, cg = t & 15;
        int gr = rbase + row;
        if (gr < M) {
          f32x4 x = *(const f32x4*)(stg + row * 68 + cg * 4);
          *(f32x4*)(Cf + (size_t)gr * ldc + bn + wn + cg * 4) = x;
        }
      }
    } else if (outmode == 1 || bn < 256) {    // bf16 out (ldc in bf16 units)
      __bf16* Cb = (__bf16*)C;
#pragma unroll
      for (int it = 0; it < 2; ++it) {
        int t = it * 64 + lane;
        int row = t >> 3, cg = t & 7;
        int gr = rbase + row;
        if (gr < M) {
          f32x4 x = *(const f32x4*)(stg + row * 68 + cg * 8);
          f32x4 y = *(const f32x4*)(stg + row * 68 + cg * 8 + 4);
          __bf16 o8[8] = {(__bf16)x[0], (__bf16)x[1], (__bf16)x[2], (__bf16)x[3],
                          (__bf16)y[0], (__bf16)y[1], (__bf16)y[2], (__bf16)y[3]};
          *(uint4*)(Cb + (size_t)gr * ldc + bn + wn + cg * 8) = *(uint4*)o8;
        }
      }
    } else {                                   // fp8 kv region of qkv row
      unsigned char* C8 = (unsigned char*)C;
      int row = lane >> 2, cg = lane & 3;      // 16 rows x 4 groups of 16 cols
      int gr = rbase + row;
      if (gr < M) {
        uint4 o;
        o.x = pk_fp8x4(*(const f32x4*)(stg + row * 68 + cg * 16 + 0));
        o.y = pk_fp8x4(*(const f32x4*)(stg + row * 68 + cg * 16 + 4));
        o.z = pk_fp8x4(*(const f32x4*)(stg + row * 68 + cg * 16 + 8));
        o.w = pk_fp8x4(*(const f32x4*)(stg + row * 68 + cg * 16 + 12));
        *(uint4*)(C8 + (size_t)gr * 1024 + 512 + (bn - 256) + wn + cg * 16) = o;
      }
    }
  }
}

// ---------------------------------------------------------------------------
// Fused Wo-GEMM + residual + LayerNorm, LDS-restaged output (unchanged R8).
// ---------------------------------------------------------------------------
__global__ __launch_bounds__(256) void gemm_wo_ln(
    const __bf16* __restrict__ A,   // agg bf16 [M][256]
    const __bf16* __restrict__ Bt,  // wot [256][256]
    float* __restrict__ h,          // fp32 residual in / LN out
    __bf16* __restrict__ hb,        // bf16 LN out
    const float* __restrict__ g, const float* __restrict__ bb)
{
  __shared__ __align__(16) __bf16 smem[2][288 * 32];
  __shared__ float red_s[32][2], red_q[32][2];
  const int tid  = threadIdx.x;
  const int wave = tid >> 6;
  const int lane = tid & 63;
  const int quad  = lane >> 4;
  const int col15 = lane & 15;
  const int bm = blockIdx.x * 32;
  const int wm = (wave >> 1) * 16;
  const int wn = (wave & 1) * 128;
  const int ch = wave & 1;

  const int at   = tid >> 7;
  const int ac   = tid & 127;
  const int arow = ac >> 2, aoff = (ac & 3) * 8;
  const __bf16* agp = A + (size_t)(bm + arow) * 256 + aoff;

  f32x4 acc[8];
#pragma unroll
  for (int j = 0; j < 8; ++j) acc[j] = (f32x4){0.f, 0.f, 0.f, 0.f};

  for (int k0 = 0; k0 < 256; k0 += 64) {
    GLDS16(agp + k0 + at * 32, &smem[at][ac * 8]);
#pragma unroll
    for (int i = 0; i < 8; ++i) {
      int c = tid + i * 256;
      int t = c >> 10, idx = c & 1023;
      GLDS16(Bt + (size_t)(idx >> 2) * 256 + (idx & 3) * 8 + k0 + t * 32,
             &smem[t][1024 + idx * 8]);
    }
    __syncthreads();
    const int ko = quad * 8;
#pragma unroll
    for (int t = 0; t < 2; ++t) {
      bf16x8 af = *(const bf16x8*)(&smem[t][(wm + col15) * 32 + ko]);
#pragma unroll
      for (int nt = 0; nt < 8; ++nt) {
        bf16x8 bfr = *(const bf16x8*)(
            &smem[t][1024 + (wn + nt * 16 + col15) * 32 + ko]);
        acc[nt] = __builtin_amdgcn_mfma_f32_16x16x32_bf16(af, bfr, acc[nt],
                                                          0, 0, 0);
      }
    }
    __syncthreads();
  }

#pragma unroll
  for (int r = 0; r < 4; ++r) {
    const int lr = wm + quad * 4 + r;
    const int gr = bm + lr;
    float s = 0.f, q = 0.f;
#pragma unroll
    for (int nt = 0; nt < 8; ++nt) {
      int gc = wn + nt * 16 + col15;
      float x = acc[nt][r] + h[(size_t)gr * 256 + gc];
      acc[nt][r] = x;
      s += x; q += x * x;
    }
    s += __shfl_xor(s, 1); q += __shfl_xor(q, 1);
    s += __shfl_xor(s, 2); q += __shfl_xor(q, 2);
    s += __shfl_xor(s, 4); q += __shfl_xor(q, 4);
    s += __shfl_xor(s, 8); q += __shfl_xor(q, 8);
    if (col15 == 0) { red_s[lr][ch] = s; red_q[lr][ch] = q; }
  }
  __syncthreads();

  float* stg = (float*)&smem[0][0];
#pragma unroll
  for (int r = 0; r < 4; ++r) {
    const int lr = wm + quad * 4 + r;
    float s = red_s[lr][0] + red_s[lr][1];
    float q = red_q[lr][0] + red_q[lr][1];
    float mu  = s * (1.f / 256);
    float var = q * (1.f / 256) - mu * mu;
    float inv = rsqrtf(var + 1e-5f);
#pragma unroll
    for (int nt = 0; nt < 8; ++nt) {
      int gc = wn + nt * 16 + col15;
      stg[lr * 260 + gc] = (acc[nt][r] - mu) * inv * g[gc] + bb[gc];
    }
  }
  __syncthreads();

#pragma unroll
  for (int it = 0; it < 8; ++it) {
    int t = it * 256 + tid;
    int row = t >> 6, cg = t & 63;
    f32x4 x = *(const f32x4*)(stg + row * 260 + cg * 4);
    *(f32x4*)(h + (size_t)(bm + row) * 256 + cg * 4) = x;
  }
#pragma unroll
  for (int it = 0; it < 4; ++it) {
    int t = it * 256 + tid;
    int row = t >> 5, cg = t & 31;
    f32x4 x = *(const f32x4*)(stg + row * 260 + cg * 8);
    f32x4 y = *(const f32x4*)(stg + row * 260 + cg * 8 + 4);
    __bf16 o8[8] = {(__bf16)x[0], (__bf16)x[1], (__bf16)x[2], (__bf16)x[3],
                    (__bf16)y[0], (__bf16)y[1], (__bf16)y[2], (__bf16)y[3]};
    *(uint4*)(hb + (size_t)(bm + row) * 256 + cg * 8) = *(uint4*)o8;
  }
}

// ---------------------------------------------------------------------------
// PREP mega-kernel (unchanged R8): transposes | h-init | histogram.
// ---------------------------------------------------------------------------
__global__ __launch_bounds__(256) void prep_kernel(
    const float* __restrict__ Wq, const float* __restrict__ Wk,
    const float* __restrict__ Wv, const float* __restrict__ Wo,
    const float* __restrict__ w1, const float* __restrict__ w2,
    __bf16* __restrict__ wqkvt, __bf16* __restrict__ wot,
    __bf16* __restrict__ w1t, __bf16* __restrict__ w2t,
    const float* __restrict__ h_in, float* __restrict__ hbuf,
    __bf16* __restrict__ hb,
    const int* __restrict__ dst, int* __restrict__ cnt)
{
  __shared__ float t[32][33];
  const int b = blockIdx.x;
  if (b >= 3524) {               // ---- histogram ----
    int e = (b - 3524) * 256 + threadIdx.x;
    if (e < NE) atomicAdd(&cnt[dst[e]], 1);
    return;
  }
  if (b >= 1024) {               // ---- h init ----
    int i = ((b - 1024) * 256 + threadIdx.x) * 8;
    if (i >= NN * DIM) return;
    float4 a = *(const float4*)(h_in + i);
    float4 c = *(const float4*)(h_in + i + 4);
    *(float4*)(hbuf + i) = a;
    *(float4*)(hbuf + i + 4) = c;
    __bf16 o[8] = {(__bf16)a.x, (__bf16)a.y, (__bf16)a.z, (__bf16)a.w,
                   (__bf16)c.x, (__bf16)c.y, (__bf16)c.z, (__bf16)c.w};
    *(uint4*)(hb + i) = *(uint4*)o;
    return;
  }
  // ---- weight transposes ----
  const float* src;
  __bf16* dstp;
  int N, Kd, bk, bn, mode = 0;  // 0: identity, 1: k-perm, 2: v-perm
  if (b < 512) {
    int m = b >> 6, tt = b & 63;
    bk = (tt & 7) * 32; bn = (tt >> 3) * 32;
    N = 256; Kd = 256;
    int l = m & 1, w = m >> 1;  // w: 0=Wq 1=Wk 2=Wv 3=Wo
    const float* Ws[4] = {Wq, Wk, Wv, Wo};
    src = Ws[w] + (size_t)l * 65536;
    if (w == 3) dstp = wot + (size_t)l * 65536;
    else { dstp = wqkvt + (size_t)l * 196608; mode = (w == 0) ? 0 : w; }
  } else if (b < 768) {
    int tt = b - 512;
    bk = (tt & 7) * 32; bn = (tt >> 3) * 32;
    N = 1024; Kd = 256; src = w1; dstp = w1t;
  } else {
    int tt = b - 768;
    bk = (tt >> 3) * 32; bn = (tt & 7) * 32;
    N = 256; Kd = 1024; src = w2; dstp = w2t;
  }
  const int tx = threadIdx.x & 31, ty = threadIdx.x >> 5;
#pragma unroll
  for (int i = 0; i < 32; i += 8)
    t[ty + i][tx] = src[(size_t)(bk + ty + i) * N + bn + tx];
  __syncthreads();
#pragma unroll
  for (int i = 0; i < 32; i += 8) {
    int n = bn + ty + i;
    int r = (mode == 0) ? n
          : 256 + ((n >> 2) * 8) + (n & 3) + (mode == 2 ? 4 : 0);
    dstp[(size_t)r * Kd + bk + tx] = (__bf16)t[tx][ty + i];
  }
}

// ---------------------------------------------------------------------------
// CSR build: scan (re-zeros cnt for cursor reuse) + scatter.
// ---------------------------------------------------------------------------
__global__ __launch_bounds__(1024) void scan_kernel(
    int* __restrict__ cnt, int* __restrict__ rowstart)
{
  __shared__ int part[1024];
  const int t = threadIdx.x;
  const int CHUNK = (NN + 1023) / 1024;  // 20
  const int base = t * CHUNK;
  int s = 0;
#pragma unroll
  for (int i = 0; i < CHUNK; ++i) {
    int idx = base + i;
    if (idx < NN) s += cnt[idx];
  }
  part[t] = s;
  __syncthreads();
  for (int off = 1; off < 1024; off <<= 1) {
    int v = (t >= off) ? part[t - off] : 0;
    __syncthreads();
    part[t] += v;
    __syncthreads();
  }
  int run = part[t] - s;
#pragma unroll
  for (int i = 0; i < CHUNK; ++i) {
    int idx = base + i;
    if (idx < NN) {
      rowstart[idx] = run;
      run += cnt[idx];
      cnt[idx] = 0;
    }
  }
  if (t == 1023) rowstart[NN] = part[1023];
}

__global__ __launch_bounds__(256) void scatter_kernel(
    const int* __restrict__ dst, const int* __restrict__ rowstart,
    int* __restrict__ cursor, int* __restrict__ eid, int E)
{
  int e = blockIdx.x * blockDim.x + threadIdx.x;
  if (e >= E) return;
  int d = dst[e];
  int pos = atomicAdd(&cursor[d], 1);
  eid[rowstart[d] + pos] = e;
}

// ---------------------------------------------------------------------------
// Fused per-node attention, single pass, one wave per dst node.
// qkv rows are 1024 B: q = 256 bf16 (bytes 0..511), kv = 512 fp8 e4m3
// (bytes 512..1023, lane's k4|v4 adjacent) -> 8 B/lane per edge (512 B/edge,
// half of R8's bf16). HW cvt_pk_f32_fp8 unpack (same HW as pack: format-
// consistent round trip).
// ---------------------------------------------------------------------------
__global__ __launch_bounds__(256) void node_attn(
    const unsigned char* __restrict__ qkv, const int* __restrict__ src,
    const int* __restrict__ rowstart, const int* __restrict__ eid,
    __bf16* __restrict__ agg)
{
  const int wave = threadIdx.x >> 6;
  const int lane = threadIdx.x & 63;
  const int d = blockIdx.x * 4 + wave;
  if (d >= NN) return;
  const int beg = rowstart[d], end = rowstart[d + 1];

  float qf0, qf1, qf2, qf3;
  {
    bf16x4 q4 = *(const bf16x4*)(qkv + (size_t)d * 1024 + lane * 8);
    qf0 = (float)q4[0]; qf1 = (float)q4[1];
    qf2 = (float)q4[2]; qf3 = (float)q4[3];
  }
  const float scale = 0.17677669529663687f;  // 1/sqrt(32)
  float z = 0.f;
  float a0 = 0.f, a1 = 0.f, a2 = 0.f, a3 = 0.f;

  for (int c = beg; c < end; c += 64) {
    const int n = min(64, end - c);
    const int myi = c + lane;
    const int s_l = (myi < end) ? src[eid[myi]] : 0;

    int s = __shfl(s_l, 0);
    uint2 kv = *(const uint2*)(qkv + (size_t)s * 1024 + 512 + lane * 8);
    for (int i = 0; i < n; ++i) {
      uint2 kvn = kv;
      if (i + 1 < n) {  // prefetch next edge's kv
        int sn = __shfl(s_l, i + 1);
        kvn = *(const uint2*)(qkv + (size_t)sn * 1024 + 512 + lane * 8);
      }
      f32x2 k01 = __builtin_amdgcn_cvt_pk_f32_fp8(kv.x, false);
      f32x2 k23 = __builtin_amdgcn_cvt_pk_f32_fp8(kv.x, true);
      float p = qf0 * k01[0] + qf1 * k01[1] + qf2 * k23[0] + qf3 * k23[1];
      p += __shfl_xor(p, 1);
      p += __shfl_xor(p, 2);
      p += __shfl_xor(p, 4);
      float a = __expf(p * scale);
      f32x2 v01 = __builtin_amdgcn_cvt_pk_f32_fp8(kv.y, false);
      f32x2 v23 = __builtin_amdgcn_cvt_pk_f32_fp8(kv.y, true);
      z += a;
      a0 += a * v01[0];
      a1 += a * v01[1];
      a2 += a * v23[0];
      a3 += a * v23[1];
      kv = kvn;
    }
  }
  const float inv = 1.f / (z + 1e-9f);
  __bf16 o[4] = {(__bf16)(a0 * inv), (__bf16)(a1 * inv),
                 (__bf16)(a2 * inv), (__bf16)(a3 * inv)};
  *(uint2*)(agg + (size_t)d * DIM + lane * 4) = *(uint2*)o;
}

// ---------------------------------------------------------------------------
extern "C" void kernel_launch(void* const* d_in, const int* in_sizes, int n_in,
                              void* d_out, int out_size, void* d_ws, size_t ws_size,
                              hipStream_t stream)
{
  const float* h_in = (const float*)d_in[0];
  const int*   src  = (const int*)d_in[1];
  const int*   dst  = (const int*)d_in[2];
  const float* Wq   = (const float*)d_in[3];
  const float* Wk   = (const float*)d_in[4];
  const float* Wv   = (const float*)d_in[5];
  const float* Wo   = (const float*)d_in[6];
  const float* ln_g = (const float*)d_in[7];
  const float* ln_b = (const float*)d_in[8];
  const float* w1   = (const float*)d_in[9];
  const float* b1   = (const float*)d_in[10];
  const float* w2   = (const float*)d_in[11];
  const float* b2   = (const float*)d_in[12];
  float* out = (float*)d_out;

  // workspace layout (fp32-equivalent units)
  float*  ws   = (float*)d_ws;
  float*  hbuf = ws;                                  // NN*DIM fp32
  float*  big  = hbuf + (size_t)NN * DIM;             // 15.36M floats
  __bf16* hbf  = (__bf16*)(big + (size_t)NN * 768);   // NN*DIM bf16
  __bf16* wbf  = hbf + (size_t)NN * DIM;              // 1.05M bf16
  int*    cnt      = (int*)(wbf + 1048576);           // NN
  int*    rowstart = cnt + NN;                        // NN+1
  int*    eid      = rowstart + NN + 1;               // NE

  unsigned char* qkvb = (unsigned char*)big;  // NN rows x 1024 B (q bf16|kv fp8)
  __bf16* ffnb = (__bf16*)big;                // NN*HUS bf16 (FFN hidden)

  __bf16* wqkvt = wbf;                       // 2 x [768][256] (kv permuted)
  __bf16* wot   = wqkvt + 2 * 768 * 256;     // 2 x [256][256]
  __bf16* w1t   = wot + 2 * 256 * 256;       // [1024][256]
  __bf16* w2t   = w1t + 1024 * 256;          // [256][1024]

  const dim3 blk(256);
  const int  g_node = (NN + 3) / 4;

  // prep: memset + mega-prep (transposes | h-init | hist) + scan + scatter
  hipMemsetAsync(cnt, 0, NN * sizeof(int), stream);
  prep_kernel<<<4774, blk, 0, stream>>>(Wq, Wk, Wv, Wo, w1, w2,
                                        wqkvt, wot, w1t, w2t,
                                        h_in, hbuf, hbf, dst, cnt);
  scan_kernel<<<1, 1024, 0, stream>>>(cnt, rowstart);
  scatter_kernel<<<(NE + 255) / 256, blk, 0, stream>>>(
      dst, rowstart, cnt, eid, NE);

  const dim3 g_qkv(6, (NN + 127) / 128);   // N=768, BM=128
  const dim3 g_ffn1(8, (NN + 127) / 128);  // N=1024, BM=128
  const dim3 g_ffn2(2, (NN + 63) / 64);    // N=256, BM=64 -> 626 blocks
  const int  g_woln = NN / 32;             // 625 blocks (exact)

  for (int l = 0; l < NLAYER; ++l) {
    // fused q|kv projection -> q bf16 + kv fp8, row stride 1024 B
    gemm_bf16_t<0, 128><<<g_qkv, blk, 0, stream>>>(
        hbf, DIM, wqkvt + (size_t)l * 196608, DIM, qkvb, 512,
        nullptr, NN, 768, DIM, 0, 2);

    // single-pass attention; agg -> bf16 into hbf
    node_attn<<<g_node, blk, 0, stream>>>(qkvb, src, rowstart, eid, hbf);

    // fused Wo-GEMM + residual + LN -> hbuf (fp32) + hbf (bf16)
    gemm_wo_ln<<<g_woln, blk, 0, stream>>>(
        hbf, wot + (size_t)l * 65536, hbuf, hbf,
        ln_g + l * DIM, ln_b + l * DIM);
  }

  // FFN1: relu(h@w1+b1) -> bf16 hidden
  gemm_bf16_t<1, 128><<<g_ffn1, blk, 0, stream>>>(
      hbf, DIM, w1t, DIM, ffnb, HUS, b1, NN, HUS, DIM, 1, 1);
  // FFN2: hidden @ w2 + b2 -> out (fp32)
  gemm_bf16_t<2, 64><<<g_ffn2, blk, 0, stream>>>(
      ffnb, HUS, w2t, HUS, out, DIM, b2, NN, DIM, HUS, 0, 0);
}

// Round 10
// 332.400 us; speedup vs baseline: 9.6535x; 1.0651x over previous
//
#include <hip/hip_runtime.h>
#include <cstddef>

// Problem constants (from reference)
#define NN 20000      // nodes
#define NE 320000     // edges
#define DIM 256       // model dim
#define NHEAD 8
#define DHEAD 32      // DK == DV == 32
#define NLAYER 2
#define HUS 1024

typedef __bf16 bf16x8 __attribute__((ext_vector_type(8)));
typedef __bf16 bf16x4 __attribute__((ext_vector_type(4)));
typedef float  f32x4  __attribute__((ext_vector_type(4)));
typedef float  f32x2  __attribute__((ext_vector_type(2)));

// async global->LDS, 16B per lane; LDS dest must be wave-uniform base + lane*16
#define GLDS16(g, l) __builtin_amdgcn_global_load_lds(                        \
    (const __attribute__((address_space(1))) void*)(g),                       \
    (__attribute__((address_space(3))) void*)(l), 16, 0, 0)

// pack 4 fp32 -> 4 fp8 e4m3 (OCP on gfx950) in one uint
static __device__ inline unsigned pk_fp8x4(f32x4 x) {
  int v = 0;
  v = __builtin_amdgcn_cvt_pk_fp8_f32(x[0], x[1], v, false);
  v = __builtin_amdgcn_cvt_pk_fp8_f32(x[2], x[3], v, true);
  return (unsigned)v;
}

// ---------------------------------------------------------------------------
// bf16 MFMA GEMM: C[M,N] = A[M,K] @ Bt[N,K]^T  (A, Bt bf16 row-major)
// BM = BMT (128 or 64), BN=128, 256 threads = 4 waves 2x2; 2x BK=32 tiles
// per barrier pair. LDS-restaged epilogue (16B/lane coalesced stores).
// outmode: 0 = fp32, 1 = bf16, 2 = qkv-mixed (row = 1024B: 256 bf16 q at
// byte 0, 512 fp8 kv at byte 512; tiles bn<256 -> bf16, bn>=256 -> fp8).
// C/D layout: col = lane&15, row = quad*4 + reg.
// ---------------------------------------------------------------------------
template <int TAG, int BMT>
__global__ __launch_bounds__(256) void gemm_bf16_t(
    const __bf16* __restrict__ A, int lda,
    const __bf16* __restrict__ Bt, int ldb,
    void* __restrict__ C, int ldc,
    const float* __restrict__ bias,
    int M, int N, int K, int relu, int outmode)
{
  constexpr int MT = BMT / 32;            // m-tiles per wave
  constexpr int BOFF = BMT * 32;          // Bs offset (elems) within buffer
  __shared__ __align__(16) __bf16 smem[2][256 * 32];  // 32 KB total
  const int tid  = threadIdx.x;
  const int wave = tid >> 6;
  const int lane = tid & 63;
  const int bm = blockIdx.y * BMT;
  const int bn = blockIdx.x * 128;
  const int wm = (wave >> 1) * (BMT / 2);
  const int wn = (wave & 1) * 64;
  const int quad  = lane >> 4;
  const int col15 = lane & 15;

  // A staging per 32-tile: BMT*4 chunks of 16B
  const int ar1 = tid >> 2, ao1 = (tid & 3) * 8;
  const bool mok1 = (bm + ar1) < M;
  const __bf16* ag1 = A + (size_t)(bm + ar1) * lda + ao1;
  const int ar2 = (tid + 256) >> 2, ao2 = ((tid + 256) & 3) * 8;
  const bool mok2 = (BMT == 128) && ((bm + ar2) < M);
  const __bf16* ag2 = A + (size_t)(bm + ar2) * lda + ao2;

  f32x4 acc[MT][4];
#pragma unroll
  for (int i = 0; i < MT; ++i)
#pragma unroll
    for (int j = 0; j < 4; ++j) acc[i][j] = (f32x4){0.f, 0.f, 0.f, 0.f};

  for (int k0 = 0; k0 < K; k0 += 64) {
#pragma unroll
    for (int t = 0; t < 2; ++t) {
      if (mok1) GLDS16(ag1 + k0 + t * 32, &smem[t][tid * 8]);
      if (BMT == 128) {
        if (mok2) GLDS16(ag2 + k0 + t * 32, &smem[t][(tid + 256) * 8]);
      }
#pragma unroll
      for (int i = 0; i < 2; ++i) {   // B: 512 chunks per tile
        int c = tid + i * 256;
        GLDS16(Bt + (size_t)(bn + (c >> 2)) * ldb + (c & 3) * 8 + k0 + t * 32,
               &smem[t][BOFF + c * 8]);
      }
    }
    __syncthreads();

    const int ko = quad * 8;
#pragma unroll
    for (int t = 0; t < 2; ++t) {
      bf16x8 af[MT], bfr[4];
#pragma unroll
      for (int mt = 0; mt < MT; ++mt)
        af[mt] = *(const bf16x8*)(&smem[t][(wm + mt * 16 + col15) * 32 + ko]);
#pragma unroll
      for (int nt = 0; nt < 4; ++nt)
        bfr[nt] = *(const bf16x8*)(
            &smem[t][BOFF + (wn + nt * 16 + col15) * 32 + ko]);
#pragma unroll
      for (int mt = 0; mt < MT; ++mt)
#pragma unroll
        for (int nt = 0; nt < 4; ++nt)
          acc[mt][nt] = __builtin_amdgcn_mfma_f32_16x16x32_bf16(
              af[mt], bfr[nt], acc[mt][nt], 0, 0, 0);
    }
    __syncthreads();
  }

  // ---- LDS-restaged epilogue ----
  float bv[4];
#pragma unroll
  for (int nt = 0; nt < 4; ++nt)
    bv[nt] = bias ? bias[bn + wn + nt * 16 + col15] : 0.f;

  float* stg = ((float*)&smem[0][0]) + wave * 2048;  // 8 KB/wave

#pragma unroll
  for (int mt = 0; mt < MT; ++mt) {
    __syncthreads();  // uniform; protects smem reuse across quarters
#pragma unroll
    for (int nt = 0; nt < 4; ++nt)
#pragma unroll
      for (int r = 0; r < 4; ++r) {
        float o = acc[mt][nt][r] + bv[nt];
        if (relu) o = fmaxf(o, 0.f);
        stg[(quad * 4 + r) * 68 + nt * 16 + col15] = o;
      }
    const int rbase = bm + wm + mt * 16;
    if (outmode == 0) {                       // fp32 out
      float* Cf = (float*)C;
#pragma unroll
      for (int it = 0; it < 4; ++it) {
        int t = it * 64 + lane;
        int row = t >> 4, cg = t & 15;
        int gr = rbase + row;
        if (gr < M) {
          f32x4 x = *(const f32x4*)(stg + row * 68 + cg * 4);
          *(f32x4*)(Cf + (size_t)gr * ldc + bn + wn + cg * 4) = x;
        }
      }
    } else if (outmode == 1 || bn < 256) {    // bf16 out (ldc in bf16 units)
      __bf16* Cb = (__bf16*)C;
#pragma unroll
      for (int it = 0; it < 2; ++it) {
        int t = it * 64 + lane;
        int row = t >> 3, cg = t & 7;
        int gr = rbase + row;
        if (gr < M) {
          f32x4 x = *(const f32x4*)(stg + row * 68 + cg * 8);
          f32x4 y = *(const f32x4*)(stg + row * 68 + cg * 8 + 4);
          __bf16 o8[8] = {(__bf16)x[0], (__bf16)x[1], (__bf16)x[2], (__bf16)x[3],
                          (__bf16)y[0], (__bf16)y[1], (__bf16)y[2], (__bf16)y[3]};
          *(uint4*)(Cb + (size_t)gr * ldc + bn + wn + cg * 8) = *(uint4*)o8;
        }
      }
    } else {                                   // fp8 kv region of qkv row
      unsigned char* C8 = (unsigned char*)C;
      int row = lane >> 2, cg = lane & 3;      // 16 rows x 4 groups of 16 cols
      int gr = rbase + row;
      if (gr < M) {
        uint4 o;
        o.x = pk_fp8x4(*(const f32x4*)(stg + row * 68 + cg * 16 + 0));
        o.y = pk_fp8x4(*(const f32x4*)(stg + row * 68 + cg * 16 + 4));
        o.z = pk_fp8x4(*(const f32x4*)(stg + row * 68 + cg * 16 + 8));
        o.w = pk_fp8x4(*(const f32x4*)(stg + row * 68 + cg * 16 + 12));
        *(uint4*)(C8 + (size_t)gr * 1024 + 512 + (bn - 256) + wn + cg * 16) = o;
      }
    }
  }
}

// ---------------------------------------------------------------------------
// Fused Wo-GEMM + residual + LayerNorm, LDS-restaged output (unchanged).
// ---------------------------------------------------------------------------
__global__ __launch_bounds__(256) void gemm_wo_ln(
    const __bf16* __restrict__ A,   // agg bf16 [M][256]
    const __bf16* __restrict__ Bt,  // wot [256][256]
    float* __restrict__ h,          // fp32 residual in / LN out
    __bf16* __restrict__ hb,        // bf16 LN out
    const float* __restrict__ g, const float* __restrict__ bb)
{
  __shared__ __align__(16) __bf16 smem[2][288 * 32];
  __shared__ float red_s[32][2], red_q[32][2];
  const int tid  = threadIdx.x;
  const int wave = tid >> 6;
  const int lane = tid & 63;
  const int quad  = lane >> 4;
  const int col15 = lane & 15;
  const int bm = blockIdx.x * 32;
  const int wm = (wave >> 1) * 16;
  const int wn = (wave & 1) * 128;
  const int ch = wave & 1;

  const int at   = tid >> 7;
  const int ac   = tid & 127;
  const int arow = ac >> 2, aoff = (ac & 3) * 8;
  const __bf16* agp = A + (size_t)(bm + arow) * 256 + aoff;

  f32x4 acc[8];
#pragma unroll
  for (int j = 0; j < 8; ++j) acc[j] = (f32x4){0.f, 0.f, 0.f, 0.f};

  for (int k0 = 0; k0 < 256; k0 += 64) {
    GLDS16(agp + k0 + at * 32, &smem[at][ac * 8]);
#pragma unroll
    for (int i = 0; i < 8; ++i) {
      int c = tid + i * 256;
      int t = c >> 10, idx = c & 1023;
      GLDS16(Bt + (size_t)(idx >> 2) * 256 + (idx & 3) * 8 + k0 + t * 32,
             &smem[t][1024 + idx * 8]);
    }
    __syncthreads();
    const int ko = quad * 8;
#pragma unroll
    for (int t = 0; t < 2; ++t) {
      bf16x8 af = *(const bf16x8*)(&smem[t][(wm + col15) * 32 + ko]);
#pragma unroll
      for (int nt = 0; nt < 8; ++nt) {
        bf16x8 bfr = *(const bf16x8*)(
            &smem[t][1024 + (wn + nt * 16 + col15) * 32 + ko]);
        acc[nt] = __builtin_amdgcn_mfma_f32_16x16x32_bf16(af, bfr, acc[nt],
                                                          0, 0, 0);
      }
    }
    __syncthreads();
  }

#pragma unroll
  for (int r = 0; r < 4; ++r) {
    const int lr = wm + quad * 4 + r;
    const int gr = bm + lr;
    float s = 0.f, q = 0.f;
#pragma unroll
    for (int nt = 0; nt < 8; ++nt) {
      int gc = wn + nt * 16 + col15;
      float x = acc[nt][r] + h[(size_t)gr * 256 + gc];
      acc[nt][r] = x;
      s += x; q += x * x;
    }
    s += __shfl_xor(s, 1); q += __shfl_xor(q, 1);
    s += __shfl_xor(s, 2); q += __shfl_xor(q, 2);
    s += __shfl_xor(s, 4); q += __shfl_xor(q, 4);
    s += __shfl_xor(s, 8); q += __shfl_xor(q, 8);
    if (col15 == 0) { red_s[lr][ch] = s; red_q[lr][ch] = q; }
  }
  __syncthreads();

  float* stg = (float*)&smem[0][0];
#pragma unroll
  for (int r = 0; r < 4; ++r) {
    const int lr = wm + quad * 4 + r;
    float s = red_s[lr][0] + red_s[lr][1];
    float q = red_q[lr][0] + red_q[lr][1];
    float mu  = s * (1.f / 256);
    float var = q * (1.f / 256) - mu * mu;
    float inv = rsqrtf(var + 1e-5f);
#pragma unroll
    for (int nt = 0; nt < 8; ++nt) {
      int gc = wn + nt * 16 + col15;
      stg[lr * 260 + gc] = (acc[nt][r] - mu) * inv * g[gc] + bb[gc];
    }
  }
  __syncthreads();

#pragma unroll
  for (int it = 0; it < 8; ++it) {
    int t = it * 256 + tid;
    int row = t >> 6, cg = t & 63;
    f32x4 x = *(const f32x4*)(stg + row * 260 + cg * 4);
    *(f32x4*)(h + (size_t)(bm + row) * 256 + cg * 4) = x;
  }
#pragma unroll
  for (int it = 0; it < 4; ++it) {
    int t = it * 256 + tid;
    int row = t >> 5, cg = t & 31;
    f32x4 x = *(const f32x4*)(stg + row * 260 + cg * 8);
    f32x4 y = *(const f32x4*)(stg + row * 260 + cg * 8 + 4);
    __bf16 o8[8] = {(__bf16)x[0], (__bf16)x[1], (__bf16)x[2], (__bf16)x[3],
                    (__bf16)y[0], (__bf16)y[1], (__bf16)y[2], (__bf16)y[3]};
    *(uint4*)(hb + (size_t)(bm + row) * 256 + cg * 8) = *(uint4*)o8;
  }
}

// ---------------------------------------------------------------------------
// PREP mega-kernel (unchanged): transposes | h-init | histogram.
// ---------------------------------------------------------------------------
__global__ __launch_bounds__(256) void prep_kernel(
    const float* __restrict__ Wq, const float* __restrict__ Wk,
    const float* __restrict__ Wv, const float* __restrict__ Wo,
    const float* __restrict__ w1, const float* __restrict__ w2,
    __bf16* __restrict__ wqkvt, __bf16* __restrict__ wot,
    __bf16* __restrict__ w1t, __bf16* __restrict__ w2t,
    const float* __restrict__ h_in, float* __restrict__ hbuf,
    __bf16* __restrict__ hb,
    const int* __restrict__ dst, int* __restrict__ cnt)
{
  __shared__ float t[32][33];
  const int b = blockIdx.x;
  if (b >= 3524) {               // ---- histogram ----
    int e = (b - 3524) * 256 + threadIdx.x;
    if (e < NE) atomicAdd(&cnt[dst[e]], 1);
    return;
  }
  if (b >= 1024) {               // ---- h init ----
    int i = ((b - 1024) * 256 + threadIdx.x) * 8;
    if (i >= NN * DIM) return;
    float4 a = *(const float4*)(h_in + i);
    float4 c = *(const float4*)(h_in + i + 4);
    *(float4*)(hbuf + i) = a;
    *(float4*)(hbuf + i + 4) = c;
    __bf16 o[8] = {(__bf16)a.x, (__bf16)a.y, (__bf16)a.z, (__bf16)a.w,
                   (__bf16)c.x, (__bf16)c.y, (__bf16)c.z, (__bf16)c.w};
    *(uint4*)(hb + i) = *(uint4*)o;
    return;
  }
  // ---- weight transposes ----
  const float* src;
  __bf16* dstp;
  int N, Kd, bk, bn, mode = 0;  // 0: identity, 1: k-perm, 2: v-perm
  if (b < 512) {
    int m = b >> 6, tt = b & 63;
    bk = (tt & 7) * 32; bn = (tt >> 3) * 32;
    N = 256; Kd = 256;
    int l = m & 1, w = m >> 1;  // w: 0=Wq 1=Wk 2=Wv 3=Wo
    const float* Ws[4] = {Wq, Wk, Wv, Wo};
    src = Ws[w] + (size_t)l * 65536;
    if (w == 3) dstp = wot + (size_t)l * 65536;
    else { dstp = wqkvt + (size_t)l * 196608; mode = (w == 0) ? 0 : w; }
  } else if (b < 768) {
    int tt = b - 512;
    bk = (tt & 7) * 32; bn = (tt >> 3) * 32;
    N = 1024; Kd = 256; src = w1; dstp = w1t;
  } else {
    int tt = b - 768;
    bk = (tt >> 3) * 32; bn = (tt & 7) * 32;
    N = 256; Kd = 1024; src = w2; dstp = w2t;
  }
  const int tx = threadIdx.x & 31, ty = threadIdx.x >> 5;
#pragma unroll
  for (int i = 0; i < 32; i += 8)
    t[ty + i][tx] = src[(size_t)(bk + ty + i) * N + bn + tx];
  __syncthreads();
#pragma unroll
  for (int i = 0; i < 32; i += 8) {
    int n = bn + ty + i;
    int r = (mode == 0) ? n
          : 256 + ((n >> 2) * 8) + (n & 3) + (mode == 2 ? 4 : 0);
    dstp[(size_t)r * Kd + bk + tx] = (__bf16)t[tx][ty + i];
  }
}

// ---------------------------------------------------------------------------
// CSR build: scan (re-zeros cnt for cursor reuse) + scatter (stores SRC id
// directly -> node_attn needs no eid->src dependent gather).
// ---------------------------------------------------------------------------
__global__ __launch_bounds__(1024) void scan_kernel(
    int* __restrict__ cnt, int* __restrict__ rowstart)
{
  __shared__ int part[1024];
  const int t = threadIdx.x;
  const int CHUNK = (NN + 1023) / 1024;  // 20
  const int base = t * CHUNK;
  int s = 0;
#pragma unroll
  for (int i = 0; i < CHUNK; ++i) {
    int idx = base + i;
    if (idx < NN) s += cnt[idx];
  }
  part[t] = s;
  __syncthreads();
  for (int off = 1; off < 1024; off <<= 1) {
    int v = (t >= off) ? part[t - off] : 0;
    __syncthreads();
    part[t] += v;
    __syncthreads();
  }
  int run = part[t] - s;
#pragma unroll
  for (int i = 0; i < CHUNK; ++i) {
    int idx = base + i;
    if (idx < NN) {
      rowstart[idx] = run;
      run += cnt[idx];
      cnt[idx] = 0;
    }
  }
  if (t == 1023) rowstart[NN] = part[1023];
}

__global__ __launch_bounds__(256) void scatter_kernel(
    const int* __restrict__ src, const int* __restrict__ dst,
    const int* __restrict__ rowstart,
    int* __restrict__ cursor, int* __restrict__ csrc, int E)
{
  int e = blockIdx.x * blockDim.x + threadIdx.x;
  if (e >= E) return;
  int d = dst[e];
  int pos = atomicAdd(&cursor[d], 1);
  csrc[rowstart[d] + pos] = src[e];
}

// ---------------------------------------------------------------------------
// Fused per-node attention, split-wave: one wave per dst node, two 32-lane
// halves each processing alternate edges (2 independent gather chains/wave).
// qkv rows 1024 B: q bf16 (bytes 0..511), kv fp8 e4m3 (512..1023).
// Lane ln32 owns 16 B of kv = k[8a..+4)|v[8a..+4)|k[8a+4..+4)|v[8a+4..+4),
// a=ln32; head = ln32>>2 (4 lanes/head); q: bf16x8 at byte ln32*16.
// Halves' z/acc combined via shfl_xor(,32); lanes<32 store 16 B bf16 out.
// ---------------------------------------------------------------------------
__global__ __launch_bounds__(256) void node_attn(
    const unsigned char* __restrict__ qkv,
    const int* __restrict__ rowstart, const int* __restrict__ csrc,
    __bf16* __restrict__ agg)
{
  const int wave = threadIdx.x >> 6;
  const int lane = threadIdx.x & 63;
  const int hw   = lane >> 5;
  const int ln32 = lane & 31;
  const int d = blockIdx.x * 4 + wave;
  if (d >= NN) return;
  const int beg = rowstart[d], end = rowstart[d + 1];

  float qf[8];
  {
    bf16x8 q8 = *(const bf16x8*)(qkv + (size_t)d * 1024 + ln32 * 16);
#pragma unroll
    for (int j = 0; j < 8; ++j) qf[j] = (float)q8[j];
  }
  const float scale = 0.17677669529663687f;  // 1/sqrt(32)
  float z = 0.f;
  float ac[8];
#pragma unroll
  for (int j = 0; j < 8; ++j) ac[j] = 0.f;

  for (int c = beg; c < end; c += 64) {
    const int n = min(64, end - c);
    const int myi = c + lane;
    const int s_l = (myi < end) ? csrc[myi] : 0;   // coalesced batch load

    uint4 kv = make_uint4(0u, 0u, 0u, 0u);
    if (hw < n) {
      int s = __shfl(s_l, hw);
      kv = *(const uint4*)(qkv + (size_t)s * 1024 + 512 + ln32 * 16);
    }
    for (int i = hw; i < n; i += 2) {
      uint4 kvn = kv;
      if (i + 2 < n) {  // prefetch this half's next edge
        int sn = __shfl(s_l, i + 2);
        kvn = *(const uint4*)(qkv + (size_t)sn * 1024 + 512 + ln32 * 16);
      }
      f32x2 k01 = __builtin_amdgcn_cvt_pk_f32_fp8(kv.x, false);
      f32x2 k23 = __builtin_amdgcn_cvt_pk_f32_fp8(kv.x, true);
      f32x2 k45 = __builtin_amdgcn_cvt_pk_f32_fp8(kv.z, false);
      f32x2 k67 = __builtin_amdgcn_cvt_pk_f32_fp8(kv.z, true);
      float p = qf[0] * k01[0] + qf[1] * k01[1] + qf[2] * k23[0] +
                qf[3] * k23[1] + qf[4] * k45[0] + qf[5] * k45[1] +
                qf[6] * k67[0] + qf[7] * k67[1];
      p += __shfl_xor(p, 1);
      p += __shfl_xor(p, 2);
      float a = __expf(p * scale);
      z += a;
      f32x2 v01 = __builtin_amdgcn_cvt_pk_f32_fp8(kv.y, false);
      f32x2 v23 = __builtin_amdgcn_cvt_pk_f32_fp8(kv.y, true);
      f32x2 v45 = __builtin_amdgcn_cvt_pk_f32_fp8(kv.w, false);
      f32x2 v67 = __builtin_amdgcn_cvt_pk_f32_fp8(kv.w, true);
      ac[0] += a * v01[0]; ac[1] += a * v01[1];
      ac[2] += a * v23[0]; ac[3] += a * v23[1];
      ac[4] += a * v45[0]; ac[5] += a * v45[1];
      ac[6] += a * v67[0]; ac[7] += a * v67[1];
      kv = kvn;
    }
  }
  // combine halves
  z += __shfl_xor(z, 32);
#pragma unroll
  for (int j = 0; j < 8; ++j) ac[j] += __shfl_xor(ac[j], 32);
  const float inv = 1.f / (z + 1e-9f);
  if (lane < 32) {
    __bf16 o[8];
#pragma unroll
    for (int j = 0; j < 8; ++j) o[j] = (__bf16)(ac[j] * inv);
    *(uint4*)(agg + (size_t)d * DIM + ln32 * 8) = *(uint4*)o;
  }
}

// ---------------------------------------------------------------------------
extern "C" void kernel_launch(void* const* d_in, const int* in_sizes, int n_in,
                              void* d_out, int out_size, void* d_ws, size_t ws_size,
                              hipStream_t stream)
{
  const float* h_in = (const float*)d_in[0];
  const int*   src  = (const int*)d_in[1];
  const int*   dst  = (const int*)d_in[2];
  const float* Wq   = (const float*)d_in[3];
  const float* Wk   = (const float*)d_in[4];
  const float* Wv   = (const float*)d_in[5];
  const float* Wo   = (const float*)d_in[6];
  const float* ln_g = (const float*)d_in[7];
  const float* ln_b = (const float*)d_in[8];
  const float* w1   = (const float*)d_in[9];
  const float* b1   = (const float*)d_in[10];
  const float* w2   = (const float*)d_in[11];
  const float* b2   = (const float*)d_in[12];
  float* out = (float*)d_out;

  // workspace layout (fp32-equivalent units)
  float*  ws   = (float*)d_ws;
  float*  hbuf = ws;                                  // NN*DIM fp32
  float*  big  = hbuf + (size_t)NN * DIM;             // 15.36M floats
  __bf16* hbf  = (__bf16*)(big + (size_t)NN * 768);   // NN*DIM bf16
  __bf16* wbf  = hbf + (size_t)NN * DIM;              // 1.05M bf16
  int*    cnt      = (int*)(wbf + 1048576);           // NN
  int*    rowstart = cnt + NN;                        // NN+1
  int*    csrc     = rowstart + NN + 1;               // NE (src per CSR slot)

  unsigned char* qkvb = (unsigned char*)big;  // NN rows x 1024 B (q bf16|kv fp8)
  __bf16* ffnb = (__bf16*)big;                // NN*HUS bf16 (FFN hidden)

  __bf16* wqkvt = wbf;                       // 2 x [768][256] (kv permuted)
  __bf16* wot   = wqkvt + 2 * 768 * 256;     // 2 x [256][256]
  __bf16* w1t   = wot + 2 * 256 * 256;       // [1024][256]
  __bf16* w2t   = w1t + 1024 * 256;          // [256][1024]

  const dim3 blk(256);
  const int  g_node = (NN + 3) / 4;

  // prep: memset + mega-prep (transposes | h-init | hist) + scan + scatter
  hipMemsetAsync(cnt, 0, NN * sizeof(int), stream);
  prep_kernel<<<4774, blk, 0, stream>>>(Wq, Wk, Wv, Wo, w1, w2,
                                        wqkvt, wot, w1t, w2t,
                                        h_in, hbuf, hbf, dst, cnt);
  scan_kernel<<<1, 1024, 0, stream>>>(cnt, rowstart);
  scatter_kernel<<<(NE + 255) / 256, blk, 0, stream>>>(
      src, dst, rowstart, cnt, csrc, NE);

  const dim3 g_qkv(6, (NN + 127) / 128);   // N=768, BM=128
  const dim3 g_ffn1(8, (NN + 127) / 128);  // N=1024, BM=128
  const dim3 g_ffn2(2, (NN + 63) / 64);    // N=256, BM=64 -> 626 blocks
  const int  g_woln = NN / 32;             // 625 blocks (exact)

  for (int l = 0; l < NLAYER; ++l) {
    // fused q|kv projection -> q bf16 + kv fp8, row stride 1024 B
    gemm_bf16_t<0, 128><<<g_qkv, blk, 0, stream>>>(
        hbf, DIM, wqkvt + (size_t)l * 196608, DIM, qkvb, 512,
        nullptr, NN, 768, DIM, 0, 2);

    // split-wave single-pass attention; agg -> bf16 into hbf
    node_attn<<<g_node, blk, 0, stream>>>(qkvb, rowstart, csrc, hbf);

    // fused Wo-GEMM + residual + LN -> hbuf (fp32) + hbf (bf16)
    gemm_wo_ln<<<g_woln, blk, 0, stream>>>(
        hbf, wot + (size_t)l * 65536, hbuf, hbf,
        ln_g + l * DIM, ln_b + l * DIM);
  }

  // FFN1: relu(h@w1+b1) -> bf16 hidden
  gemm_bf16_t<1, 128><<<g_ffn1, blk, 0, stream>>>(
      hbf, DIM, w1t, DIM, ffnb, HUS, b1, NN, HUS, DIM, 1, 1);
  // FFN2: hidden @ w2 + b2 -> out (fp32)
  gemm_bf16_t<2, 64><<<g_ffn2, blk, 0, stream>>>(
      ffnb, HUS, w2t, HUS, out, DIM, b2, NN, DIM, HUS, 0, 0);
}

// Round 11
// 327.304 us; speedup vs baseline: 9.8038x; 1.0156x over previous
//
#include <hip/hip_runtime.h>
#include <cstddef>

// Problem constants (from reference)
#define NN 20000      // nodes
#define NE 320000     // edges
#define DIM 256       // model dim
#define NHEAD 8
#define DHEAD 32      // DK == DV == 32
#define NLAYER 2
#define HUS 1024

typedef __bf16 bf16x8 __attribute__((ext_vector_type(8)));
typedef __bf16 bf16x4 __attribute__((ext_vector_type(4)));
typedef float  f32x4  __attribute__((ext_vector_type(4)));
typedef float  f32x2  __attribute__((ext_vector_type(2)));

// async global->LDS, 16B per lane; LDS dest must be wave-uniform base + lane*16
#define GLDS16(g, l) __builtin_amdgcn_global_load_lds(                        \
    (const __attribute__((address_space(1))) void*)(g),                       \
    (__attribute__((address_space(3))) void*)(l), 16, 0, 0)

// pack 4 fp32 -> 4 fp8 e4m3 (OCP on gfx950) in one uint
static __device__ inline unsigned pk_fp8x4(f32x4 x) {
  int v = 0;
  v = __builtin_amdgcn_cvt_pk_fp8_f32(x[0], x[1], v, false);
  v = __builtin_amdgcn_cvt_pk_fp8_f32(x[2], x[3], v, true);
  return (unsigned)v;
}

// ---------------------------------------------------------------------------
// bf16 MFMA GEMM: C[M,N] = A[M,K] @ Bt[N,K]^T  (A, Bt bf16 row-major)
// BM = BMT (128 or 64), BN=128, 256 threads = 4 waves 2x2; 2x BK=32 tiles
// per barrier pair. LDS-restaged epilogue (16B/lane coalesced stores).
// XCD swizzle: grid is (8, ceil(mtiles/8)*ntiles); m = bx + 8*(by/ntiles),
// n = by % ntiles. All n-tiles of one m-tile share bx -> same linear%8 ->
// same XCD -> the A-tile is L2-local instead of being re-fetched per XCD.
// outmode: 0 = fp32, 1 = bf16, 2 = qkv-mixed (row = 1024B: 256 bf16 q at
// byte 0, 512 fp8 kv at byte 512; tiles bn<256 -> bf16, bn>=256 -> fp8).
// C/D layout: col = lane&15, row = quad*4 + reg.
// ---------------------------------------------------------------------------
template <int TAG, int BMT>
__global__ __launch_bounds__(256) void gemm_bf16_t(
    const __bf16* __restrict__ A, int lda,
    const __bf16* __restrict__ Bt, int ldb,
    void* __restrict__ C, int ldc,
    const float* __restrict__ bias,
    int M, int N, int K, int relu, int outmode,
    int mtiles, int ntiles)
{
  constexpr int MT = BMT / 32;            // m-tiles per wave
  constexpr int BOFF = BMT * 32;          // Bs offset (elems) within buffer
  const int mblk = blockIdx.x + 8 * (blockIdx.y / ntiles);
  const int nblk = blockIdx.y % ntiles;
  if (mblk >= mtiles) return;             // uniform early-out (idle pad blocks)
  __shared__ __align__(16) __bf16 smem[2][256 * 32];  // 32 KB total
  const int tid  = threadIdx.x;
  const int wave = tid >> 6;
  const int lane = tid & 63;
  const int bm = mblk * BMT;
  const int bn = nblk * 128;
  const int wm = (wave >> 1) * (BMT / 2);
  const int wn = (wave & 1) * 64;
  const int quad  = lane >> 4;
  const int col15 = lane & 15;

  // A staging per 32-tile: BMT*4 chunks of 16B
  const int ar1 = tid >> 2, ao1 = (tid & 3) * 8;
  const bool mok1 = (bm + ar1) < M;
  const __bf16* ag1 = A + (size_t)(bm + ar1) * lda + ao1;
  const int ar2 = (tid + 256) >> 2, ao2 = ((tid + 256) & 3) * 8;
  const bool mok2 = (BMT == 128) && ((bm + ar2) < M);
  const __bf16* ag2 = A + (size_t)(bm + ar2) * lda + ao2;

  f32x4 acc[MT][4];
#pragma unroll
  for (int i = 0; i < MT; ++i)
#pragma unroll
    for (int j = 0; j < 4; ++j) acc[i][j] = (f32x4){0.f, 0.f, 0.f, 0.f};

  for (int k0 = 0; k0 < K; k0 += 64) {
#pragma unroll
    for (int t = 0; t < 2; ++t) {
      if (mok1) GLDS16(ag1 + k0 + t * 32, &smem[t][tid * 8]);
      if (BMT == 128) {
        if (mok2) GLDS16(ag2 + k0 + t * 32, &smem[t][(tid + 256) * 8]);
      }
#pragma unroll
      for (int i = 0; i < 2; ++i) {   // B: 512 chunks per tile
        int c = tid + i * 256;
        GLDS16(Bt + (size_t)(bn + (c >> 2)) * ldb + (c & 3) * 8 + k0 + t * 32,
               &smem[t][BOFF + c * 8]);
      }
    }
    __syncthreads();

    const int ko = quad * 8;
#pragma unroll
    for (int t = 0; t < 2; ++t) {
      bf16x8 af[MT], bfr[4];
#pragma unroll
      for (int mt = 0; mt < MT; ++mt)
        af[mt] = *(const bf16x8*)(&smem[t][(wm + mt * 16 + col15) * 32 + ko]);
#pragma unroll
      for (int nt = 0; nt < 4; ++nt)
        bfr[nt] = *(const bf16x8*)(
            &smem[t][BOFF + (wn + nt * 16 + col15) * 32 + ko]);
#pragma unroll
      for (int mt = 0; mt < MT; ++mt)
#pragma unroll
        for (int nt = 0; nt < 4; ++nt)
          acc[mt][nt] = __builtin_amdgcn_mfma_f32_16x16x32_bf16(
              af[mt], bfr[nt], acc[mt][nt], 0, 0, 0);
    }
    __syncthreads();
  }

  // ---- LDS-restaged epilogue ----
  float bv[4];
#pragma unroll
  for (int nt = 0; nt < 4; ++nt)
    bv[nt] = bias ? bias[bn + wn + nt * 16 + col15] : 0.f;

  float* stg = ((float*)&smem[0][0]) + wave * 2048;  // 8 KB/wave

#pragma unroll
  for (int mt = 0; mt < MT; ++mt) {
    __syncthreads();  // uniform; protects smem reuse across quarters
#pragma unroll
    for (int nt = 0; nt < 4; ++nt)
#pragma unroll
      for (int r = 0; r < 4; ++r) {
        float o = acc[mt][nt][r] + bv[nt];
        if (relu) o = fmaxf(o, 0.f);
        stg[(quad * 4 + r) * 68 + nt * 16 + col15] = o;
      }
    const int rbase = bm + wm + mt * 16;
    if (outmode == 0) {                       // fp32 out
      float* Cf = (float*)C;
#pragma unroll
      for (int it = 0; it < 4; ++it) {
        int t = it * 64 + lane;
        int row = t >> 4, cg = t & 15;
        int gr = rbase + row;
        if (gr < M) {
          f32x4 x = *(const f32x4*)(stg + row * 68 + cg * 4);
          *(f32x4*)(Cf + (size_t)gr * ldc + bn + wn + cg * 4) = x;
        }
      }
    } else if (outmode == 1 || bn < 256) {    // bf16 out (ldc in bf16 units)
      __bf16* Cb = (__bf16*)C;
#pragma unroll
      for (int it = 0; it < 2; ++it) {
        int t = it * 64 + lane;
        int row = t >> 3, cg = t & 7;
        int gr = rbase + row;
        if (gr < M) {
          f32x4 x = *(const f32x4*)(stg + row * 68 + cg * 8);
          f32x4 y = *(const f32x4*)(stg + row * 68 + cg * 8 + 4);
          __bf16 o8[8] = {(__bf16)x[0], (__bf16)x[1], (__bf16)x[2], (__bf16)x[3],
                          (__bf16)y[0], (__bf16)y[1], (__bf16)y[2], (__bf16)y[3]};
          *(uint4*)(Cb + (size_t)gr * ldc + bn + wn + cg * 8) = *(uint4*)o8;
        }
      }
    } else {                                   // fp8 kv region of qkv row
      unsigned char* C8 = (unsigned char*)C;
      int row = lane >> 2, cg = lane & 3;      // 16 rows x 4 groups of 16 cols
      int gr = rbase + row;
      if (gr < M) {
        uint4 o;
        o.x = pk_fp8x4(*(const f32x4*)(stg + row * 68 + cg * 16 + 0));
        o.y = pk_fp8x4(*(const f32x4*)(stg + row * 68 + cg * 16 + 4));
        o.z = pk_fp8x4(*(const f32x4*)(stg + row * 68 + cg * 16 + 8));
        o.w = pk_fp8x4(*(const f32x4*)(stg + row * 68 + cg * 16 + 12));
        *(uint4*)(C8 + (size_t)gr * 1024 + 512 + (bn - 256) + wn + cg * 16) = o;
      }
    }
  }
}

// ---------------------------------------------------------------------------
// Fused Wo-GEMM + residual + LayerNorm, LDS-restaged output (unchanged).
// ---------------------------------------------------------------------------
__global__ __launch_bounds__(256) void gemm_wo_ln(
    const __bf16* __restrict__ A,   // agg bf16 [M][256]
    const __bf16* __restrict__ Bt,  // wot [256][256]
    float* __restrict__ h,          // fp32 residual in / LN out
    __bf16* __restrict__ hb,        // bf16 LN out
    const float* __restrict__ g, const float* __restrict__ bb)
{
  __shared__ __align__(16) __bf16 smem[2][288 * 32];
  __shared__ float red_s[32][2], red_q[32][2];
  const int tid  = threadIdx.x;
  const int wave = tid >> 6;
  const int lane = tid & 63;
  const int quad  = lane >> 4;
  const int col15 = lane & 15;
  const int bm = blockIdx.x * 32;
  const int wm = (wave >> 1) * 16;
  const int wn = (wave & 1) * 128;
  const int ch = wave & 1;

  const int at   = tid >> 7;
  const int ac   = tid & 127;
  const int arow = ac >> 2, aoff = (ac & 3) * 8;
  const __bf16* agp = A + (size_t)(bm + arow) * 256 + aoff;

  f32x4 acc[8];
#pragma unroll
  for (int j = 0; j < 8; ++j) acc[j] = (f32x4){0.f, 0.f, 0.f, 0.f};

  for (int k0 = 0; k0 < 256; k0 += 64) {
    GLDS16(agp + k0 + at * 32, &smem[at][ac * 8]);
#pragma unroll
    for (int i = 0; i < 8; ++i) {
      int c = tid + i * 256;
      int t = c >> 10, idx = c & 1023;
      GLDS16(Bt + (size_t)(idx >> 2) * 256 + (idx & 3) * 8 + k0 + t * 32,
             &smem[t][1024 + idx * 8]);
    }
    __syncthreads();
    const int ko = quad * 8;
#pragma unroll
    for (int t = 0; t < 2; ++t) {
      bf16x8 af = *(const bf16x8*)(&smem[t][(wm + col15) * 32 + ko]);
#pragma unroll
      for (int nt = 0; nt < 8; ++nt) {
        bf16x8 bfr = *(const bf16x8*)(
            &smem[t][1024 + (wn + nt * 16 + col15) * 32 + ko]);
        acc[nt] = __builtin_amdgcn_mfma_f32_16x16x32_bf16(af, bfr, acc[nt],
                                                          0, 0, 0);
      }
    }
    __syncthreads();
  }

#pragma unroll
  for (int r = 0; r < 4; ++r) {
    const int lr = wm + quad * 4 + r;
    const int gr = bm + lr;
    float s = 0.f, q = 0.f;
#pragma unroll
    for (int nt = 0; nt < 8; ++nt) {
      int gc = wn + nt * 16 + col15;
      float x = acc[nt][r] + h[(size_t)gr * 256 + gc];
      acc[nt][r] = x;
      s += x; q += x * x;
    }
    s += __shfl_xor(s, 1); q += __shfl_xor(q, 1);
    s += __shfl_xor(s, 2); q += __shfl_xor(q, 2);
    s += __shfl_xor(s, 4); q += __shfl_xor(q, 4);
    s += __shfl_xor(s, 8); q += __shfl_xor(q, 8);
    if (col15 == 0) { red_s[lr][ch] = s; red_q[lr][ch] = q; }
  }
  __syncthreads();

  float* stg = (float*)&smem[0][0];
#pragma unroll
  for (int r = 0; r < 4; ++r) {
    const int lr = wm + quad * 4 + r;
    float s = red_s[lr][0] + red_s[lr][1];
    float q = red_q[lr][0] + red_q[lr][1];
    float mu  = s * (1.f / 256);
    float var = q * (1.f / 256) - mu * mu;
    float inv = rsqrtf(var + 1e-5f);
#pragma unroll
    for (int nt = 0; nt < 8; ++nt) {
      int gc = wn + nt * 16 + col15;
      stg[lr * 260 + gc] = (acc[nt][r] - mu) * inv * g[gc] + bb[gc];
    }
  }
  __syncthreads();

#pragma unroll
  for (int it = 0; it < 8; ++it) {
    int t = it * 256 + tid;
    int row = t >> 6, cg = t & 63;
    f32x4 x = *(const f32x4*)(stg + row * 260 + cg * 4);
    *(f32x4*)(h + (size_t)(bm + row) * 256 + cg * 4) = x;
  }
#pragma unroll
  for (int it = 0; it < 4; ++it) {
    int t = it * 256 + tid;
    int row = t >> 5, cg = t & 31;
    f32x4 x = *(const f32x4*)(stg + row * 260 + cg * 8);
    f32x4 y = *(const f32x4*)(stg + row * 260 + cg * 8 + 4);
    __bf16 o8[8] = {(__bf16)x[0], (__bf16)x[1], (__bf16)x[2], (__bf16)x[3],
                    (__bf16)y[0], (__bf16)y[1], (__bf16)y[2], (__bf16)y[3]};
    *(uint4*)(hb + (size_t)(bm + row) * 256 + cg * 8) = *(uint4*)o8;
  }
}

// ---------------------------------------------------------------------------
// PREP mega-kernel (unchanged): transposes | h-init | histogram.
// ---------------------------------------------------------------------------
__global__ __launch_bounds__(256) void prep_kernel(
    const float* __restrict__ Wq, const float* __restrict__ Wk,
    const float* __restrict__ Wv, const float* __restrict__ Wo,
    const float* __restrict__ w1, const float* __restrict__ w2,
    __bf16* __restrict__ wqkvt, __bf16* __restrict__ wot,
    __bf16* __restrict__ w1t, __bf16* __restrict__ w2t,
    const float* __restrict__ h_in, float* __restrict__ hbuf,
    __bf16* __restrict__ hb,
    const int* __restrict__ dst, int* __restrict__ cnt)
{
  __shared__ float t[32][33];
  const int b = blockIdx.x;
  if (b >= 3524) {               // ---- histogram ----
    int e = (b - 3524) * 256 + threadIdx.x;
    if (e < NE) atomicAdd(&cnt[dst[e]], 1);
    return;
  }
  if (b >= 1024) {               // ---- h init ----
    int i = ((b - 1024) * 256 + threadIdx.x) * 8;
    if (i >= NN * DIM) return;
    float4 a = *(const float4*)(h_in + i);
    float4 c = *(const float4*)(h_in + i + 4);
    *(float4*)(hbuf + i) = a;
    *(float4*)(hbuf + i + 4) = c;
    __bf16 o[8] = {(__bf16)a.x, (__bf16)a.y, (__bf16)a.z, (__bf16)a.w,
                   (__bf16)c.x, (__bf16)c.y, (__bf16)c.z, (__bf16)c.w};
    *(uint4*)(hb + i) = *(uint4*)o;
    return;
  }
  // ---- weight transposes ----
  const float* src;
  __bf16* dstp;
  int N, Kd, bk, bn, mode = 0;  // 0: identity, 1: k-perm, 2: v-perm
  if (b < 512) {
    int m = b >> 6, tt = b & 63;
    bk = (tt & 7) * 32; bn = (tt >> 3) * 32;
    N = 256; Kd = 256;
    int l = m & 1, w = m >> 1;  // w: 0=Wq 1=Wk 2=Wv 3=Wo
    const float* Ws[4] = {Wq, Wk, Wv, Wo};
    src = Ws[w] + (size_t)l * 65536;
    if (w == 3) dstp = wot + (size_t)l * 65536;
    else { dstp = wqkvt + (size_t)l * 196608; mode = (w == 0) ? 0 : w; }
  } else if (b < 768) {
    int tt = b - 512;
    bk = (tt & 7) * 32; bn = (tt >> 3) * 32;
    N = 1024; Kd = 256; src = w1; dstp = w1t;
  } else {
    int tt = b - 768;
    bk = (tt >> 3) * 32; bn = (tt & 7) * 32;
    N = 256; Kd = 1024; src = w2; dstp = w2t;
  }
  const int tx = threadIdx.x & 31, ty = threadIdx.x >> 5;
#pragma unroll
  for (int i = 0; i < 32; i += 8)
    t[ty + i][tx] = src[(size_t)(bk + ty + i) * N + bn + tx];
  __syncthreads();
#pragma unroll
  for (int i = 0; i < 32; i += 8) {
    int n = bn + ty + i;
    int r = (mode == 0) ? n
          : 256 + ((n >> 2) * 8) + (n & 3) + (mode == 2 ? 4 : 0);
    dstp[(size_t)r * Kd + bk + tx] = (__bf16)t[tx][ty + i];
  }
}

// ---------------------------------------------------------------------------
// CSR build: scan (re-zeros cnt for cursor reuse) + scatter (stores SRC id).
// ---------------------------------------------------------------------------
__global__ __launch_bounds__(1024) void scan_kernel(
    int* __restrict__ cnt, int* __restrict__ rowstart)
{
  __shared__ int part[1024];
  const int t = threadIdx.x;
  const int CHUNK = (NN + 1023) / 1024;  // 20
  const int base = t * CHUNK;
  int s = 0;
#pragma unroll
  for (int i = 0; i < CHUNK; ++i) {
    int idx = base + i;
    if (idx < NN) s += cnt[idx];
  }
  part[t] = s;
  __syncthreads();
  for (int off = 1; off < 1024; off <<= 1) {
    int v = (t >= off) ? part[t - off] : 0;
    __syncthreads();
    part[t] += v;
    __syncthreads();
  }
  int run = part[t] - s;
#pragma unroll
  for (int i = 0; i < CHUNK; ++i) {
    int idx = base + i;
    if (idx < NN) {
      rowstart[idx] = run;
      run += cnt[idx];
      cnt[idx] = 0;
    }
  }
  if (t == 1023) rowstart[NN] = part[1023];
}

__global__ __launch_bounds__(256) void scatter_kernel(
    const int* __restrict__ src, const int* __restrict__ dst,
    const int* __restrict__ rowstart,
    int* __restrict__ cursor, int* __restrict__ csrc, int E)
{
  int e = blockIdx.x * blockDim.x + threadIdx.x;
  if (e >= E) return;
  int d = dst[e];
  int pos = atomicAdd(&cursor[d], 1);
  csrc[rowstart[d] + pos] = src[e];
}

// ---------------------------------------------------------------------------
// Fused per-node attention, split-wave + depth-2 pipeline: one wave per dst
// node, two 32-lane halves each processing alternate edges with TWO gathers
// in flight (kv0/kv1) -> 4 outstanding 512B gathers per wave (latency-bound
// regime: throughput ~ outstanding/latency).
// qkv rows 1024 B: q bf16 (bytes 0..511), kv fp8 e4m3 (512..1023).
// ---------------------------------------------------------------------------
__global__ __launch_bounds__(256) void node_attn(
    const unsigned char* __restrict__ qkv,
    const int* __restrict__ rowstart, const int* __restrict__ csrc,
    __bf16* __restrict__ agg)
{
  const int wave = threadIdx.x >> 6;
  const int lane = threadIdx.x & 63;
  const int hw   = lane >> 5;
  const int ln32 = lane & 31;
  const int d = blockIdx.x * 4 + wave;
  if (d >= NN) return;
  const int beg = rowstart[d], end = rowstart[d + 1];

  float qf[8];
  {
    bf16x8 q8 = *(const bf16x8*)(qkv + (size_t)d * 1024 + ln32 * 16);
#pragma unroll
    for (int j = 0; j < 8; ++j) qf[j] = (float)q8[j];
  }
  const float scale = 0.17677669529663687f;  // 1/sqrt(32)
  float z = 0.f;
  float ac[8];
#pragma unroll
  for (int j = 0; j < 8; ++j) ac[j] = 0.f;

  for (int c = beg; c < end; c += 64) {
    const int n = min(64, end - c);
    const int myi = c + lane;
    const int s_l = (myi < end) ? csrc[myi] : 0;   // coalesced batch load

    uint4 kv0 = make_uint4(0u, 0u, 0u, 0u);
    uint4 kv1 = make_uint4(0u, 0u, 0u, 0u);
    if (hw < n) {
      int s = __shfl(s_l, hw);
      kv0 = *(const uint4*)(qkv + (size_t)s * 1024 + 512 + ln32 * 16);
    }
    if (hw + 2 < n) {
      int s = __shfl(s_l, hw + 2);
      kv1 = *(const uint4*)(qkv + (size_t)s * 1024 + 512 + ln32 * 16);
    }
    for (int i = hw; i < n; i += 2) {
      uint4 kv = kv0;
      kv0 = kv1;
      if (i + 4 < n) {  // refill the 2-deep pipe
        int sn = __shfl(s_l, i + 4);
        kv1 = *(const uint4*)(qkv + (size_t)sn * 1024 + 512 + ln32 * 16);
      }
      f32x2 k01 = __builtin_amdgcn_cvt_pk_f32_fp8(kv.x, false);
      f32x2 k23 = __builtin_amdgcn_cvt_pk_f32_fp8(kv.x, true);
      f32x2 k45 = __builtin_amdgcn_cvt_pk_f32_fp8(kv.z, false);
      f32x2 k67 = __builtin_amdgcn_cvt_pk_f32_fp8(kv.z, true);
      float p = qf[0] * k01[0] + qf[1] * k01[1] + qf[2] * k23[0] +
                qf[3] * k23[1] + qf[4] * k45[0] + qf[5] * k45[1] +
                qf[6] * k67[0] + qf[7] * k67[1];
      p += __shfl_xor(p, 1);
      p += __shfl_xor(p, 2);
      float a = __expf(p * scale);
      z += a;
      f32x2 v01 = __builtin_amdgcn_cvt_pk_f32_fp8(kv.y, false);
      f32x2 v23 = __builtin_amdgcn_cvt_pk_f32_fp8(kv.y, true);
      f32x2 v45 = __builtin_amdgcn_cvt_pk_f32_fp8(kv.w, false);
      f32x2 v67 = __builtin_amdgcn_cvt_pk_f32_fp8(kv.w, true);
      ac[0] += a * v01[0]; ac[1] += a * v01[1];
      ac[2] += a * v23[0]; ac[3] += a * v23[1];
      ac[4] += a * v45[0]; ac[5] += a * v45[1];
      ac[6] += a * v67[0]; ac[7] += a * v67[1];
    }
  }
  // combine halves
  z += __shfl_xor(z, 32);
#pragma unroll
  for (int j = 0; j < 8; ++j) ac[j] += __shfl_xor(ac[j], 32);
  const float inv = 1.f / (z + 1e-9f);
  if (lane < 32) {
    __bf16 o[8];
#pragma unroll
    for (int j = 0; j < 8; ++j) o[j] = (__bf16)(ac[j] * inv);
    *(uint4*)(agg + (size_t)d * DIM + ln32 * 8) = *(uint4*)o;
  }
}

// ---------------------------------------------------------------------------
extern "C" void kernel_launch(void* const* d_in, const int* in_sizes, int n_in,
                              void* d_out, int out_size, void* d_ws, size_t ws_size,
                              hipStream_t stream)
{
  const float* h_in = (const float*)d_in[0];
  const int*   src  = (const int*)d_in[1];
  const int*   dst  = (const int*)d_in[2];
  const float* Wq   = (const float*)d_in[3];
  const float* Wk   = (const float*)d_in[4];
  const float* Wv   = (const float*)d_in[5];
  const float* Wo   = (const float*)d_in[6];
  const float* ln_g = (const float*)d_in[7];
  const float* ln_b = (const float*)d_in[8];
  const float* w1   = (const float*)d_in[9];
  const float* b1   = (const float*)d_in[10];
  const float* w2   = (const float*)d_in[11];
  const float* b2   = (const float*)d_in[12];
  float* out = (float*)d_out;

  // workspace layout (fp32-equivalent units)
  float*  ws   = (float*)d_ws;
  float*  hbuf = ws;                                  // NN*DIM fp32
  float*  big  = hbuf + (size_t)NN * DIM;             // 15.36M floats
  __bf16* hbf  = (__bf16*)(big + (size_t)NN * 768);   // NN*DIM bf16
  __bf16* wbf  = hbf + (size_t)NN * DIM;              // 1.05M bf16
  int*    cnt      = (int*)(wbf + 1048576);           // NN
  int*    rowstart = cnt + NN;                        // NN+1
  int*    csrc     = rowstart + NN + 1;               // NE (src per CSR slot)

  unsigned char* qkvb = (unsigned char*)big;  // NN rows x 1024 B (q bf16|kv fp8)
  __bf16* ffnb = (__bf16*)big;                // NN*HUS bf16 (FFN hidden)

  __bf16* wqkvt = wbf;                       // 2 x [768][256] (kv permuted)
  __bf16* wot   = wqkvt + 2 * 768 * 256;     // 2 x [256][256]
  __bf16* w1t   = wot + 2 * 256 * 256;       // [1024][256]
  __bf16* w2t   = w1t + 1024 * 256;          // [256][1024]

  const dim3 blk(256);
  const int  g_node = (NN + 3) / 4;

  // prep: memset + mega-prep (transposes | h-init | hist) + scan + scatter
  hipMemsetAsync(cnt, 0, NN * sizeof(int), stream);
  prep_kernel<<<4774, blk, 0, stream>>>(Wq, Wk, Wv, Wo, w1, w2,
                                        wqkvt, wot, w1t, w2t,
                                        h_in, hbuf, hbf, dst, cnt);
  scan_kernel<<<1, 1024, 0, stream>>>(cnt, rowstart);
  scatter_kernel<<<(NE + 255) / 256, blk, 0, stream>>>(
      src, dst, rowstart, cnt, csrc, NE);

  // XCD-swizzled grids: grid = (8, ceil(mtiles/8)*ntiles)
  const int mt128 = (NN + 127) / 128;     // 157
  const int mt64  = (NN + 63) / 64;       // 313
  const dim3 g_qkv(8, ((mt128 + 7) / 8) * 6);   // N=768:  6 n-tiles
  const dim3 g_ffn1(8, ((mt128 + 7) / 8) * 8);  // N=1024: 8 n-tiles
  const dim3 g_ffn2(8, ((mt64 + 7) / 8) * 2);   // N=256:  2 n-tiles, BM=64
  const int  g_woln = NN / 32;                  // 625 blocks (exact)

  for (int l = 0; l < NLAYER; ++l) {
    // fused q|kv projection -> q bf16 + kv fp8, row stride 1024 B
    gemm_bf16_t<0, 128><<<g_qkv, blk, 0, stream>>>(
        hbf, DIM, wqkvt + (size_t)l * 196608, DIM, qkvb, 512,
        nullptr, NN, 768, DIM, 0, 2, mt128, 6);

    // split-wave single-pass attention; agg -> bf16 into hbf
    node_attn<<<g_node, blk, 0, stream>>>(qkvb, rowstart, csrc, hbf);

    // fused Wo-GEMM + residual + LN -> hbuf (fp32) + hbf (bf16)
    gemm_wo_ln<<<g_woln, blk, 0, stream>>>(
        hbf, wot + (size_t)l * 65536, hbuf, hbf,
        ln_g + l * DIM, ln_b + l * DIM);
  }

  // FFN1: relu(h@w1+b1) -> bf16 hidden
  gemm_bf16_t<1, 128><<<g_ffn1, blk, 0, stream>>>(
      hbf, DIM, w1t, DIM, ffnb, HUS, b1, NN, HUS, DIM, 1, 1, mt128, 8);
  // FFN2: hidden @ w2 + b2 -> out (fp32)
  gemm_bf16_t<2, 64><<<g_ffn2, blk, 0, stream>>>(
      ffnb, HUS, w2t, HUS, out, DIM, b2, NN, DIM, HUS, 0, 0, mt64, 2);
}